// Round 2
// baseline (2983.235 us; speedup 1.0000x reference)
//
#include <hip/hip_runtime.h>

#define B_   4
#define TT_  2048
#define C_   2048
#define H_   32
#define S_   64
#define DF_  7168
#define TCH  512
#define NCH  4

typedef unsigned short u16;
typedef __bf16 bf16x8 __attribute__((ext_vector_type(8)));
typedef float  f32x4  __attribute__((ext_vector_type(4)));

__device__ __forceinline__ u16 f2bf(float f) {
  unsigned u = __builtin_bit_cast(unsigned, f);
  u = u + 0x7FFFu + ((u >> 16) & 1u);
  return (u16)(u >> 16);
}
__device__ __forceinline__ float bf2f(u16 v) {
  unsigned u = ((unsigned)v) << 16;
  return __builtin_bit_cast(float, u);
}

#define GLOAD16(g, l) __builtin_amdgcn_global_load_lds( \
    (const __attribute__((address_space(1))) void*)(g), \
    (__attribute__((address_space(3))) void*)(l), 16, 0, 0)

// ---- weight convert+transpose: W (K,Nfull) f32, cols [n0off, n0off+gx*32) -> Wt (ncols,K) bf16
__global__ __launch_bounds__(256) void wcvt_t(const float* __restrict__ W,
                                              u16* __restrict__ Wt, int K, int Nfull,
                                              int n0off) {
  __shared__ alignas(16) float tile[32][33];
  int nloc = blockIdx.x * 32, k0 = blockIdx.y * 32;
  int tx = threadIdx.x & 31, ty = threadIdx.x >> 5;
  for (int r = ty; r < 32; r += 8)
    tile[r][tx] = W[(size_t)(k0 + r) * Nfull + n0off + nloc + tx];
  __syncthreads();
  for (int r = ty; r < 32; r += 8)
    Wt[(size_t)(nloc + r) * K + k0 + tx] = f2bf(tile[tx][r]);
}

// ---- layernorm over C=2048, f32 in -> bf16 out ------------------------------
__global__ __launch_bounds__(256) void ln_rows(const float* __restrict__ x,
                                               const float* __restrict__ g,
                                               const float* __restrict__ b,
                                               u16* __restrict__ out) {
  const int row = blockIdx.x;
  const float* xr = x + (size_t)row * C_;
  float v[8]; float s = 0.f, s2 = 0.f;
#pragma unroll
  for (int i = 0; i < 8; i++) { v[i] = xr[threadIdx.x + i * 256]; s += v[i]; s2 += v[i] * v[i]; }
#pragma unroll
  for (int o = 32; o > 0; o >>= 1) { s += __shfl_down(s, o); s2 += __shfl_down(s2, o); }
  __shared__ float rs[4], rs2[4];
  int wid = threadIdx.x >> 6, lane = threadIdx.x & 63;
  if (lane == 0) { rs[wid] = s; rs2[wid] = s2; }
  __syncthreads();
  s = rs[0] + rs[1] + rs[2] + rs[3];
  s2 = rs2[0] + rs2[1] + rs2[2] + rs2[3];
  float m = s * (1.f / C_);
  float var = s2 * (1.f / C_) - m * m;
  float inv = rsqrtf(var + 1e-5f);
  u16* orow = out + (size_t)row * C_;
#pragma unroll
  for (int i = 0; i < 8; i++) {
    int c = threadIdx.x + i * 256;
    orow[c] = f2bf((v[i] - m) * inv * g[c] + b[c]);
  }
}

// ---- decay tables -----------------------------------------------------------
__global__ void wtabs_k(const float* __restrict__ td, float* __restrict__ wb_tab,
                        float* __restrict__ wk_tab, float* __restrict__ wspow) {
  int h = blockIdx.x, t = threadIdx.x;
  float w = expf(-expf(td[h]));
  wb_tab[h * TCH + t] = powf(w, (float)t);
  wk_tab[h * TCH + t] = powf(w, (float)(TCH - 1 - t));
  if (t == 0) wspow[h] = powf(w, (float)TCH);
}

__global__ void zero_k(float* __restrict__ p) {
  p[(size_t)blockIdx.x * 256 + threadIdx.x] = 0.f;
}

// ---- mix helper: dst[0..8) = cur*m + prev*(1-m), bf16 -----------------------
__device__ __forceinline__ void mix8(const u16* cur, const u16* prev, bool hasp,
                                     const float* mc, u16* dst) {
  ushort4 c0 = *(const ushort4*)cur;
  ushort4 c1 = *(const ushort4*)(cur + 4);
  ushort4 p0 = {0, 0, 0, 0}, p1 = {0, 0, 0, 0};
  if (hasp) { p0 = *(const ushort4*)prev; p1 = *(const ushort4*)(prev + 4); }
  float4 mA = *(const float4*)mc;
  float4 mB = *(const float4*)(mc + 4);
  ushort4 r0, r1;
  r0.x = f2bf(bf2f(c0.x) * mA.x + bf2f(p0.x) * (1.f - mA.x));
  r0.y = f2bf(bf2f(c0.y) * mA.y + bf2f(p0.y) * (1.f - mA.y));
  r0.z = f2bf(bf2f(c0.z) * mA.z + bf2f(p0.z) * (1.f - mA.z));
  r0.w = f2bf(bf2f(c0.w) * mA.w + bf2f(p0.w) * (1.f - mA.w));
  r1.x = f2bf(bf2f(c1.x) * mB.x + bf2f(p1.x) * (1.f - mB.x));
  r1.y = f2bf(bf2f(c1.y) * mB.y + bf2f(p1.y) * (1.f - mB.y));
  r1.z = f2bf(bf2f(c1.z) * mB.z + bf2f(p1.z) * (1.f - mB.z));
  r1.w = f2bf(bf2f(c1.w) * mB.w + bf2f(p1.w) * (1.f - mB.w));
  *(ushort4*)dst = r0;
  *(ushort4*)(dst + 4) = r1;
}

// ---- GEMM with fused time-shift mix on A: C = mix(h) @ Bt^T -----------------
// h: (8192, 2048) bf16. Bt: (N, 2048) bf16. EPI: 0=store bf16, 2=relu^2 bf16, 3=sigmoid bf16
template <int EPI>
__global__ __launch_bounds__(256) void gemm_mix(const u16* __restrict__ h,
                                                const float* __restrict__ mixc,
                                                const u16* __restrict__ Bt,
                                                void* __restrict__ Cv, int N) {
  __shared__ alignas(16) u16 As[128 * 32];
  __shared__ alignas(16) u16 Bs[128 * 32];
  const int tid = threadIdx.x;
  const int wid = tid >> 6, lane = tid & 63;
  const int fr = lane & 15, fq = lane >> 4;
  const int m0 = blockIdx.x * 128, n0 = blockIdx.y * 128;
  const int wm = (wid >> 1) * 64, wn = (wid & 1) * 64;
  const int rowS = tid >> 2, colS = (tid & 3) * 8;
  const u16* Bg = Bt + (size_t)(n0 + rowS) * 2048 + colS;
  char* ldsB = (char*)Bs + wid * 1024;
  const int row0 = m0 + rowS;
  const int row1 = row0 + 64;
  const bool hp0 = (row0 & (TT_ - 1)) != 0;
  const bool hp1 = (row1 & (TT_ - 1)) != 0;
  const u16* hc0 = h + (size_t)row0 * C_ + colS;
  const u16* hc1 = h + (size_t)row1 * C_ + colS;
  f32x4 acc[4][4];
#pragma unroll
  for (int i = 0; i < 4; i++)
#pragma unroll
    for (int j = 0; j < 4; j++) acc[i][j] = (f32x4){0.f, 0.f, 0.f, 0.f};

  for (int k0 = 0; k0 < 2048; k0 += 32) {
    GLOAD16(Bg + k0, ldsB);
    GLOAD16(Bg + k0 + (size_t)64 * 2048, ldsB + 4096);
    mix8(hc0 + k0, hc0 + k0 - C_, hp0, &mixc[k0 + colS], &As[rowS * 32 + colS]);
    mix8(hc1 + k0, hc1 + k0 - C_, hp1, &mixc[k0 + colS], &As[(rowS + 64) * 32 + colS]);
    __syncthreads();
    bf16x8 av[4], bv[4];
#pragma unroll
    for (int m = 0; m < 4; m++) av[m] = *(const bf16x8*)&As[(wm + m * 16 + fr) * 32 + fq * 8];
#pragma unroll
    for (int n = 0; n < 4; n++) bv[n] = *(const bf16x8*)&Bs[(wn + n * 16 + fr) * 32 + fq * 8];
#pragma unroll
    for (int m = 0; m < 4; m++)
#pragma unroll
      for (int n = 0; n < 4; n++)
        acc[m][n] = __builtin_amdgcn_mfma_f32_16x16x32_bf16(av[m], bv[n], acc[m][n], 0, 0, 0);
    __syncthreads();
  }
#pragma unroll
  for (int m = 0; m < 4; m++)
#pragma unroll
    for (int n = 0; n < 4; n++)
#pragma unroll
      for (int j = 0; j < 4; j++) {
        int row = m0 + wm + m * 16 + fq * 4 + j;
        int col = n0 + wn + n * 16 + fr;
        size_t idx = (size_t)row * N + col;
        float v = acc[m][n][j];
        if (EPI == 0) ((u16*)Cv)[idx] = f2bf(v);
        else if (EPI == 2) { float r = v > 0.f ? v : 0.f; ((u16*)Cv)[idx] = f2bf(r * r); }
        else ((u16*)Cv)[idx] = f2bf(1.f / (1.f + expf(-v)));
      }
}

// ---- plain GEMM: A (M,K) bf16, Bt (N,K) bf16 --------------------------------
// EPI: 1 = f32 out = acc + res ; 5 = f32 out = acc (raw partial)
//      6 = f32 out = res + bf16(mul) * (acc + prev_out)
template <int EPI>
__global__ __launch_bounds__(256) void gemm_bt(const u16* __restrict__ A,
                                               const u16* __restrict__ Bt,
                                               void* __restrict__ Cv,
                                               const float* __restrict__ res,
                                               const u16* __restrict__ mul,
                                               int M, int N, int K) {
  __shared__ alignas(16) u16 As[128 * 32];
  __shared__ alignas(16) u16 Bs[128 * 32];
  const int tid = threadIdx.x;
  const int wid = tid >> 6, lane = tid & 63;
  const int fr = lane & 15, fq = lane >> 4;
  const int m0 = blockIdx.x * 128, n0 = blockIdx.y * 128;
  const int wm = (wid >> 1) * 64, wn = (wid & 1) * 64;
  const int rowS = tid >> 2, colS = (tid & 3) * 8;
  const u16* Ag = A + (size_t)(m0 + rowS) * K + colS;
  const u16* Bg = Bt + (size_t)(n0 + rowS) * K + colS;
  char* ldsA = (char*)As + wid * 1024;
  char* ldsB = (char*)Bs + wid * 1024;
  f32x4 acc[4][4];
#pragma unroll
  for (int i = 0; i < 4; i++)
#pragma unroll
    for (int j = 0; j < 4; j++) acc[i][j] = (f32x4){0.f, 0.f, 0.f, 0.f};

  for (int k0 = 0; k0 < K; k0 += 32) {
    GLOAD16(Ag + k0, ldsA);
    GLOAD16(Ag + k0 + (size_t)64 * K, ldsA + 4096);
    GLOAD16(Bg + k0, ldsB);
    GLOAD16(Bg + k0 + (size_t)64 * K, ldsB + 4096);
    __syncthreads();
    bf16x8 av[4], bv[4];
#pragma unroll
    for (int m = 0; m < 4; m++) av[m] = *(const bf16x8*)&As[(wm + m * 16 + fr) * 32 + fq * 8];
#pragma unroll
    for (int n = 0; n < 4; n++) bv[n] = *(const bf16x8*)&Bs[(wn + n * 16 + fr) * 32 + fq * 8];
#pragma unroll
    for (int m = 0; m < 4; m++)
#pragma unroll
      for (int n = 0; n < 4; n++)
        acc[m][n] = __builtin_amdgcn_mfma_f32_16x16x32_bf16(av[m], bv[n], acc[m][n], 0, 0, 0);
    __syncthreads();
  }
#pragma unroll
  for (int m = 0; m < 4; m++)
#pragma unroll
    for (int n = 0; n < 4; n++)
#pragma unroll
      for (int j = 0; j < 4; j++) {
        int row = m0 + wm + m * 16 + fq * 4 + j;
        int col = n0 + wn + n * 16 + fr;
        size_t idx = (size_t)row * N + col;
        float v = acc[m][n][j];
        if (EPI == 1) ((float*)Cv)[idx] = v + res[idx];
        else if (EPI == 5) ((float*)Cv)[idx] = v;
        else {
          float pv = ((float*)Cv)[idx];
          ((float*)Cv)[idx] = res[idx] + bf2f(mul[idx]) * (v + pv);
        }
      }
}

// ---- attention: per-chunk output --------------------------------------------
__global__ __launch_bounds__(256) void att_out_k(const u16* __restrict__ R,
                                                 const u16* __restrict__ Kk,
                                                 const u16* __restrict__ V,
                                                 const float* __restrict__ state,
                                                 const float* __restrict__ wb_tab,
                                                 const float* __restrict__ u_vec,
                                                 u16* __restrict__ xa, int c0) {
  const int bh = blockIdx.x, tile = blockIdx.y;
  const int b = bh >> 5, h = bh & 31;
  const int tid = threadIdx.x;
  const int t0 = tile * 64;
  const size_t rowbase = (size_t)b * TT_ + (size_t)c0 * TCH + t0;
  const size_t chunkbase = (size_t)b * TT_ + (size_t)c0 * TCH;
  const u16* Rp = R + rowbase * C_ + h * 64;
  const u16* Kp = Kk + chunkbase * C_ + h * 64;
  const u16* Vp = V + chunkbase * C_ + h * 64;
  __shared__ alignas(16) float rr_s[64][68];
  __shared__ alignas(16) float ks_s[64][68];
  __shared__ alignas(16) float vs_s[64][68];
  __shared__ alignas(16) float as_s[64][68];
  for (int e = tid; e < 4096; e += 256) {
    int t = e >> 6, s = e & 63;
    rr_s[t][s] = bf2f(Rp[(size_t)t * C_ + s]);
  }
  __syncthreads();
  const int s_o = tid & 63, wv = tid >> 6;
  float acc[16];
#pragma unroll
  for (int i = 0; i < 16; i++) acc[i] = 0.f;
  const float* stp = state + (size_t)bh * 4096 + s_o;
  for (int sp = 0; sp < 64; sp++) {
    float stv = stp[sp * 64];
#pragma unroll
    for (int i = 0; i < 16; i++) acc[i] += rr_s[wv * 16 + i][sp] * stv;
  }
#pragma unroll
  for (int i = 0; i < 16; i++) acc[i] *= wb_tab[h * TCH + t0 + wv * 16 + i];
  const float uh = u_vec[h];
  const int t4 = (tid >> 4) << 2, u4 = (tid & 15) << 2;
  for (int ub = 0; ub < 8; ub++) {
    const int u0 = ub * 64;
    for (int e = tid; e < 4096; e += 256) {
      int uu = e >> 6, s = e & 63;
      ks_s[uu][s] = bf2f(Kp[(size_t)(u0 + uu) * C_ + s]);
      vs_s[uu][s] = bf2f(Vp[(size_t)(u0 + uu) * C_ + s]);
    }
    __syncthreads();
    float a44[4][4];
#pragma unroll
    for (int i = 0; i < 4; i++)
#pragma unroll
      for (int j = 0; j < 4; j++) a44[i][j] = 0.f;
    for (int s4 = 0; s4 < 16; s4++) {
      float4 rr4[4], kk4[4];
#pragma unroll
      for (int q = 0; q < 4; q++) rr4[q] = *(const float4*)&rr_s[t4 + q][s4 * 4];
#pragma unroll
      for (int q = 0; q < 4; q++) kk4[q] = *(const float4*)&ks_s[u4 + q][s4 * 4];
#pragma unroll
      for (int i = 0; i < 4; i++)
#pragma unroll
        for (int j = 0; j < 4; j++)
          a44[i][j] += rr4[i].x * kk4[j].x + rr4[i].y * kk4[j].y +
                       rr4[i].z * kk4[j].z + rr4[i].w * kk4[j].w;
    }
#pragma unroll
    for (int i = 0; i < 4; i++) {
      int tl = t0 + t4 + i;
#pragma unroll
      for (int j = 0; j < 4; j++) {
        int ul = u0 + u4 + j;
        float f = (ul < tl) ? wb_tab[h * TCH + (tl - ul - 1)] : ((ul == tl) ? uh : 0.f);
        as_s[t4 + i][u4 + j] = a44[i][j] * f;
      }
    }
    __syncthreads();
    for (int ul4 = 0; ul4 < 16; ul4++) {
      float vvv[4];
#pragma unroll
      for (int q = 0; q < 4; q++) vvv[q] = vs_s[ul4 * 4 + q][s_o];
#pragma unroll
      for (int i = 0; i < 16; i++) {
        const float4 a4 = *(const float4*)&as_s[wv * 16 + i][ul4 * 4];
        acc[i] += a4.x * vvv[0] + a4.y * vvv[1] + a4.z * vvv[2] + a4.w * vvv[3];
      }
    }
    __syncthreads();
  }
  u16* xout = xa + rowbase * C_ + h * 64;
#pragma unroll
  for (int i = 0; i < 16; i++) xout[(size_t)(wv * 16 + i) * C_ + s_o] = f2bf(acc[i]);
}

// ---- attention: per-chunk state update --------------------------------------
__global__ __launch_bounds__(256) void att_state_k(const u16* __restrict__ Kk,
                                                   const u16* __restrict__ V,
                                                   float* __restrict__ state,
                                                   const float* __restrict__ wk_tab,
                                                   const float* __restrict__ wspow, int c0) {
  const int bh = blockIdx.x;
  const int b = bh >> 5, h = bh & 31;
  const int tid = threadIdx.x;
  const int u_o = tid & 63, wv = tid >> 6;
  const size_t chunkbase = (size_t)b * TT_ + (size_t)c0 * TCH;
  const u16* Kp = Kk + chunkbase * C_ + h * 64;
  const u16* Vp = V + chunkbase * C_ + h * 64;
  __shared__ alignas(16) float ks_s[64][68];
  __shared__ alignas(16) float vs_s[64][68];
  float acc[16];
#pragma unroll
  for (int i = 0; i < 16; i++) acc[i] = 0.f;
  for (int tb = 0; tb < 8; tb++) {
    for (int e = tid; e < 4096; e += 256) {
      int tt = e >> 6, s = e & 63;
      float wkv = wk_tab[h * TCH + tb * 64 + tt];
      ks_s[tt][s] = bf2f(Kp[(size_t)(tb * 64 + tt) * C_ + s]) * wkv;
      vs_s[tt][s] = bf2f(Vp[(size_t)(tb * 64 + tt) * C_ + s]);
    }
    __syncthreads();
    for (int tt = 0; tt < 64; tt++) {
      float vv = vs_s[tt][u_o];
#pragma unroll
      for (int q = 0; q < 4; q++) {
        const float4 k4 = *(const float4*)&ks_s[tt][wv * 16 + q * 4];
        acc[q * 4 + 0] += k4.x * vv;
        acc[q * 4 + 1] += k4.y * vv;
        acc[q * 4 + 2] += k4.z * vv;
        acc[q * 4 + 3] += k4.w * vv;
      }
    }
    __syncthreads();
  }
  const float wsv = wspow[h];
  float* st = state + (size_t)bh * 4096;
#pragma unroll
  for (int i = 0; i < 16; i++) {
    int s_i = wv * 16 + i;
    st[(size_t)s_i * 64 + u_o] = wsv * st[(size_t)s_i * 64 + u_o] + acc[i];
  }
}

// ---- per-head groupnorm: bf16 in, bf16 out ----------------------------------
__global__ __launch_bounds__(256) void gnorm(const u16* __restrict__ xa,
                                             const float* __restrict__ g,
                                             const float* __restrict__ b,
                                             u16* __restrict__ out) {
  const int row = blockIdx.x;
  const int lane = threadIdx.x & 63, wv = threadIdx.x >> 6;
  const u16* xp = xa + (size_t)row * C_;
  u16* op = out + (size_t)row * C_;
  for (int h = wv; h < 32; h += 4) {
    float v = bf2f(xp[h * 64 + lane]) * 0.125f;
    float s = v, s2 = v * v;
#pragma unroll
    for (int o = 32; o > 0; o >>= 1) { s += __shfl_down(s, o); s2 += __shfl_down(s2, o); }
    s = __shfl(s, 0); s2 = __shfl(s2, 0);
    float m = s * (1.f / 64.f), var = s2 * (1.f / 64.f) - m * m;
    float nv = (v - m) * rsqrtf(var + 1e-5f);
    op[h * 64 + lane] = f2bf(nv * g[h * 64 + lane] + b[h * 64 + lane]);
  }
}

// ---- launcher ---------------------------------------------------------------
extern "C" void kernel_launch(void* const* d_in, const int* in_sizes, int n_in,
                              void* d_out, int out_size, void* d_ws, size_t ws_size,
                              hipStream_t stream) {
  (void)in_sizes; (void)n_in; (void)out_size; (void)ws_size;
  const float* x    = (const float*)d_in[0];
  const float* ln1g = (const float*)d_in[1];
  const float* ln1b = (const float*)d_in[2];
  const float* ln2g = (const float*)d_in[3];
  const float* ln2b = (const float*)d_in[4];
  const float* amk  = (const float*)d_in[5];
  const float* amv  = (const float*)d_in[6];
  const float* amr  = (const float*)d_in[7];
  const float* tdec = (const float*)d_in[8];
  const float* tfaa = (const float*)d_in[9];
  const float* Wr   = (const float*)d_in[10];
  const float* Wk   = (const float*)d_in[11];
  const float* Wv   = (const float*)d_in[12];
  const float* Wo   = (const float*)d_in[13];
  const float* lnxg = (const float*)d_in[14];
  const float* lnxb = (const float*)d_in[15];
  const float* fmk  = (const float*)d_in[16];
  const float* fmr  = (const float*)d_in[17];
  const float* Wfk  = (const float*)d_in[18];
  const float* Wfr  = (const float*)d_in[19];
  const float* Wfv  = (const float*)d_in[20];

  char* ws = (char*)d_ws;
  const size_t MB = 1ull << 20;
  // Peak footprint: 224 MiB.
  u16* WFR = (u16*)(ws + 0 * MB);          // [0,8)    Wfr^T bf16
  u16* WR  = (u16*)(ws + 8 * MB);          // [8,16)
  u16* WK  = (u16*)(ws + 16 * MB);         // [16,24)
  u16* WV  = (u16*)(ws + 24 * MB);         // [24,32)
  u16* WO  = (u16*)(ws + 32 * MB);         // [32,40)
  u16* H1  = (u16*)(ws + 40 * MB);         // [40,72)  h1 -> xa -> h2
  u16* RB  = (u16*)(ws + 72 * MB);         // [72,104) r  -> xa_n -> sr
  u16* KB  = (u16*)(ws + 104 * MB);        // [104,136) k  \  -> x_mid f32 [104,168)
  u16* VB  = (u16*)(ws + 136 * MB);        // [136,168) v  /
  u16* FKH = (u16*)(ws + 0 * MB);          // [0,14)   Wfk half bf16 (FFN phase)
  u16* FVH = (u16*)(ws + 14 * MB);         // [14,28)  Wfv half bf16
  float* ST  = (float*)(ws + 28 * MB);     // [28,30)  state
  float* WBT = (float*)(ws + 30 * MB);                 // 64 KiB
  float* WKT = (float*)(ws + 30 * MB + 65536);         // 64 KiB
  float* WSP = (float*)(ws + 30 * MB + 131072);        // 128 B
  u16* KF  = (u16*)(ws + 168 * MB);        // [168,224) kf half bf16
  u16* XA  = H1;
  u16* XAN = RB;
  u16* H2  = H1;
  u16* SR  = RB;
  float* XMID = (float*)(ws + 104 * MB);

  dim3 blk(256);
  wcvt_t<<<dim3(64, 64), blk, 0, stream>>>(Wr, WR, 2048, 2048, 0);
  wcvt_t<<<dim3(64, 64), blk, 0, stream>>>(Wk, WK, 2048, 2048, 0);
  wcvt_t<<<dim3(64, 64), blk, 0, stream>>>(Wv, WV, 2048, 2048, 0);
  wcvt_t<<<dim3(64, 64), blk, 0, stream>>>(Wo, WO, 2048, 2048, 0);
  wcvt_t<<<dim3(64, 64), blk, 0, stream>>>(Wfr, WFR, 2048, 2048, 0);

  ln_rows<<<8192, blk, 0, stream>>>(x, ln1g, ln1b, H1);

  gemm_mix<0><<<dim3(64, 16), blk, 0, stream>>>(H1, amr, WR, RB, 2048);
  gemm_mix<0><<<dim3(64, 16), blk, 0, stream>>>(H1, amk, WK, KB, 2048);
  gemm_mix<0><<<dim3(64, 16), blk, 0, stream>>>(H1, amv, WV, VB, 2048);

  wtabs_k<<<32, 512, 0, stream>>>(tdec, WBT, WKT, WSP);
  zero_k<<<2048, blk, 0, stream>>>(ST);

  for (int c = 0; c < NCH; c++) {
    att_out_k<<<dim3(128, 8), blk, 0, stream>>>(RB, KB, VB, ST, WBT, tfaa, XA, c);
    att_state_k<<<128, blk, 0, stream>>>(KB, VB, ST, WKT, WSP, c);
  }

  gnorm<<<8192, blk, 0, stream>>>(XA, lnxg, lnxb, XAN);
  gemm_bt<1><<<dim3(64, 16), blk, 0, stream>>>(XAN, WO, XMID, x, nullptr, 8192, 2048, 2048);

  ln_rows<<<8192, blk, 0, stream>>>(XMID, ln2g, ln2b, H2);
  gemm_mix<3><<<dim3(64, 16), blk, 0, stream>>>(H2, fmr, WFR, SR, 2048);

  // FFN half 0
  wcvt_t<<<dim3(112, 64), blk, 0, stream>>>(Wfk, FKH, 2048, 7168, 0);
  gemm_mix<2><<<dim3(64, 28), blk, 0, stream>>>(H2, fmk, FKH, KF, 3584);
  wcvt_t<<<dim3(64, 112), blk, 0, stream>>>(Wfv, FVH, 3584, 2048, 0);
  gemm_bt<5><<<dim3(64, 16), blk, 0, stream>>>(KF, FVH, (float*)d_out, nullptr, nullptr, 8192, 2048, 3584);
  // FFN half 1
  wcvt_t<<<dim3(112, 64), blk, 0, stream>>>(Wfk, FKH, 2048, 7168, 3584);
  gemm_mix<2><<<dim3(64, 28), blk, 0, stream>>>(H2, fmk, FKH, KF, 3584);
  wcvt_t<<<dim3(64, 112), blk, 0, stream>>>(Wfv + (size_t)3584 * 2048, FVH, 3584, 2048, 0);
  gemm_bt<6><<<dim3(64, 16), blk, 0, stream>>>(KF, FVH, (float*)d_out, XMID, SR, 8192, 2048, 3584);
}

// Round 3
// 2784.377 us; speedup vs baseline: 1.0714x; 1.0714x over previous
//
#include <hip/hip_runtime.h>

#define B_   4
#define TT_  2048
#define C_   2048
#define H_   32
#define S_   64
#define DF_  7168
#define TCH  512
#define NCH  4

typedef unsigned short u16;
typedef __bf16 bf16x8 __attribute__((ext_vector_type(8)));
typedef float  f32x4  __attribute__((ext_vector_type(4)));

__device__ __forceinline__ u16 f2bf(float f) {
  unsigned u = __builtin_bit_cast(unsigned, f);
  u = u + 0x7FFFu + ((u >> 16) & 1u);
  return (u16)(u >> 16);
}
__device__ __forceinline__ float bf2f(u16 v) {
  unsigned u = ((unsigned)v) << 16;
  return __builtin_bit_cast(float, u);
}

#define GLOAD16(g, l) __builtin_amdgcn_global_load_lds( \
    (const __attribute__((address_space(1))) void*)(g), \
    (__attribute__((address_space(3))) void*)(l), 16, 0, 0)

// ---- weight convert+transpose: W (K,Nfull) f32 cols [n0off,...) -> Wt (ncols,K) bf16
__global__ __launch_bounds__(256) void wcvt_t(const float* __restrict__ W,
                                              u16* __restrict__ Wt, int K, int Nfull,
                                              int n0off) {
  __shared__ alignas(16) float tile[32][33];
  int nloc = blockIdx.x * 32, k0 = blockIdx.y * 32;
  int tx = threadIdx.x & 31, ty = threadIdx.x >> 5;
  for (int r = ty; r < 32; r += 8)
    tile[r][tx] = W[(size_t)(k0 + r) * Nfull + n0off + nloc + tx];
  __syncthreads();
  for (int r = ty; r < 32; r += 8)
    Wt[(size_t)(nloc + r) * K + k0 + tx] = f2bf(tile[tx][r]);
}

// ---- layernorm over C=2048, f32 in -> bf16 out ------------------------------
__global__ __launch_bounds__(256) void ln_rows(const float* __restrict__ x,
                                               const float* __restrict__ g,
                                               const float* __restrict__ b,
                                               u16* __restrict__ out) {
  const int row = blockIdx.x;
  const float* xr = x + (size_t)row * C_;
  float v[8]; float s = 0.f, s2 = 0.f;
#pragma unroll
  for (int i = 0; i < 8; i++) { v[i] = xr[threadIdx.x + i * 256]; s += v[i]; s2 += v[i] * v[i]; }
#pragma unroll
  for (int o = 32; o > 0; o >>= 1) { s += __shfl_down(s, o); s2 += __shfl_down(s2, o); }
  __shared__ float rs[4], rs2[4];
  int wid = threadIdx.x >> 6, lane = threadIdx.x & 63;
  if (lane == 0) { rs[wid] = s; rs2[wid] = s2; }
  __syncthreads();
  s = rs[0] + rs[1] + rs[2] + rs[3];
  s2 = rs2[0] + rs2[1] + rs2[2] + rs2[3];
  float m = s * (1.f / C_);
  float var = s2 * (1.f / C_) - m * m;
  float inv = rsqrtf(var + 1e-5f);
  u16* orow = out + (size_t)row * C_;
#pragma unroll
  for (int i = 0; i < 8; i++) {
    int c = threadIdx.x + i * 256;
    orow[c] = f2bf((v[i] - m) * inv * g[c] + b[c]);
  }
}

// ---- decay tables -----------------------------------------------------------
__global__ void wtabs_k(const float* __restrict__ td, float* __restrict__ wb_tab,
                        float* __restrict__ wk_tab, float* __restrict__ wspow) {
  int h = blockIdx.x, t = threadIdx.x;
  float w = expf(-expf(td[h]));
  wb_tab[h * TCH + t] = powf(w, (float)t);
  wk_tab[h * TCH + t] = powf(w, (float)(TCH - 1 - t));
  if (t == 0) wspow[h] = powf(w, (float)TCH);
}

__global__ void zero_k(float* __restrict__ p) {
  p[(size_t)blockIdx.x * 256 + threadIdx.x] = 0.f;
}

// ---- standalone time-shift mixes (bf16 h, 8 elems/thread) -------------------
__device__ __forceinline__ void mix_body(const u16* cur, const u16* prev, bool hasp,
                                         const float* mc, u16* dst) {
  ushort4 c0 = *(const ushort4*)cur;
  ushort4 c1 = *(const ushort4*)(cur + 4);
  ushort4 p0 = {0, 0, 0, 0}, p1 = {0, 0, 0, 0};
  if (hasp) { p0 = *(const ushort4*)prev; p1 = *(const ushort4*)(prev + 4); }
  float4 mA = *(const float4*)mc;
  float4 mB = *(const float4*)(mc + 4);
  ushort4 r0, r1;
  r0.x = f2bf(bf2f(c0.x) * mA.x + bf2f(p0.x) * (1.f - mA.x));
  r0.y = f2bf(bf2f(c0.y) * mA.y + bf2f(p0.y) * (1.f - mA.y));
  r0.z = f2bf(bf2f(c0.z) * mA.z + bf2f(p0.z) * (1.f - mA.z));
  r0.w = f2bf(bf2f(c0.w) * mA.w + bf2f(p0.w) * (1.f - mA.w));
  r1.x = f2bf(bf2f(c1.x) * mB.x + bf2f(p1.x) * (1.f - mB.x));
  r1.y = f2bf(bf2f(c1.y) * mB.y + bf2f(p1.y) * (1.f - mB.y));
  r1.z = f2bf(bf2f(c1.z) * mB.z + bf2f(p1.z) * (1.f - mB.z));
  r1.w = f2bf(bf2f(c1.w) * mB.w + bf2f(p1.w) * (1.f - mB.w));
  *(ushort4*)dst = r0;
  *(ushort4*)(dst + 4) = r1;
}

__global__ __launch_bounds__(256) void mix3(const u16* __restrict__ h,
                                            const float* __restrict__ mk,
                                            const float* __restrict__ mv,
                                            const float* __restrict__ mr,
                                            u16* __restrict__ xk, u16* __restrict__ xv,
                                            u16* __restrict__ xr) {
  size_t i8 = (size_t)blockIdx.x * 256 + threadIdx.x;
  size_t off = i8 * 8;
  int c0 = (int)(off & (C_ - 1));
  int row = (int)(i8 >> 8);
  bool hasp = (row & (TT_ - 1)) != 0;
  const u16* cur = h + off;
  const u16* prev = cur - C_;
  mix_body(cur, prev, hasp, mk + c0, xk + off);
  mix_body(cur, prev, hasp, mv + c0, xv + off);
  mix_body(cur, prev, hasp, mr + c0, xr + off);
}

__global__ __launch_bounds__(256) void mix2(const u16* __restrict__ h,
                                            const float* __restrict__ mk,
                                            const float* __restrict__ mr,
                                            u16* __restrict__ xk, u16* __restrict__ xr) {
  size_t i8 = (size_t)blockIdx.x * 256 + threadIdx.x;
  size_t off = i8 * 8;
  int c0 = (int)(off & (C_ - 1));
  int row = (int)(i8 >> 8);
  bool hasp = (row & (TT_ - 1)) != 0;
  const u16* cur = h + off;
  const u16* prev = cur - C_;
  mix_body(cur, prev, hasp, mk + c0, xk + off);
  mix_body(cur, prev, hasp, mr + c0, xr + off);
}

// ---- plain GEMM (m97 structure + XCD swizzle): C(M,N) = A(M,K[lda]) * Bt(N,K[ldb])^T
// EPI: 0 = bf16 store ; 1 = f32 acc+res ; 2 = bf16 relu^2 ; 5 = f32 raw ;
//      7 = f32 out += acc ; 8 = f32 out = res + sigmoid(acc)*out
template <int EPI>
__global__ __launch_bounds__(256) void gemm_bt(const u16* __restrict__ A,
                                               const u16* __restrict__ Bt,
                                               void* __restrict__ Cv,
                                               const float* __restrict__ res,
                                               int N, int K, int lda, int ldb, int gy) {
  __shared__ alignas(16) u16 As[128 * 32];
  __shared__ alignas(16) u16 Bs[128 * 32];
  // XCD-aware bijective swizzle (nwg % 8 == 0 for all our grids)
  const int nwg = gridDim.x;
  const int qq = nwg >> 3;
  const int wg = (int)(blockIdx.x & 7) * qq + (int)(blockIdx.x >> 3);
  const int bx = wg / gy, by = wg % gy;
  const int tid = threadIdx.x;
  const int wid = tid >> 6, lane = tid & 63;
  const int fr = lane & 15, fq = lane >> 4;
  const int m0 = bx * 128, n0 = by * 128;
  const int wm = (wid >> 1) * 64, wn = (wid & 1) * 64;
  const int rowS = tid >> 2, colS = (tid & 3) * 8;
  const u16* Ag = A + (size_t)(m0 + rowS) * lda + colS;
  const u16* Bg = Bt + (size_t)(n0 + rowS) * ldb + colS;
  char* ldsA = (char*)As + wid * 1024;
  char* ldsB = (char*)Bs + wid * 1024;
  f32x4 acc[4][4];
#pragma unroll
  for (int i = 0; i < 4; i++)
#pragma unroll
    for (int j = 0; j < 4; j++) acc[i][j] = (f32x4){0.f, 0.f, 0.f, 0.f};

  for (int k0 = 0; k0 < K; k0 += 32) {
    GLOAD16(Ag + k0, ldsA);
    GLOAD16(Ag + k0 + (size_t)64 * lda, ldsA + 4096);
    GLOAD16(Bg + k0, ldsB);
    GLOAD16(Bg + k0 + (size_t)64 * ldb, ldsB + 4096);
    __syncthreads();
    bf16x8 av[4], bv[4];
#pragma unroll
    for (int m = 0; m < 4; m++) av[m] = *(const bf16x8*)&As[(wm + m * 16 + fr) * 32 + fq * 8];
#pragma unroll
    for (int n = 0; n < 4; n++) bv[n] = *(const bf16x8*)&Bs[(wn + n * 16 + fr) * 32 + fq * 8];
#pragma unroll
    for (int m = 0; m < 4; m++)
#pragma unroll
      for (int n = 0; n < 4; n++)
        acc[m][n] = __builtin_amdgcn_mfma_f32_16x16x32_bf16(av[m], bv[n], acc[m][n], 0, 0, 0);
    __syncthreads();
  }
#pragma unroll
  for (int m = 0; m < 4; m++)
#pragma unroll
    for (int n = 0; n < 4; n++)
#pragma unroll
      for (int j = 0; j < 4; j++) {
        int row = m0 + wm + m * 16 + fq * 4 + j;
        int col = n0 + wn + n * 16 + fr;
        size_t idx = (size_t)row * N + col;
        float v = acc[m][n][j];
        if (EPI == 0) ((u16*)Cv)[idx] = f2bf(v);
        else if (EPI == 1) ((float*)Cv)[idx] = v + res[idx];
        else if (EPI == 2) { float r = v > 0.f ? v : 0.f; ((u16*)Cv)[idx] = f2bf(r * r); }
        else if (EPI == 5) ((float*)Cv)[idx] = v;
        else if (EPI == 7) ((float*)Cv)[idx] += v;
        else {
          float pv = ((float*)Cv)[idx];
          float sg = 1.f / (1.f + expf(-v));
          ((float*)Cv)[idx] = res[idx] + sg * pv;
        }
      }
}

// ---- attention: per-chunk output --------------------------------------------
__global__ __launch_bounds__(256) void att_out_k(const u16* __restrict__ R,
                                                 const u16* __restrict__ Kk,
                                                 const u16* __restrict__ V,
                                                 const float* __restrict__ state,
                                                 const float* __restrict__ wb_tab,
                                                 const float* __restrict__ u_vec,
                                                 u16* __restrict__ xa, int c0) {
  const int bh = blockIdx.x, tile = blockIdx.y;
  const int b = bh >> 5, h = bh & 31;
  const int tid = threadIdx.x;
  const int t0 = tile * 64;
  const size_t rowbase = (size_t)b * TT_ + (size_t)c0 * TCH + t0;
  const size_t chunkbase = (size_t)b * TT_ + (size_t)c0 * TCH;
  const u16* Rp = R + rowbase * C_ + h * 64;
  const u16* Kp = Kk + chunkbase * C_ + h * 64;
  const u16* Vp = V + chunkbase * C_ + h * 64;
  __shared__ alignas(16) float rr_s[64][68];
  __shared__ alignas(16) float ks_s[64][68];
  __shared__ alignas(16) float vs_s[64][68];
  __shared__ alignas(16) float as_s[64][68];
  for (int e = tid; e < 4096; e += 256) {
    int t = e >> 6, s = e & 63;
    rr_s[t][s] = bf2f(Rp[(size_t)t * C_ + s]);
  }
  __syncthreads();
  const int s_o = tid & 63, wv = tid >> 6;
  float acc[16];
#pragma unroll
  for (int i = 0; i < 16; i++) acc[i] = 0.f;
  const float* stp = state + (size_t)bh * 4096 + s_o;
  for (int sp = 0; sp < 64; sp++) {
    float stv = stp[sp * 64];
#pragma unroll
    for (int i = 0; i < 16; i++) acc[i] += rr_s[wv * 16 + i][sp] * stv;
  }
#pragma unroll
  for (int i = 0; i < 16; i++) acc[i] *= wb_tab[h * TCH + t0 + wv * 16 + i];
  const float uh = u_vec[h];
  const int t4 = (tid >> 4) << 2, u4 = (tid & 15) << 2;
  for (int ub = 0; ub < 8; ub++) {
    const int u0 = ub * 64;
    for (int e = tid; e < 4096; e += 256) {
      int uu = e >> 6, s = e & 63;
      ks_s[uu][s] = bf2f(Kp[(size_t)(u0 + uu) * C_ + s]);
      vs_s[uu][s] = bf2f(Vp[(size_t)(u0 + uu) * C_ + s]);
    }
    __syncthreads();
    float a44[4][4];
#pragma unroll
    for (int i = 0; i < 4; i++)
#pragma unroll
      for (int j = 0; j < 4; j++) a44[i][j] = 0.f;
    for (int s4 = 0; s4 < 16; s4++) {
      float4 rr4[4], kk4[4];
#pragma unroll
      for (int q = 0; q < 4; q++) rr4[q] = *(const float4*)&rr_s[t4 + q][s4 * 4];
#pragma unroll
      for (int q = 0; q < 4; q++) kk4[q] = *(const float4*)&ks_s[u4 + q][s4 * 4];
#pragma unroll
      for (int i = 0; i < 4; i++)
#pragma unroll
        for (int j = 0; j < 4; j++)
          a44[i][j] += rr4[i].x * kk4[j].x + rr4[i].y * kk4[j].y +
                       rr4[i].z * kk4[j].z + rr4[i].w * kk4[j].w;
    }
#pragma unroll
    for (int i = 0; i < 4; i++) {
      int tl = t0 + t4 + i;
#pragma unroll
      for (int j = 0; j < 4; j++) {
        int ul = u0 + u4 + j;
        float f = (ul < tl) ? wb_tab[h * TCH + (tl - ul - 1)] : ((ul == tl) ? uh : 0.f);
        as_s[t4 + i][u4 + j] = a44[i][j] * f;
      }
    }
    __syncthreads();
    for (int ul4 = 0; ul4 < 16; ul4++) {
      float vvv[4];
#pragma unroll
      for (int q = 0; q < 4; q++) vvv[q] = vs_s[ul4 * 4 + q][s_o];
#pragma unroll
      for (int i = 0; i < 16; i++) {
        const float4 a4 = *(const float4*)&as_s[wv * 16 + i][ul4 * 4];
        acc[i] += a4.x * vvv[0] + a4.y * vvv[1] + a4.z * vvv[2] + a4.w * vvv[3];
      }
    }
    __syncthreads();
  }
  u16* xout = xa + rowbase * C_ + h * 64;
#pragma unroll
  for (int i = 0; i < 16; i++) xout[(size_t)(wv * 16 + i) * C_ + s_o] = f2bf(acc[i]);
}

// ---- attention: per-chunk state update --------------------------------------
__global__ __launch_bounds__(256) void att_state_k(const u16* __restrict__ Kk,
                                                   const u16* __restrict__ V,
                                                   float* __restrict__ state,
                                                   const float* __restrict__ wk_tab,
                                                   const float* __restrict__ wspow, int c0) {
  const int bh = blockIdx.x;
  const int b = bh >> 5, h = bh & 31;
  const int tid = threadIdx.x;
  const int u_o = tid & 63, wv = tid >> 6;
  const size_t chunkbase = (size_t)b * TT_ + (size_t)c0 * TCH;
  const u16* Kp = Kk + chunkbase * C_ + h * 64;
  const u16* Vp = V + chunkbase * C_ + h * 64;
  __shared__ alignas(16) float ks_s[64][68];
  __shared__ alignas(16) float vs_s[64][68];
  float acc[16];
#pragma unroll
  for (int i = 0; i < 16; i++) acc[i] = 0.f;
  for (int tb = 0; tb < 8; tb++) {
    for (int e = tid; e < 4096; e += 256) {
      int tt = e >> 6, s = e & 63;
      float wkv = wk_tab[h * TCH + tb * 64 + tt];
      ks_s[tt][s] = bf2f(Kp[(size_t)(tb * 64 + tt) * C_ + s]) * wkv;
      vs_s[tt][s] = bf2f(Vp[(size_t)(tb * 64 + tt) * C_ + s]);
    }
    __syncthreads();
    for (int tt = 0; tt < 64; tt++) {
      float vv = vs_s[tt][u_o];
#pragma unroll
      for (int q = 0; q < 4; q++) {
        const float4 k4 = *(const float4*)&ks_s[tt][wv * 16 + q * 4];
        acc[q * 4 + 0] += k4.x * vv;
        acc[q * 4 + 1] += k4.y * vv;
        acc[q * 4 + 2] += k4.z * vv;
        acc[q * 4 + 3] += k4.w * vv;
      }
    }
    __syncthreads();
  }
  const float wsv = wspow[h];
  float* st = state + (size_t)bh * 4096;
#pragma unroll
  for (int i = 0; i < 16; i++) {
    int s_i = wv * 16 + i;
    st[(size_t)s_i * 64 + u_o] = wsv * st[(size_t)s_i * 64 + u_o] + acc[i];
  }
}

// ---- per-head groupnorm: bf16 in, bf16 out ----------------------------------
__global__ __launch_bounds__(256) void gnorm(const u16* __restrict__ xa,
                                             const float* __restrict__ g,
                                             const float* __restrict__ b,
                                             u16* __restrict__ out) {
  const int row = blockIdx.x;
  const int lane = threadIdx.x & 63, wv = threadIdx.x >> 6;
  const u16* xp = xa + (size_t)row * C_;
  u16* op = out + (size_t)row * C_;
  for (int h = wv; h < 32; h += 4) {
    float v = bf2f(xp[h * 64 + lane]) * 0.125f;
    float s = v, s2 = v * v;
#pragma unroll
    for (int o = 32; o > 0; o >>= 1) { s += __shfl_down(s, o); s2 += __shfl_down(s2, o); }
    s = __shfl(s, 0); s2 = __shfl(s2, 0);
    float m = s * (1.f / 64.f), var = s2 * (1.f / 64.f) - m * m;
    float nv = (v - m) * rsqrtf(var + 1e-5f);
    op[h * 64 + lane] = f2bf(nv * g[h * 64 + lane] + b[h * 64 + lane]);
  }
}

// ---- launcher ---------------------------------------------------------------
extern "C" void kernel_launch(void* const* d_in, const int* in_sizes, int n_in,
                              void* d_out, int out_size, void* d_ws, size_t ws_size,
                              hipStream_t stream) {
  (void)in_sizes; (void)n_in; (void)out_size; (void)ws_size;
  const float* x    = (const float*)d_in[0];
  const float* ln1g = (const float*)d_in[1];
  const float* ln1b = (const float*)d_in[2];
  const float* ln2g = (const float*)d_in[3];
  const float* ln2b = (const float*)d_in[4];
  const float* amk  = (const float*)d_in[5];
  const float* amv  = (const float*)d_in[6];
  const float* amr  = (const float*)d_in[7];
  const float* tdec = (const float*)d_in[8];
  const float* tfaa = (const float*)d_in[9];
  const float* Wr   = (const float*)d_in[10];
  const float* Wk   = (const float*)d_in[11];
  const float* Wv   = (const float*)d_in[12];
  const float* Wo   = (const float*)d_in[13];
  const float* lnxg = (const float*)d_in[14];
  const float* lnxb = (const float*)d_in[15];
  const float* fmk  = (const float*)d_in[16];
  const float* fmr  = (const float*)d_in[17];
  const float* Wfk  = (const float*)d_in[18];
  const float* Wfr  = (const float*)d_in[19];
  const float* Wfv  = (const float*)d_in[20];

  char* ws = (char*)d_ws;
  const size_t MB = 1ull << 20;
  // Peak footprint ~227 MiB (static overlay map; round-2's 224 MiB proved safe).
  u16* WR  = (u16*)(ws + 0 * MB);     // dead after r-GEMM
  u16* WK  = (u16*)(ws + 8 * MB);     // dead after k-GEMM
  u16* WV  = (u16*)(ws + 16 * MB);    // dead after v-GEMM
  u16* WO  = (u16*)(ws + 24 * MB);    // dead after x_mid
  u16* WFR = (u16*)(ws + 32 * MB);    // live until final GEMM
  u16* WFK = (u16*)(ws + 40 * MB);    // (7168,2048) bf16, 28 MB
  u16* WFV = (u16*)(ws + 68 * MB);    // (2048,7168) bf16, 28 MB
  u16* H1  = (u16*)(ws + 96 * MB);    // h1 -> r -> xan -> xr2
  u16* XR  = (u16*)(ws + 128 * MB);   // xr -> k -> x_mid(f32, 128-192)
  u16* XK  = (u16*)(ws + 160 * MB);   // xk -> v
  u16* XV  = (u16*)(ws + 192 * MB);   // xv -> xa -> h2 -> kf_q
  float* ST  = (float*)(ws + 224 * MB);           // 2 MB state
  float* WBT = (float*)(ws + 226 * MB);           // 64 KB
  float* WKT = (float*)(ws + 226 * MB + 65536);   // 64 KB
  float* WSP = (float*)(ws + 226 * MB + 131072);  // 128 B
  u16* RB   = H1;
  u16* KB   = XR;
  u16* VB   = XK;
  u16* XA   = XV;
  u16* XAN  = H1;
  float* XMID = (float*)XR;           // 64 MB f32 (128-192)
  u16* H2   = XV;
  u16* XK2  = WR;                     // 0-32 (W{R,K,V,O} dead by then)
  u16* XR2  = H1;
  u16* KFQ  = XV;                     // 28 MB quarter buffer
  float* OUT = (float*)d_out;

  dim3 blk(256);
  // ---- weight conversions (all upfront) ----
  wcvt_t<<<dim3(64, 64), blk, 0, stream>>>(Wr, WR, 2048, 2048, 0);
  wcvt_t<<<dim3(64, 64), blk, 0, stream>>>(Wk, WK, 2048, 2048, 0);
  wcvt_t<<<dim3(64, 64), blk, 0, stream>>>(Wv, WV, 2048, 2048, 0);
  wcvt_t<<<dim3(64, 64), blk, 0, stream>>>(Wo, WO, 2048, 2048, 0);
  wcvt_t<<<dim3(64, 64), blk, 0, stream>>>(Wfr, WFR, 2048, 2048, 0);
  wcvt_t<<<dim3(224, 64), blk, 0, stream>>>(Wfk, WFK, 2048, 7168, 0);
  wcvt_t<<<dim3(64, 224), blk, 0, stream>>>(Wfv, WFV, 7168, 2048, 0);

  // ---- attention branch ----
  ln_rows<<<8192, blk, 0, stream>>>(x, ln1g, ln1b, H1);
  mix3<<<8192, blk, 0, stream>>>(H1, amk, amv, amr, XK, XV, XR);
  gemm_bt<0><<<1024, blk, 0, stream>>>(XR, WR, RB, nullptr, 2048, 2048, 2048, 2048, 16);
  gemm_bt<0><<<1024, blk, 0, stream>>>(XK, WK, KB, nullptr, 2048, 2048, 2048, 2048, 16);
  gemm_bt<0><<<1024, blk, 0, stream>>>(XV, WV, VB, nullptr, 2048, 2048, 2048, 2048, 16);

  wtabs_k<<<32, 512, 0, stream>>>(tdec, WBT, WKT, WSP);
  zero_k<<<2048, blk, 0, stream>>>(ST);
  for (int c = 0; c < NCH; c++) {
    att_out_k<<<dim3(128, 8), blk, 0, stream>>>(RB, KB, VB, ST, WBT, tfaa, XA, c);
    att_state_k<<<128, blk, 0, stream>>>(KB, VB, ST, WKT, WSP, c);
  }

  gnorm<<<8192, blk, 0, stream>>>(XA, lnxg, lnxb, XAN);
  gemm_bt<1><<<1024, blk, 0, stream>>>(XAN, WO, XMID, x, 2048, 2048, 2048, 2048, 16);

  // ---- FFN branch ----
  ln_rows<<<8192, blk, 0, stream>>>(XMID, ln2g, ln2b, H2);
  mix2<<<8192, blk, 0, stream>>>(H2, fmk, fmr, XK2, XR2);

  for (int q = 0; q < 4; q++) {
    const u16* wfk_q = WFK + (size_t)q * 1792 * 2048;
    const u16* wfv_q = WFV + (size_t)q * 1792;
    gemm_bt<2><<<896, blk, 0, stream>>>(XK2, wfk_q, KFQ, nullptr, 1792, 2048, 2048, 2048, 14);
    if (q == 0)
      gemm_bt<5><<<1024, blk, 0, stream>>>(KFQ, wfv_q, OUT, nullptr, 2048, 1792, 1792, 7168, 16);
    else
      gemm_bt<7><<<1024, blk, 0, stream>>>(KFQ, wfv_q, OUT, nullptr, 2048, 1792, 1792, 7168, 16);
  }
  // final: out = x_mid + sigmoid(xr2 @ Wfr^T) * out
  gemm_bt<8><<<1024, blk, 0, stream>>>(XR2, WFR, OUT, XMID, 2048, 2048, 2048, 2048, 16);
}

// Round 4
// 1980.875 us; speedup vs baseline: 1.5060x; 1.4056x over previous
//
#include <hip/hip_runtime.h>

#define B_   4
#define TT_  2048
#define C_   2048
#define H_   32
#define S_   64
#define DF_  7168
#define TCH  512
#define NCH  4

typedef unsigned short u16;
typedef __bf16 bf16x8 __attribute__((ext_vector_type(8)));
typedef float  f32x4  __attribute__((ext_vector_type(4)));

__device__ __forceinline__ u16 f2bf(float f) {
  unsigned u = __builtin_bit_cast(unsigned, f);
  u = u + 0x7FFFu + ((u >> 16) & 1u);
  return (u16)(u >> 16);
}
__device__ __forceinline__ float bf2f(u16 v) {
  unsigned u = ((unsigned)v) << 16;
  return __builtin_bit_cast(float, u);
}

#define GLOAD16(g, l) __builtin_amdgcn_global_load_lds( \
    (const __attribute__((address_space(1))) void*)(g), \
    (__attribute__((address_space(3))) void*)(l), 16, 0, 0)

// ---- weight convert+transpose ----------------------------------------------
__global__ __launch_bounds__(256) void wcvt_t(const float* __restrict__ W,
                                              u16* __restrict__ Wt, int K, int Nfull,
                                              int n0off) {
  __shared__ alignas(16) float tile[32][33];
  int nloc = blockIdx.x * 32, k0 = blockIdx.y * 32;
  int tx = threadIdx.x & 31, ty = threadIdx.x >> 5;
  for (int r = ty; r < 32; r += 8)
    tile[r][tx] = W[(size_t)(k0 + r) * Nfull + n0off + nloc + tx];
  __syncthreads();
  for (int r = ty; r < 32; r += 8)
    Wt[(size_t)(nloc + r) * K + k0 + tx] = f2bf(tile[tx][r]);
}

// ---- layernorm over C=2048, f32 in -> bf16 out ------------------------------
__global__ __launch_bounds__(256) void ln_rows(const float* __restrict__ x,
                                               const float* __restrict__ g,
                                               const float* __restrict__ b,
                                               u16* __restrict__ out) {
  const int row = blockIdx.x;
  const float* xr = x + (size_t)row * C_;
  float v[8]; float s = 0.f, s2 = 0.f;
#pragma unroll
  for (int i = 0; i < 8; i++) { v[i] = xr[threadIdx.x + i * 256]; s += v[i]; s2 += v[i] * v[i]; }
#pragma unroll
  for (int o = 32; o > 0; o >>= 1) { s += __shfl_down(s, o); s2 += __shfl_down(s2, o); }
  __shared__ float rs[4], rs2[4];
  int wid = threadIdx.x >> 6, lane = threadIdx.x & 63;
  if (lane == 0) { rs[wid] = s; rs2[wid] = s2; }
  __syncthreads();
  s = rs[0] + rs[1] + rs[2] + rs[3];
  s2 = rs2[0] + rs2[1] + rs2[2] + rs2[3];
  float m = s * (1.f / C_);
  float var = s2 * (1.f / C_) - m * m;
  float inv = rsqrtf(var + 1e-5f);
  u16* orow = out + (size_t)row * C_;
#pragma unroll
  for (int i = 0; i < 8; i++) {
    int c = threadIdx.x + i * 256;
    orow[c] = f2bf((v[i] - m) * inv * g[c] + b[c]);
  }
}

// ---- decay tables -----------------------------------------------------------
__global__ void wtabs_k(const float* __restrict__ td, float* __restrict__ wb_tab,
                        float* __restrict__ wk_tab, float* __restrict__ wspow) {
  int h = blockIdx.x, t = threadIdx.x;
  float w = expf(-expf(td[h]));
  wb_tab[h * TCH + t] = powf(w, (float)t);
  wk_tab[h * TCH + t] = powf(w, (float)(TCH - 1 - t));
  if (t == 0) wspow[h] = powf(w, (float)TCH);
}

// ---- time-shift mixes -------------------------------------------------------
__device__ __forceinline__ void mix_body(const u16* cur, const u16* prev, bool hasp,
                                         const float* mc, u16* dst) {
  ushort4 c0 = *(const ushort4*)cur;
  ushort4 c1 = *(const ushort4*)(cur + 4);
  ushort4 p0 = {0, 0, 0, 0}, p1 = {0, 0, 0, 0};
  if (hasp) { p0 = *(const ushort4*)prev; p1 = *(const ushort4*)(prev + 4); }
  float4 mA = *(const float4*)mc;
  float4 mB = *(const float4*)(mc + 4);
  ushort4 r0, r1;
  r0.x = f2bf(bf2f(c0.x) * mA.x + bf2f(p0.x) * (1.f - mA.x));
  r0.y = f2bf(bf2f(c0.y) * mA.y + bf2f(p0.y) * (1.f - mA.y));
  r0.z = f2bf(bf2f(c0.z) * mA.z + bf2f(p0.z) * (1.f - mA.z));
  r0.w = f2bf(bf2f(c0.w) * mA.w + bf2f(p0.w) * (1.f - mA.w));
  r1.x = f2bf(bf2f(c1.x) * mB.x + bf2f(p1.x) * (1.f - mB.x));
  r1.y = f2bf(bf2f(c1.y) * mB.y + bf2f(p1.y) * (1.f - mB.y));
  r1.z = f2bf(bf2f(c1.z) * mB.z + bf2f(p1.z) * (1.f - mB.z));
  r1.w = f2bf(bf2f(c1.w) * mB.w + bf2f(p1.w) * (1.f - mB.w));
  *(ushort4*)dst = r0;
  *(ushort4*)(dst + 4) = r1;
}

__global__ __launch_bounds__(256) void mix3(const u16* __restrict__ h,
                                            const float* __restrict__ mk,
                                            const float* __restrict__ mv,
                                            const float* __restrict__ mr,
                                            u16* __restrict__ xk, u16* __restrict__ xv,
                                            u16* __restrict__ xr) {
  size_t i8 = (size_t)blockIdx.x * 256 + threadIdx.x;
  size_t off = i8 * 8;
  int c0 = (int)(off & (C_ - 1));
  int row = (int)(i8 >> 8);
  bool hasp = (row & (TT_ - 1)) != 0;
  const u16* cur = h + off;
  const u16* prev = cur - C_;
  mix_body(cur, prev, hasp, mk + c0, xk + off);
  mix_body(cur, prev, hasp, mv + c0, xv + off);
  mix_body(cur, prev, hasp, mr + c0, xr + off);
}

__global__ __launch_bounds__(256) void mix2(const u16* __restrict__ h,
                                            const float* __restrict__ mk,
                                            const float* __restrict__ mr,
                                            u16* __restrict__ xk, u16* __restrict__ xr) {
  size_t i8 = (size_t)blockIdx.x * 256 + threadIdx.x;
  size_t off = i8 * 8;
  int c0 = (int)(off & (C_ - 1));
  int row = (int)(i8 >> 8);
  bool hasp = (row & (TT_ - 1)) != 0;
  const u16* cur = h + off;
  const u16* prev = cur - C_;
  mix_body(cur, prev, hasp, mk + c0, xk + off);
  mix_body(cur, prev, hasp, mr + c0, xr + off);
}

// ---- plain GEMM (m97 structure + XCD swizzle) -------------------------------
template <int EPI>
__global__ __launch_bounds__(256) void gemm_bt(const u16* __restrict__ A,
                                               const u16* __restrict__ Bt,
                                               void* __restrict__ Cv,
                                               const float* __restrict__ res,
                                               int N, int K, int lda, int ldb, int gy) {
  __shared__ alignas(16) u16 As[128 * 32];
  __shared__ alignas(16) u16 Bs[128 * 32];
  const int nwg = gridDim.x;
  const int qq = nwg >> 3;
  const int wg = (int)(blockIdx.x & 7) * qq + (int)(blockIdx.x >> 3);
  const int bx = wg / gy, by = wg % gy;
  const int tid = threadIdx.x;
  const int wid = tid >> 6, lane = tid & 63;
  const int fr = lane & 15, fq = lane >> 4;
  const int m0 = bx * 128, n0 = by * 128;
  const int wm = (wid >> 1) * 64, wn = (wid & 1) * 64;
  const int rowS = tid >> 2, colS = (tid & 3) * 8;
  const u16* Ag = A + (size_t)(m0 + rowS) * lda + colS;
  const u16* Bg = Bt + (size_t)(n0 + rowS) * ldb + colS;
  char* ldsA = (char*)As + wid * 1024;
  char* ldsB = (char*)Bs + wid * 1024;
  f32x4 acc[4][4];
#pragma unroll
  for (int i = 0; i < 4; i++)
#pragma unroll
    for (int j = 0; j < 4; j++) acc[i][j] = (f32x4){0.f, 0.f, 0.f, 0.f};

  for (int k0 = 0; k0 < K; k0 += 32) {
    GLOAD16(Ag + k0, ldsA);
    GLOAD16(Ag + k0 + (size_t)64 * lda, ldsA + 4096);
    GLOAD16(Bg + k0, ldsB);
    GLOAD16(Bg + k0 + (size_t)64 * ldb, ldsB + 4096);
    __syncthreads();
    bf16x8 av[4], bv[4];
#pragma unroll
    for (int m = 0; m < 4; m++) av[m] = *(const bf16x8*)&As[(wm + m * 16 + fr) * 32 + fq * 8];
#pragma unroll
    for (int n = 0; n < 4; n++) bv[n] = *(const bf16x8*)&Bs[(wn + n * 16 + fr) * 32 + fq * 8];
#pragma unroll
    for (int m = 0; m < 4; m++)
#pragma unroll
      for (int n = 0; n < 4; n++)
        acc[m][n] = __builtin_amdgcn_mfma_f32_16x16x32_bf16(av[m], bv[n], acc[m][n], 0, 0, 0);
    __syncthreads();
  }
#pragma unroll
  for (int m = 0; m < 4; m++)
#pragma unroll
    for (int n = 0; n < 4; n++)
#pragma unroll
      for (int j = 0; j < 4; j++) {
        int row = m0 + wm + m * 16 + fq * 4 + j;
        int col = n0 + wn + n * 16 + fr;
        size_t idx = (size_t)row * N + col;
        float v = acc[m][n][j];
        if (EPI == 0) ((u16*)Cv)[idx] = f2bf(v);
        else if (EPI == 1) ((float*)Cv)[idx] = v + res[idx];
        else if (EPI == 2) { float r = v > 0.f ? v : 0.f; ((u16*)Cv)[idx] = f2bf(r * r); }
        else if (EPI == 5) ((float*)Cv)[idx] = v;
        else if (EPI == 7) ((float*)Cv)[idx] += v;
        else {
          float pv = ((float*)Cv)[idx];
          float sg = 1.f / (1.f + expf(-v));
          ((float*)Cv)[idx] = res[idx] + sg * pv;
        }
      }
}

// ---- kvsum: per-chunk S_c[s][sv] = sum_t wk[t]*K[t][s]*V[t][sv]  (MFMA) -----
__global__ __launch_bounds__(256) void kvsum_m(const u16* __restrict__ K,
                                               const u16* __restrict__ V,
                                               const float* __restrict__ wk_tab,
                                               float* __restrict__ SC) {
  const int bh = blockIdx.x & 127, c = blockIdx.x >> 7;
  const int b = bh >> 5, h = bh & 31;
  const int tid = threadIdx.x, w = tid >> 6, lane = tid & 63;
  const int fr = lane & 15, fq = lane >> 4;
  const size_t chunkbase = (size_t)b * TT_ + (size_t)c * TCH;
  const u16* Kp = K + chunkbase * C_ + h * 64;
  const u16* Vp = V + chunkbase * C_ + h * 64;
  __shared__ alignas(16) u16 Kts[64 * 128];  // [s][t] swizzled, 16KB
  __shared__ alignas(16) u16 Vts[64 * 128];  // [sv][t] swizzled
  f32x4 acc[4];
#pragma unroll
  for (int n = 0; n < 4; n++) acc[n] = (f32x4){0.f, 0.f, 0.f, 0.f};

  for (int tb = 0; tb < 4; tb++) {
    __syncthreads();
    const int u = tid >> 1;                 // local t 0..127
    const int tg = tb * 128 + u;
    const float wkv = wk_tab[h * TCH + tg];
#pragma unroll
    for (int i = 0; i < 4; i++) {
      int s0 = (tid & 1) * 32 + i * 8;
      uint4 dK = *(const uint4*)(Kp + (size_t)tg * C_ + s0);
      uint4 dV = *(const uint4*)(Vp + (size_t)tg * C_ + s0);
      const u16* ek = (const u16*)&dK;
      const u16* ev = (const u16*)&dV;
#pragma unroll
      for (int j = 0; j < 8; j++) {
        int s = s0 + j;
        int byte = s * 256 + u * 2;
        byte ^= (s & 7) << 4;
        *(u16*)((char*)Kts + byte) = f2bf(bf2f(ek[j]) * wkv);
        *(u16*)((char*)Vts + byte) = ev[j];
      }
    }
    __syncthreads();
#pragma unroll
    for (int kk = 0; kk < 4; kk++) {
      int rbyteA = (w * 16 + fr) * 256 + kk * 64 + fq * 16;
      rbyteA ^= (fr & 7) << 4;
      bf16x8 av = *(const bf16x8*)((char*)Kts + rbyteA);
#pragma unroll
      for (int n = 0; n < 4; n++) {
        int rbyteB = (n * 16 + fr) * 256 + kk * 64 + fq * 16;
        rbyteB ^= (fr & 7) << 4;
        bf16x8 bv = *(const bf16x8*)((char*)Vts + rbyteB);
        acc[n] = __builtin_amdgcn_mfma_f32_16x16x32_bf16(av, bv, acc[n], 0, 0, 0);
      }
    }
  }
  float* out = SC + ((size_t)c * 128 + bh) * 4096;
#pragma unroll
  for (int n = 0; n < 4; n++)
#pragma unroll
    for (int j = 0; j < 4; j++) {
      int srow = w * 16 + fq * 4 + j;
      int scol = n * 16 + fr;
      out[srow * 64 + scol] = acc[n][j];
    }
}

// ---- state combine: STC[c] = sum_{j<c} ws^(c-1-j) SC[j] ---------------------
__global__ __launch_bounds__(256) void stcomb(const float* __restrict__ SC,
                                              float* __restrict__ STC,
                                              const float* __restrict__ wspow) {
  const int bh = blockIdx.x;
  const float ws = wspow[bh & 31];
  const int tid = threadIdx.x;
#pragma unroll
  for (int e = 0; e < 16; e++) {
    int idx = e * 256 + tid;
    float st = 0.f;
#pragma unroll
    for (int c = 0; c < 4; c++) {
      STC[((size_t)c * 128 + bh) * 4096 + idx] = st;
      st = ws * st + SC[((size_t)c * 128 + bh) * 4096 + idx];
    }
  }
}

// ---- attention output (MFMA, batched over chunks) ---------------------------
__global__ __launch_bounds__(256) void att_out_m(const u16* __restrict__ R,
                                                 const u16* __restrict__ K,
                                                 const u16* __restrict__ V,
                                                 const float* __restrict__ STC,
                                                 const float* __restrict__ wb_tab,
                                                 const float* __restrict__ u_vec,
                                                 u16* __restrict__ xa) {
  const int bh = blockIdx.x;       // 0..127
  const int ti = blockIdx.y;       // 0..7
  const int c  = blockIdx.z;       // 0..3
  const int b = bh >> 5, h = bh & 31;
  const int tid = threadIdx.x, w = tid >> 6, lane = tid & 63;
  const int fr = lane & 15, fq = lane >> 4;
  const int t0 = ti * 64;
  const size_t chunkbase = (size_t)b * TT_ + (size_t)c * TCH;
  const u16* Rp = R + (chunkbase + t0) * C_ + h * 64;
  const u16* Kp = K + chunkbase * C_ + h * 64;
  const u16* Vp = V + chunkbase * C_ + h * 64;

  __shared__ alignas(16) u16 Rs[64 * 64];    // [t][s]  swizzled, 8KB
  __shared__ alignas(16) u16 Ks[128 * 64];   // [u][s]  swizzled, 16KB
  __shared__ alignas(16) u16 Vts[64 * 128];  // [sv][u] swizzled, 16KB
  __shared__ alignas(16) u16 As[64 * 128];   // [t][u]  swizzled, 16KB
  __shared__ alignas(16) float Ss[64 * 64];  // state [sp][s], plain, 16KB
  __shared__ float wbs[512];

  // stage R (swizzled b128), state (plain), wb table
#pragma unroll
  for (int it = 0; it < 2; it++) {
    int r = (tid >> 3) + it * 32;
    int cb = (tid & 7) * 16;
    uint4 d = *(const uint4*)((const char*)(Rp + (size_t)r * C_) + cb);
    int byte = r * 128 + cb;
    byte ^= (r & 7) << 4;
    *(uint4*)((char*)Rs + byte) = d;
  }
  const float* stp = STC + ((size_t)c * 128 + bh) * 4096;
#pragma unroll
  for (int it = 0; it < 4; it++) {
    int i = tid + it * 256;
    *(float4*)&Ss[i * 4] = *(const float4*)&stp[i * 4];
  }
  wbs[tid] = wb_tab[h * TCH + tid];
  wbs[tid + 256] = wb_tab[h * TCH + tid + 256];
  const float uh = u_vec[h];
  __syncthreads();

  // state term (f32 VALU): stt[n][j] = sum_sp R[t][sp] * state[sp][scol]
  float stt[4][4];
#pragma unroll
  for (int n = 0; n < 4; n++)
#pragma unroll
    for (int j = 0; j < 4; j++) stt[n][j] = 0.f;
  {
#pragma unroll 2
    for (int sp0 = 0; sp0 < 64; sp0 += 8) {
      bf16x8 rr8[4];
#pragma unroll
      for (int j = 0; j < 4; j++) {
        int row = w * 16 + fq * 4 + j;
        int byte = row * 128 + sp0 * 2;
        byte ^= (row & 7) << 4;
        rr8[j] = *(const bf16x8*)((char*)Rs + byte);
      }
#pragma unroll
      for (int e = 0; e < 8; e++) {
        float sv[4];
#pragma unroll
        for (int n = 0; n < 4; n++) sv[n] = Ss[(sp0 + e) * 64 + n * 16 + fr];
#pragma unroll
        for (int j = 0; j < 4; j++) {
          float rv = (float)rr8[j][e];
#pragma unroll
          for (int n = 0; n < 4; n++) stt[n][j] += rv * sv[n];
        }
      }
    }
  }
  f32x4 pv[4];
#pragma unroll
  for (int n = 0; n < 4; n++) {
#pragma unroll
    for (int j = 0; j < 4; j++) {
      int tg = t0 + w * 16 + fq * 4 + j;
      pv[n][j] = stt[n][j] * wbs[tg];
    }
  }

  // u-block loop (causal skip)
  const int ubmax = ti >> 1;
  for (int ub = 0; ub <= ubmax; ub++) {
    const int u0 = ub * 128;
    __syncthreads();
    // stage K (128x64, swizzled b128) and Vt (transposed, swizzled b16)
#pragma unroll
    for (int it = 0; it < 4; it++) {
      int r = (tid >> 3) + it * 32;
      int cb = (tid & 7) * 16;
      uint4 d = *(const uint4*)((const char*)(Kp + (size_t)(u0 + r) * C_) + cb);
      int byte = r * 128 + cb;
      byte ^= (r & 7) << 4;
      *(uint4*)((char*)Ks + byte) = d;
    }
    {
      const int u = tid >> 1;
#pragma unroll
      for (int i = 0; i < 4; i++) {
        int s0 = (tid & 1) * 32 + i * 8;
        uint4 d = *(const uint4*)(Vp + (size_t)(u0 + u) * C_ + s0);
        const u16* ev = (const u16*)&d;
#pragma unroll
        for (int j = 0; j < 8; j++) {
          int s = s0 + j;
          int byte = s * 256 + u * 2;
          byte ^= (s & 7) << 4;
          *(u16*)((char*)Vts + byte) = ev[j];
        }
      }
    }
    __syncthreads();
    // QK^T: wave rows [w*16, w*16+16) x 128 u
    f32x4 accA[8];
#pragma unroll
    for (int n = 0; n < 8; n++) accA[n] = (f32x4){0.f, 0.f, 0.f, 0.f};
#pragma unroll
    for (int kk = 0; kk < 2; kk++) {
      int rbA = (w * 16 + fr) * 128 + kk * 64 + fq * 16;
      rbA ^= (fr & 7) << 4;
      bf16x8 av = *(const bf16x8*)((char*)Rs + rbA);
#pragma unroll
      for (int n = 0; n < 8; n++) {
        int rbB = (n * 16 + fr) * 128 + kk * 64 + fq * 16;
        rbB ^= (fr & 7) << 4;
        bf16x8 bv = *(const bf16x8*)((char*)Ks + rbB);
        accA[n] = __builtin_amdgcn_mfma_f32_16x16x32_bf16(av, bv, accA[n], 0, 0, 0);
      }
    }
    // mask + bf16 + write to As (own rows only)
#pragma unroll
    for (int n = 0; n < 8; n++) {
#pragma unroll
      for (int j = 0; j < 4; j++) {
        int tl = w * 16 + fq * 4 + j;
        int tg = t0 + tl;
        int u = u0 + n * 16 + fr;
        int d = tg - u;
        float f = (d > 0) ? wbs[d - 1] : ((d == 0) ? uh : 0.f);
        int byte = tl * 256 + (n * 16 + fr) * 2;
        byte ^= (tl & 7) << 4;
        *(u16*)((char*)As + byte) = f2bf(accA[n][j] * f);
      }
    }
    // PV: pv += A_u @ V_u  (reads own As rows; Vts staged this iter)
#pragma unroll
    for (int kk = 0; kk < 4; kk++) {
      int rbA = (w * 16 + fr) * 256 + kk * 64 + fq * 16;
      rbA ^= (fr & 7) << 4;
      bf16x8 ap = *(const bf16x8*)((char*)As + rbA);
#pragma unroll
      for (int n = 0; n < 4; n++) {
        int rbB = (n * 16 + fr) * 256 + kk * 64 + fq * 16;
        rbB ^= (fr & 7) << 4;
        bf16x8 vp = *(const bf16x8*)((char*)Vts + rbB);
        pv[n] = __builtin_amdgcn_mfma_f32_16x16x32_bf16(ap, vp, pv[n], 0, 0, 0);
      }
    }
  }
  // epilogue
  u16* xout = xa + (chunkbase + t0) * C_ + h * 64;
#pragma unroll
  for (int n = 0; n < 4; n++)
#pragma unroll
    for (int j = 0; j < 4; j++) {
      int tl = w * 16 + fq * 4 + j;
      xout[(size_t)tl * C_ + n * 16 + fr] = f2bf(pv[n][j]);
    }
}

// ---- per-head groupnorm ------------------------------------------------------
__global__ __launch_bounds__(256) void gnorm(const u16* __restrict__ xa,
                                             const float* __restrict__ g,
                                             const float* __restrict__ b,
                                             u16* __restrict__ out) {
  const int row = blockIdx.x;
  const int lane = threadIdx.x & 63, wv = threadIdx.x >> 6;
  const u16* xp = xa + (size_t)row * C_;
  u16* op = out + (size_t)row * C_;
  for (int h = wv; h < 32; h += 4) {
    float v = bf2f(xp[h * 64 + lane]) * 0.125f;
    float s = v, s2 = v * v;
#pragma unroll
    for (int o = 32; o > 0; o >>= 1) { s += __shfl_down(s, o); s2 += __shfl_down(s2, o); }
    s = __shfl(s, 0); s2 = __shfl(s2, 0);
    float m = s * (1.f / 64.f), var = s2 * (1.f / 64.f) - m * m;
    float nv = (v - m) * rsqrtf(var + 1e-5f);
    op[h * 64 + lane] = f2bf(nv * g[h * 64 + lane] + b[h * 64 + lane]);
  }
}

// ---- launcher ---------------------------------------------------------------
extern "C" void kernel_launch(void* const* d_in, const int* in_sizes, int n_in,
                              void* d_out, int out_size, void* d_ws, size_t ws_size,
                              hipStream_t stream) {
  (void)in_sizes; (void)n_in; (void)out_size; (void)ws_size;
  const float* x    = (const float*)d_in[0];
  const float* ln1g = (const float*)d_in[1];
  const float* ln1b = (const float*)d_in[2];
  const float* ln2g = (const float*)d_in[3];
  const float* ln2b = (const float*)d_in[4];
  const float* amk  = (const float*)d_in[5];
  const float* amv  = (const float*)d_in[6];
  const float* amr  = (const float*)d_in[7];
  const float* tdec = (const float*)d_in[8];
  const float* tfaa = (const float*)d_in[9];
  const float* Wr   = (const float*)d_in[10];
  const float* Wk   = (const float*)d_in[11];
  const float* Wv   = (const float*)d_in[12];
  const float* Wo   = (const float*)d_in[13];
  const float* lnxg = (const float*)d_in[14];
  const float* lnxb = (const float*)d_in[15];
  const float* fmk  = (const float*)d_in[16];
  const float* fmr  = (const float*)d_in[17];
  const float* Wfk  = (const float*)d_in[18];
  const float* Wfr  = (const float*)d_in[19];
  const float* Wfv  = (const float*)d_in[20];

  char* ws = (char*)d_ws;
  const size_t MB = 1ull << 20;
  u16* WR  = (u16*)(ws + 0 * MB);     // dead after r-GEMM; then SC (8MB)
  u16* WK  = (u16*)(ws + 8 * MB);     // dead after k-GEMM; then STC (8MB)
  u16* WV  = (u16*)(ws + 16 * MB);    // dead after v-GEMM
  u16* WO  = (u16*)(ws + 24 * MB);    // dead after x_mid
  u16* WFR = (u16*)(ws + 32 * MB);
  u16* WFK = (u16*)(ws + 40 * MB);    // 28 MB
  u16* WFV = (u16*)(ws + 68 * MB);    // 28 MB
  u16* H1  = (u16*)(ws + 96 * MB);    // h1 -> r -> xan -> xr2
  u16* XR  = (u16*)(ws + 128 * MB);   // xr -> k -> x_mid(f32, 128-192)
  u16* XK  = (u16*)(ws + 160 * MB);   // xk -> v
  u16* XV  = (u16*)(ws + 192 * MB);   // xv -> xa -> h2 -> kf_q
  float* WBT = (float*)(ws + 224 * MB);
  float* WKT = (float*)(ws + 224 * MB + 65536);
  float* WSP = (float*)(ws + 224 * MB + 131072);
  float* SCb  = (float*)(ws + 0 * MB);   // 8 MB (WR region, free at attn time)
  float* STCb = (float*)(ws + 8 * MB);   // 8 MB (WK region)
  u16* RB   = H1;
  u16* KB   = XR;
  u16* VB   = XK;
  u16* XA   = XV;
  u16* XAN  = H1;
  float* XMID = (float*)XR;
  u16* H2   = XV;
  u16* XK2  = WR;
  u16* XR2  = H1;
  u16* KFQ  = XV;
  float* OUT = (float*)d_out;

  dim3 blk(256);
  wcvt_t<<<dim3(64, 64), blk, 0, stream>>>(Wr, WR, 2048, 2048, 0);
  wcvt_t<<<dim3(64, 64), blk, 0, stream>>>(Wk, WK, 2048, 2048, 0);
  wcvt_t<<<dim3(64, 64), blk, 0, stream>>>(Wv, WV, 2048, 2048, 0);
  wcvt_t<<<dim3(64, 64), blk, 0, stream>>>(Wo, WO, 2048, 2048, 0);
  wcvt_t<<<dim3(64, 64), blk, 0, stream>>>(Wfr, WFR, 2048, 2048, 0);
  wcvt_t<<<dim3(224, 64), blk, 0, stream>>>(Wfk, WFK, 2048, 7168, 0);
  wcvt_t<<<dim3(64, 224), blk, 0, stream>>>(Wfv, WFV, 7168, 2048, 0);

  ln_rows<<<8192, blk, 0, stream>>>(x, ln1g, ln1b, H1);
  mix3<<<8192, blk, 0, stream>>>(H1, amk, amv, amr, XK, XV, XR);
  gemm_bt<0><<<1024, blk, 0, stream>>>(XR, WR, RB, nullptr, 2048, 2048, 2048, 2048, 16);
  gemm_bt<0><<<1024, blk, 0, stream>>>(XK, WK, KB, nullptr, 2048, 2048, 2048, 2048, 16);
  gemm_bt<0><<<1024, blk, 0, stream>>>(XV, WV, VB, nullptr, 2048, 2048, 2048, 2048, 16);

  wtabs_k<<<32, 512, 0, stream>>>(tdec, WBT, WKT, WSP);
  kvsum_m<<<512, blk, 0, stream>>>(KB, VB, WKT, SCb);
  stcomb<<<128, blk, 0, stream>>>(SCb, STCb, WSP);
  att_out_m<<<dim3(128, 8, 4), blk, 0, stream>>>(RB, KB, VB, STCb, WBT, tfaa, XA);

  gnorm<<<8192, blk, 0, stream>>>(XA, lnxg, lnxb, XAN);
  gemm_bt<1><<<1024, blk, 0, stream>>>(XAN, WO, XMID, x, 2048, 2048, 2048, 2048, 16);

  ln_rows<<<8192, blk, 0, stream>>>(XMID, ln2g, ln2b, H2);
  mix2<<<8192, blk, 0, stream>>>(H2, fmk, fmr, XK2, XR2);

  for (int q = 0; q < 4; q++) {
    const u16* wfk_q = WFK + (size_t)q * 1792 * 2048;
    const u16* wfv_q = WFV + (size_t)q * 1792;
    gemm_bt<2><<<896, blk, 0, stream>>>(XK2, wfk_q, KFQ, nullptr, 1792, 2048, 2048, 2048, 14);
    if (q == 0)
      gemm_bt<5><<<1024, blk, 0, stream>>>(KFQ, wfv_q, OUT, nullptr, 2048, 1792, 1792, 7168, 16);
    else
      gemm_bt<7><<<1024, blk, 0, stream>>>(KFQ, wfv_q, OUT, nullptr, 2048, 1792, 1792, 7168, 16);
  }
  gemm_bt<8><<<1024, blk, 0, stream>>>(XR2, WFR, OUT, XMID, 2048, 2048, 2048, 2048, 16);
}

// Round 5
// 1878.406 us; speedup vs baseline: 1.5882x; 1.0546x over previous
//
#include <hip/hip_runtime.h>

#define B_   4
#define TT_  2048
#define C_   2048
#define H_   32
#define S_   64
#define DF_  7168
#define TCH  512
#define NCH  4

typedef unsigned short u16;
typedef __bf16 bf16x8 __attribute__((ext_vector_type(8)));
typedef float  f32x4  __attribute__((ext_vector_type(4)));

__device__ __forceinline__ u16 f2bf(float f) {
  unsigned u = __builtin_bit_cast(unsigned, f);
  u = u + 0x7FFFu + ((u >> 16) & 1u);
  return (u16)(u >> 16);
}
__device__ __forceinline__ float bf2f(u16 v) {
  unsigned u = ((unsigned)v) << 16;
  return __builtin_bit_cast(float, u);
}

#define GLOAD16(g, l) __builtin_amdgcn_global_load_lds( \
    (const __attribute__((address_space(1))) void*)(g), \
    (__attribute__((address_space(3))) void*)(l), 16, 0, 0)

// ---- weight convert+transpose ----------------------------------------------
__global__ __launch_bounds__(256) void wcvt_t(const float* __restrict__ W,
                                              u16* __restrict__ Wt, int K, int Nfull,
                                              int n0off) {
  __shared__ alignas(16) float tile[32][33];
  int nloc = blockIdx.x * 32, k0 = blockIdx.y * 32;
  int tx = threadIdx.x & 31, ty = threadIdx.x >> 5;
  for (int r = ty; r < 32; r += 8)
    tile[r][tx] = W[(size_t)(k0 + r) * Nfull + n0off + nloc + tx];
  __syncthreads();
  for (int r = ty; r < 32; r += 8)
    Wt[(size_t)(nloc + r) * K + k0 + tx] = f2bf(tile[tx][r]);
}

// ---- layernorm over C=2048, f32 in -> bf16 out ------------------------------
__global__ __launch_bounds__(256) void ln_rows(const float* __restrict__ x,
                                               const float* __restrict__ g,
                                               const float* __restrict__ b,
                                               u16* __restrict__ out) {
  const int row = blockIdx.x;
  const float* xr = x + (size_t)row * C_;
  float v[8]; float s = 0.f, s2 = 0.f;
#pragma unroll
  for (int i = 0; i < 8; i++) { v[i] = xr[threadIdx.x + i * 256]; s += v[i]; s2 += v[i] * v[i]; }
#pragma unroll
  for (int o = 32; o > 0; o >>= 1) { s += __shfl_down(s, o); s2 += __shfl_down(s2, o); }
  __shared__ float rs[4], rs2[4];
  int wid = threadIdx.x >> 6, lane = threadIdx.x & 63;
  if (lane == 0) { rs[wid] = s; rs2[wid] = s2; }
  __syncthreads();
  s = rs[0] + rs[1] + rs[2] + rs[3];
  s2 = rs2[0] + rs2[1] + rs2[2] + rs2[3];
  float m = s * (1.f / C_);
  float var = s2 * (1.f / C_) - m * m;
  float inv = rsqrtf(var + 1e-5f);
  u16* orow = out + (size_t)row * C_;
#pragma unroll
  for (int i = 0; i < 8; i++) {
    int c = threadIdx.x + i * 256;
    orow[c] = f2bf((v[i] - m) * inv * g[c] + b[c]);
  }
}

// ---- decay tables -----------------------------------------------------------
__global__ void wtabs_k(const float* __restrict__ td, float* __restrict__ wb_tab,
                        float* __restrict__ wk_tab, float* __restrict__ wspow) {
  int h = blockIdx.x, t = threadIdx.x;
  float w = expf(-expf(td[h]));
  wb_tab[h * TCH + t] = powf(w, (float)t);
  wk_tab[h * TCH + t] = powf(w, (float)(TCH - 1 - t));
  if (t == 0) wspow[h] = powf(w, (float)TCH);
}

// ---- time-shift mixes -------------------------------------------------------
__device__ __forceinline__ void mix_body(const u16* cur, const u16* prev, bool hasp,
                                         const float* mc, u16* dst) {
  ushort4 c0 = *(const ushort4*)cur;
  ushort4 c1 = *(const ushort4*)(cur + 4);
  ushort4 p0 = {0, 0, 0, 0}, p1 = {0, 0, 0, 0};
  if (hasp) { p0 = *(const ushort4*)prev; p1 = *(const ushort4*)(prev + 4); }
  float4 mA = *(const float4*)mc;
  float4 mB = *(const float4*)(mc + 4);
  ushort4 r0, r1;
  r0.x = f2bf(bf2f(c0.x) * mA.x + bf2f(p0.x) * (1.f - mA.x));
  r0.y = f2bf(bf2f(c0.y) * mA.y + bf2f(p0.y) * (1.f - mA.y));
  r0.z = f2bf(bf2f(c0.z) * mA.z + bf2f(p0.z) * (1.f - mA.z));
  r0.w = f2bf(bf2f(c0.w) * mA.w + bf2f(p0.w) * (1.f - mA.w));
  r1.x = f2bf(bf2f(c1.x) * mB.x + bf2f(p1.x) * (1.f - mB.x));
  r1.y = f2bf(bf2f(c1.y) * mB.y + bf2f(p1.y) * (1.f - mB.y));
  r1.z = f2bf(bf2f(c1.z) * mB.z + bf2f(p1.z) * (1.f - mB.z));
  r1.w = f2bf(bf2f(c1.w) * mB.w + bf2f(p1.w) * (1.f - mB.w));
  *(ushort4*)dst = r0;
  *(ushort4*)(dst + 4) = r1;
}

__global__ __launch_bounds__(256) void mix3(const u16* __restrict__ h,
                                            const float* __restrict__ mk,
                                            const float* __restrict__ mv,
                                            const float* __restrict__ mr,
                                            u16* __restrict__ xk, u16* __restrict__ xv,
                                            u16* __restrict__ xr) {
  size_t i8 = (size_t)blockIdx.x * 256 + threadIdx.x;
  size_t off = i8 * 8;
  int c0 = (int)(off & (C_ - 1));
  int row = (int)(i8 >> 8);
  bool hasp = (row & (TT_ - 1)) != 0;
  const u16* cur = h + off;
  const u16* prev = cur - C_;
  mix_body(cur, prev, hasp, mk + c0, xk + off);
  mix_body(cur, prev, hasp, mv + c0, xv + off);
  mix_body(cur, prev, hasp, mr + c0, xr + off);
}

__global__ __launch_bounds__(256) void mix2(const u16* __restrict__ h,
                                            const float* __restrict__ mk,
                                            const float* __restrict__ mr,
                                            u16* __restrict__ xk, u16* __restrict__ xr) {
  size_t i8 = (size_t)blockIdx.x * 256 + threadIdx.x;
  size_t off = i8 * 8;
  int c0 = (int)(off & (C_ - 1));
  int row = (int)(i8 >> 8);
  bool hasp = (row & (TT_ - 1)) != 0;
  const u16* cur = h + off;
  const u16* prev = cur - C_;
  mix_body(cur, prev, hasp, mk + c0, xk + off);
  mix_body(cur, prev, hasp, mr + c0, xr + off);
}

// ---- plain GEMM (m97 structure + XCD swizzle) -------------------------------
template <int EPI>
__global__ __launch_bounds__(256) void gemm_bt(const u16* __restrict__ A,
                                               const u16* __restrict__ Bt,
                                               void* __restrict__ Cv,
                                               const float* __restrict__ res,
                                               int N, int K, int lda, int ldb, int gy) {
  __shared__ alignas(16) u16 As[128 * 32];
  __shared__ alignas(16) u16 Bs[128 * 32];
  const int nwg = gridDim.x;
  const int qq = nwg >> 3;
  const int wg = (int)(blockIdx.x & 7) * qq + (int)(blockIdx.x >> 3);
  const int bx = wg / gy, by = wg % gy;
  const int tid = threadIdx.x;
  const int wid = tid >> 6, lane = tid & 63;
  const int fr = lane & 15, fq = lane >> 4;
  const int m0 = bx * 128, n0 = by * 128;
  const int wm = (wid >> 1) * 64, wn = (wid & 1) * 64;
  const int rowS = tid >> 2, colS = (tid & 3) * 8;
  const u16* Ag = A + (size_t)(m0 + rowS) * lda + colS;
  const u16* Bg = Bt + (size_t)(n0 + rowS) * ldb + colS;
  char* ldsA = (char*)As + wid * 1024;
  char* ldsB = (char*)Bs + wid * 1024;
  f32x4 acc[4][4];
#pragma unroll
  for (int i = 0; i < 4; i++)
#pragma unroll
    for (int j = 0; j < 4; j++) acc[i][j] = (f32x4){0.f, 0.f, 0.f, 0.f};

  for (int k0 = 0; k0 < K; k0 += 32) {
    GLOAD16(Ag + k0, ldsA);
    GLOAD16(Ag + k0 + (size_t)64 * lda, ldsA + 4096);
    GLOAD16(Bg + k0, ldsB);
    GLOAD16(Bg + k0 + (size_t)64 * ldb, ldsB + 4096);
    __syncthreads();
    bf16x8 av[4], bv[4];
#pragma unroll
    for (int m = 0; m < 4; m++) av[m] = *(const bf16x8*)&As[(wm + m * 16 + fr) * 32 + fq * 8];
#pragma unroll
    for (int n = 0; n < 4; n++) bv[n] = *(const bf16x8*)&Bs[(wn + n * 16 + fr) * 32 + fq * 8];
#pragma unroll
    for (int m = 0; m < 4; m++)
#pragma unroll
      for (int n = 0; n < 4; n++)
        acc[m][n] = __builtin_amdgcn_mfma_f32_16x16x32_bf16(av[m], bv[n], acc[m][n], 0, 0, 0);
    __syncthreads();
  }
#pragma unroll
  for (int m = 0; m < 4; m++)
#pragma unroll
    for (int n = 0; n < 4; n++)
#pragma unroll
      for (int j = 0; j < 4; j++) {
        int row = m0 + wm + m * 16 + fq * 4 + j;
        int col = n0 + wn + n * 16 + fr;
        size_t idx = (size_t)row * N + col;
        float v = acc[m][n][j];
        if (EPI == 0) ((u16*)Cv)[idx] = f2bf(v);
        else if (EPI == 1) ((float*)Cv)[idx] = v + res[idx];
        else if (EPI == 2) { float r = v > 0.f ? v : 0.f; ((u16*)Cv)[idx] = f2bf(r * r); }
        else if (EPI == 5) ((float*)Cv)[idx] = v;
        else if (EPI == 7) ((float*)Cv)[idx] += v;
        else {
          float pv = ((float*)Cv)[idx];
          float sg = 1.f / (1.f + expf(-v));
          ((float*)Cv)[idx] = res[idx] + sg * pv;
        }
      }
}

// ---- kvsum: per-chunk S_c[s][sv] = sum_t wk[t]*K[t][s]*V[t][sv]  (MFMA) -----
__global__ __launch_bounds__(256) void kvsum_m(const u16* __restrict__ K,
                                               const u16* __restrict__ V,
                                               const float* __restrict__ wk_tab,
                                               float* __restrict__ SC) {
  const int bh = blockIdx.x & 127, c = blockIdx.x >> 7;
  const int b = bh >> 5, h = bh & 31;
  const int tid = threadIdx.x, w = tid >> 6, lane = tid & 63;
  const int fr = lane & 15, fq = lane >> 4;
  const size_t chunkbase = (size_t)b * TT_ + (size_t)c * TCH;
  const u16* Kp = K + chunkbase * C_ + h * 64;
  const u16* Vp = V + chunkbase * C_ + h * 64;
  __shared__ alignas(16) u16 Kts[64 * 128];  // [s][t] swizzled, 16KB
  __shared__ alignas(16) u16 Vts[64 * 128];  // [sv][t] swizzled
  f32x4 acc[4];
#pragma unroll
  for (int n = 0; n < 4; n++) acc[n] = (f32x4){0.f, 0.f, 0.f, 0.f};

  for (int tb = 0; tb < 4; tb++) {
    __syncthreads();
    const int u = tid >> 1;                 // local t 0..127
    const int tg = tb * 128 + u;
    const float wkv = wk_tab[h * TCH + tg];
#pragma unroll
    for (int i = 0; i < 4; i++) {
      int s0 = (tid & 1) * 32 + i * 8;
      uint4 dK = *(const uint4*)(Kp + (size_t)tg * C_ + s0);
      uint4 dV = *(const uint4*)(Vp + (size_t)tg * C_ + s0);
      const u16* ek = (const u16*)&dK;
      const u16* ev = (const u16*)&dV;
#pragma unroll
      for (int j = 0; j < 8; j++) {
        int s = s0 + j;
        int byte = s * 256 + u * 2;
        byte ^= (s & 7) << 4;
        *(u16*)((char*)Kts + byte) = f2bf(bf2f(ek[j]) * wkv);
        *(u16*)((char*)Vts + byte) = ev[j];
      }
    }
    __syncthreads();
#pragma unroll
    for (int kk = 0; kk < 4; kk++) {
      int rbyteA = (w * 16 + fr) * 256 + kk * 64 + fq * 16;
      rbyteA ^= (fr & 7) << 4;
      bf16x8 av = *(const bf16x8*)((char*)Kts + rbyteA);
#pragma unroll
      for (int n = 0; n < 4; n++) {
        int rbyteB = (n * 16 + fr) * 256 + kk * 64 + fq * 16;
        rbyteB ^= (fr & 7) << 4;
        bf16x8 bv = *(const bf16x8*)((char*)Vts + rbyteB);
        acc[n] = __builtin_amdgcn_mfma_f32_16x16x32_bf16(av, bv, acc[n], 0, 0, 0);
      }
    }
  }
  float* out = SC + ((size_t)c * 128 + bh) * 4096;
#pragma unroll
  for (int n = 0; n < 4; n++)
#pragma unroll
    for (int j = 0; j < 4; j++) {
      int srow = w * 16 + fq * 4 + j;
      int scol = n * 16 + fr;
      out[srow * 64 + scol] = acc[n][j];
    }
}

// ---- state combine: STt[c][s][sp] = bf16( sum_{j<c} ws^(c-1-j) SC[j][sp][s] )
__global__ __launch_bounds__(256) void stcomb(const float* __restrict__ SC,
                                              u16* __restrict__ STt,
                                              const float* __restrict__ wspow) {
  const int bh = blockIdx.x;
  const float ws = wspow[bh & 31];
  const int tid = threadIdx.x;
#pragma unroll
  for (int e = 0; e < 16; e++) {
    int idxT = e * 256 + tid;          // dst index: s*64 + sp
    int s = idxT >> 6, sp = idxT & 63;
    int src = sp * 64 + s;             // SC is [sp][s]
    float st = 0.f;
#pragma unroll
    for (int c = 0; c < 4; c++) {
      STt[((size_t)c * 128 + bh) * 4096 + idxT] = f2bf(st);
      st = ws * st + SC[((size_t)c * 128 + bh) * 4096 + src];
    }
  }
}

// ---- attention output (MFMA, batched over chunks; 34KB LDS) -----------------
__global__ __launch_bounds__(256) void att_out_m(const u16* __restrict__ R,
                                                 const u16* __restrict__ K,
                                                 const u16* __restrict__ V,
                                                 const u16* __restrict__ STt,
                                                 const float* __restrict__ wb_tab,
                                                 const float* __restrict__ u_vec,
                                                 u16* __restrict__ xa) {
  const int bh = blockIdx.x;       // 0..127
  const int ti = blockIdx.y;       // 0..7
  const int c  = blockIdx.z;       // 0..3
  const int b = bh >> 5, h = bh & 31;
  const int tid = threadIdx.x, w = tid >> 6, lane = tid & 63;
  const int fr = lane & 15, fq = lane >> 4;
  const int t0 = ti * 64;
  const size_t chunkbase = (size_t)b * TT_ + (size_t)c * TCH;
  const u16* Rp = R + (chunkbase + t0) * C_ + h * 64;
  const u16* Kp = K + chunkbase * C_ + h * 64;
  const u16* Vp = V + chunkbase * C_ + h * 64;

  __shared__ alignas(16) u16 Rs[64 * 64];   // [t][s]   swizzled, 8KB
  __shared__ alignas(16) u16 Ks[64 * 64];   // [u][s]   swizzled, 8KB
  __shared__ alignas(16) u16 Vts[64 * 64];  // [sv][u]  swizzled, 8KB
  __shared__ alignas(16) u16 Xs[64 * 64];   // STt then As, 8KB
  __shared__ float wbs[512];                // 2KB

  // stage R and STt (both 64x64 bf16, swizzled b128 writes)
#pragma unroll
  for (int it = 0; it < 2; it++) {
    int r = (tid >> 3) + it * 32;
    int cb = (tid & 7) * 16;
    uint4 d = *(const uint4*)((const char*)(Rp + (size_t)r * C_) + cb);
    int byte = (r * 128 + cb) ^ ((r & 7) << 4);
    *(uint4*)((char*)Rs + byte) = d;
  }
  const u16* stg = STt + ((size_t)c * 128 + bh) * 4096;
#pragma unroll
  for (int it = 0; it < 2; it++) {
    int s = (tid >> 3) + it * 32;
    int cb = (tid & 7) * 16;
    uint4 d = *(const uint4*)((const char*)(stg + (size_t)s * 64) + cb);
    int byte = (s * 128 + cb) ^ ((s & 7) << 4);
    *(uint4*)((char*)Xs + byte) = d;
  }
  wbs[tid] = wb_tab[h * TCH + tid];
  wbs[tid + 256] = wb_tab[h * TCH + tid + 256];
  const float uh = u_vec[h];
  __syncthreads();

  // state term via MFMA: pv[t][s] = sum_sp R[t][sp] * STt[s][sp]
  f32x4 pv[4];
#pragma unroll
  for (int n = 0; n < 4; n++) pv[n] = (f32x4){0.f, 0.f, 0.f, 0.f};
#pragma unroll
  for (int kk = 0; kk < 2; kk++) {
    int rbA = ((w * 16 + fr) * 128 + kk * 64 + fq * 16) ^ ((fr & 7) << 4);
    bf16x8 av = *(const bf16x8*)((char*)Rs + rbA);
#pragma unroll
    for (int n = 0; n < 4; n++) {
      int rbB = ((n * 16 + fr) * 128 + kk * 64 + fq * 16) ^ ((fr & 7) << 4);
      bf16x8 bv = *(const bf16x8*)((char*)Xs + rbB);
      pv[n] = __builtin_amdgcn_mfma_f32_16x16x32_bf16(av, bv, pv[n], 0, 0, 0);
    }
  }
  // scale state term by wb[t]
#pragma unroll
  for (int n = 0; n < 4; n++)
#pragma unroll
    for (int j = 0; j < 4; j++) {
      int tg = t0 + w * 16 + fq * 4 + j;
      pv[n][j] *= wbs[tg];
    }

  // u-block loop (64-wide causal)
  for (int ub = 0; ub <= ti; ub++) {
    const int u0 = ub * 64;
    __syncthreads();   // also fences state-term Xs reads before As reuse
    // stage K rows (swizzled b128) and V transposed (scatter b16)
#pragma unroll
    for (int it = 0; it < 2; it++) {
      int r = (tid >> 3) + it * 32;
      int cb = (tid & 7) * 16;
      uint4 d = *(const uint4*)((const char*)(Kp + (size_t)(u0 + r) * C_) + cb);
      int byte = (r * 128 + cb) ^ ((r & 7) << 4);
      *(uint4*)((char*)Ks + byte) = d;
    }
#pragma unroll
    for (int it = 0; it < 2; it++) {
      int u = (tid >> 3) + it * 32;
      int s0 = (tid & 7) * 8;
      uint4 d = *(const uint4*)(Vp + (size_t)(u0 + u) * C_ + s0);
      const u16* ev = (const u16*)&d;
#pragma unroll
      for (int j = 0; j < 8; j++) {
        int s = s0 + j;
        int byte = (s * 128 + u * 2) ^ ((s & 7) << 4);
        *(u16*)((char*)Vts + byte) = ev[j];
      }
    }
    __syncthreads();
    // QK^T
    f32x4 accA[4];
#pragma unroll
    for (int n = 0; n < 4; n++) accA[n] = (f32x4){0.f, 0.f, 0.f, 0.f};
#pragma unroll
    for (int kk = 0; kk < 2; kk++) {
      int rbA = ((w * 16 + fr) * 128 + kk * 64 + fq * 16) ^ ((fr & 7) << 4);
      bf16x8 av = *(const bf16x8*)((char*)Rs + rbA);
#pragma unroll
      for (int n = 0; n < 4; n++) {
        int rbB = ((n * 16 + fr) * 128 + kk * 64 + fq * 16) ^ ((fr & 7) << 4);
        bf16x8 bv = *(const bf16x8*)((char*)Ks + rbB);
        accA[n] = __builtin_amdgcn_mfma_f32_16x16x32_bf16(av, bv, accA[n], 0, 0, 0);
      }
    }
    // mask + bf16 -> As (own wave rows only)
#pragma unroll
    for (int n = 0; n < 4; n++) {
#pragma unroll
      for (int j = 0; j < 4; j++) {
        int tl = w * 16 + fq * 4 + j;
        int tg = t0 + tl;
        int u = u0 + n * 16 + fr;
        int d = tg - u;
        float f = (d > 0) ? wbs[d - 1] : ((d == 0) ? uh : 0.f);
        int byte = (tl * 128 + (n * 16 + fr) * 2) ^ ((tl & 7) << 4);
        *(u16*)((char*)Xs + byte) = f2bf(accA[n][j] * f);
      }
    }
    // PV: pv += A_u @ V_u (own As rows; intra-wave LDS dep)
#pragma unroll
    for (int kk = 0; kk < 2; kk++) {
      int rbA = ((w * 16 + fr) * 128 + kk * 64 + fq * 16) ^ ((fr & 7) << 4);
      bf16x8 ap = *(const bf16x8*)((char*)Xs + rbA);
#pragma unroll
      for (int n = 0; n < 4; n++) {
        int rbB = ((n * 16 + fr) * 128 + kk * 64 + fq * 16) ^ ((fr & 7) << 4);
        bf16x8 vp = *(const bf16x8*)((char*)Vts + rbB);
        pv[n] = __builtin_amdgcn_mfma_f32_16x16x32_bf16(ap, vp, pv[n], 0, 0, 0);
      }
    }
  }
  // epilogue
  u16* xout = xa + (chunkbase + t0) * C_ + h * 64;
#pragma unroll
  for (int n = 0; n < 4; n++)
#pragma unroll
    for (int j = 0; j < 4; j++) {
      int tl = w * 16 + fq * 4 + j;
      xout[(size_t)tl * C_ + n * 16 + fr] = f2bf(pv[n][j]);
    }
}

// ---- per-head groupnorm ------------------------------------------------------
__global__ __launch_bounds__(256) void gnorm(const u16* __restrict__ xa,
                                             const float* __restrict__ g,
                                             const float* __restrict__ b,
                                             u16* __restrict__ out) {
  const int row = blockIdx.x;
  const int lane = threadIdx.x & 63, wv = threadIdx.x >> 6;
  const u16* xp = xa + (size_t)row * C_;
  u16* op = out + (size_t)row * C_;
  for (int h = wv; h < 32; h += 4) {
    float v = bf2f(xp[h * 64 + lane]) * 0.125f;
    float s = v, s2 = v * v;
#pragma unroll
    for (int o = 32; o > 0; o >>= 1) { s += __shfl_down(s, o); s2 += __shfl_down(s2, o); }
    s = __shfl(s, 0); s2 = __shfl(s2, 0);
    float m = s * (1.f / 64.f), var = s2 * (1.f / 64.f) - m * m;
    float nv = (v - m) * rsqrtf(var + 1e-5f);
    op[h * 64 + lane] = f2bf(nv * g[h * 64 + lane] + b[h * 64 + lane]);
  }
}

// ---- launcher ---------------------------------------------------------------
extern "C" void kernel_launch(void* const* d_in, const int* in_sizes, int n_in,
                              void* d_out, int out_size, void* d_ws, size_t ws_size,
                              hipStream_t stream) {
  (void)in_sizes; (void)n_in; (void)out_size; (void)ws_size;
  const float* x    = (const float*)d_in[0];
  const float* ln1g = (const float*)d_in[1];
  const float* ln1b = (const float*)d_in[2];
  const float* ln2g = (const float*)d_in[3];
  const float* ln2b = (const float*)d_in[4];
  const float* amk  = (const float*)d_in[5];
  const float* amv  = (const float*)d_in[6];
  const float* amr  = (const float*)d_in[7];
  const float* tdec = (const float*)d_in[8];
  const float* tfaa = (const float*)d_in[9];
  const float* Wr   = (const float*)d_in[10];
  const float* Wk   = (const float*)d_in[11];
  const float* Wv   = (const float*)d_in[12];
  const float* Wo   = (const float*)d_in[13];
  const float* lnxg = (const float*)d_in[14];
  const float* lnxb = (const float*)d_in[15];
  const float* fmk  = (const float*)d_in[16];
  const float* fmr  = (const float*)d_in[17];
  const float* Wfk  = (const float*)d_in[18];
  const float* Wfr  = (const float*)d_in[19];
  const float* Wfv  = (const float*)d_in[20];

  char* ws = (char*)d_ws;
  const size_t MB = 1ull << 20;
  u16* WR  = (u16*)(ws + 0 * MB);     // dead after r-GEMM; then SC (8MB)
  u16* WK  = (u16*)(ws + 8 * MB);     // dead after k-GEMM; then STt (4MB)
  u16* WV  = (u16*)(ws + 16 * MB);    // dead after v-GEMM
  u16* WO  = (u16*)(ws + 24 * MB);    // dead after x_mid
  u16* WFR = (u16*)(ws + 32 * MB);
  u16* WFK = (u16*)(ws + 40 * MB);    // 28 MB
  u16* WFV = (u16*)(ws + 68 * MB);    // 28 MB
  u16* H1  = (u16*)(ws + 96 * MB);    // h1 -> r -> xan -> xr2
  u16* XR  = (u16*)(ws + 128 * MB);   // xr -> k -> x_mid(f32, 128-192)
  u16* XK  = (u16*)(ws + 160 * MB);   // xk -> v
  u16* XV  = (u16*)(ws + 192 * MB);   // xv -> xa -> h2 -> kf_q
  float* WBT = (float*)(ws + 224 * MB);
  float* WKT = (float*)(ws + 224 * MB + 65536);
  float* WSP = (float*)(ws + 224 * MB + 131072);
  float* SCb = (float*)(ws + 0 * MB);   // 8 MB (WR region, free at attn time)
  u16* STTb  = (u16*)(ws + 8 * MB);     // 4 MB (WK region)
  u16* RB   = H1;
  u16* KB   = XR;
  u16* VB   = XK;
  u16* XA   = XV;
  u16* XAN  = H1;
  float* XMID = (float*)XR;
  u16* H2   = XV;
  u16* XK2  = WR;
  u16* XR2  = H1;
  u16* KFQ  = XV;
  float* OUT = (float*)d_out;

  dim3 blk(256);
  wcvt_t<<<dim3(64, 64), blk, 0, stream>>>(Wr, WR, 2048, 2048, 0);
  wcvt_t<<<dim3(64, 64), blk, 0, stream>>>(Wk, WK, 2048, 2048, 0);
  wcvt_t<<<dim3(64, 64), blk, 0, stream>>>(Wv, WV, 2048, 2048, 0);
  wcvt_t<<<dim3(64, 64), blk, 0, stream>>>(Wo, WO, 2048, 2048, 0);
  wcvt_t<<<dim3(64, 64), blk, 0, stream>>>(Wfr, WFR, 2048, 2048, 0);
  wcvt_t<<<dim3(224, 64), blk, 0, stream>>>(Wfk, WFK, 2048, 7168, 0);
  wcvt_t<<<dim3(64, 224), blk, 0, stream>>>(Wfv, WFV, 7168, 2048, 0);

  ln_rows<<<8192, blk, 0, stream>>>(x, ln1g, ln1b, H1);
  mix3<<<8192, blk, 0, stream>>>(H1, amk, amv, amr, XK, XV, XR);
  gemm_bt<0><<<1024, blk, 0, stream>>>(XR, WR, RB, nullptr, 2048, 2048, 2048, 2048, 16);
  gemm_bt<0><<<1024, blk, 0, stream>>>(XK, WK, KB, nullptr, 2048, 2048, 2048, 2048, 16);
  gemm_bt<0><<<1024, blk, 0, stream>>>(XV, WV, VB, nullptr, 2048, 2048, 2048, 2048, 16);

  wtabs_k<<<32, 512, 0, stream>>>(tdec, WBT, WKT, WSP);
  kvsum_m<<<512, blk, 0, stream>>>(KB, VB, WKT, SCb);
  stcomb<<<128, blk, 0, stream>>>(SCb, STTb, WSP);
  att_out_m<<<dim3(128, 8, 4), blk, 0, stream>>>(RB, KB, VB, STTb, WBT, tfaa, XA);

  gnorm<<<8192, blk, 0, stream>>>(XA, lnxg, lnxb, XAN);
  gemm_bt<1><<<1024, blk, 0, stream>>>(XAN, WO, XMID, x, 2048, 2048, 2048, 2048, 16);

  ln_rows<<<8192, blk, 0, stream>>>(XMID, ln2g, ln2b, H2);
  mix2<<<8192, blk, 0, stream>>>(H2, fmk, fmr, XK2, XR2);

  for (int q = 0; q < 4; q++) {
    const u16* wfk_q = WFK + (size_t)q * 1792 * 2048;
    const u16* wfv_q = WFV + (size_t)q * 1792;
    gemm_bt<2><<<896, blk, 0, stream>>>(XK2, wfk_q, KFQ, nullptr, 1792, 2048, 2048, 2048, 14);
    if (q == 0)
      gemm_bt<5><<<1024, blk, 0, stream>>>(KFQ, wfv_q, OUT, nullptr, 2048, 1792, 1792, 7168, 16);
    else
      gemm_bt<7><<<1024, blk, 0, stream>>>(KFQ, wfv_q, OUT, nullptr, 2048, 1792, 1792, 7168, 16);
  }
  gemm_bt<8><<<1024, blk, 0, stream>>>(XR2, WFR, OUT, XMID, 2048, 2048, 2048, 2048, 16);
}

// Round 7
// 1684.704 us; speedup vs baseline: 1.7708x; 1.1150x over previous
//
#include <hip/hip_runtime.h>

#define B_   4
#define TT_  2048
#define C_   2048
#define H_   32
#define S_   64
#define DF_  7168
#define TCH  512
#define NCH  4

typedef unsigned short u16;
typedef __bf16 bf16x8 __attribute__((ext_vector_type(8)));
typedef float  f32x4  __attribute__((ext_vector_type(4)));

__device__ __forceinline__ u16 f2bf(float f) {
  unsigned u = __builtin_bit_cast(unsigned, f);
  u = u + 0x7FFFu + ((u >> 16) & 1u);
  return (u16)(u >> 16);
}
__device__ __forceinline__ float bf2f(u16 v) {
  unsigned u = ((unsigned)v) << 16;
  return __builtin_bit_cast(float, u);
}

#define GLOAD16(g, l) __builtin_amdgcn_global_load_lds( \
    (const __attribute__((address_space(1))) void*)(g), \
    (__attribute__((address_space(3))) void*)(l), 16, 0, 0)

// ---- weight convert+transpose ----------------------------------------------
__global__ __launch_bounds__(256) void wcvt_t(const float* __restrict__ W,
                                              u16* __restrict__ Wt, int K, int Nfull,
                                              int n0off) {
  __shared__ alignas(16) float tile[32][33];
  int nloc = blockIdx.x * 32, k0 = blockIdx.y * 32;
  int tx = threadIdx.x & 31, ty = threadIdx.x >> 5;
  for (int r = ty; r < 32; r += 8)
    tile[r][tx] = W[(size_t)(k0 + r) * Nfull + n0off + nloc + tx];
  __syncthreads();
  for (int r = ty; r < 32; r += 8)
    Wt[(size_t)(nloc + r) * K + k0 + tx] = f2bf(tile[tx][r]);
}

// ---- layernorm over C=2048, f32 in -> bf16 out ------------------------------
__global__ __launch_bounds__(256) void ln_rows(const float* __restrict__ x,
                                               const float* __restrict__ g,
                                               const float* __restrict__ b,
                                               u16* __restrict__ out) {
  const int row = blockIdx.x;
  const float* xr = x + (size_t)row * C_;
  float v[8]; float s = 0.f, s2 = 0.f;
#pragma unroll
  for (int i = 0; i < 8; i++) { v[i] = xr[threadIdx.x + i * 256]; s += v[i]; s2 += v[i] * v[i]; }
#pragma unroll
  for (int o = 32; o > 0; o >>= 1) { s += __shfl_down(s, o); s2 += __shfl_down(s2, o); }
  __shared__ float rs[4], rs2[4];
  int wid = threadIdx.x >> 6, lane = threadIdx.x & 63;
  if (lane == 0) { rs[wid] = s; rs2[wid] = s2; }
  __syncthreads();
  s = rs[0] + rs[1] + rs[2] + rs[3];
  s2 = rs2[0] + rs2[1] + rs2[2] + rs2[3];
  float m = s * (1.f / C_);
  float var = s2 * (1.f / C_) - m * m;
  float inv = rsqrtf(var + 1e-5f);
  u16* orow = out + (size_t)row * C_;
#pragma unroll
  for (int i = 0; i < 8; i++) {
    int c = threadIdx.x + i * 256;
    orow[c] = f2bf((v[i] - m) * inv * g[c] + b[c]);
  }
}

// ---- decay tables -----------------------------------------------------------
__global__ void wtabs_k(const float* __restrict__ td, float* __restrict__ wb_tab,
                        float* __restrict__ wk_tab, float* __restrict__ wspow) {
  int h = blockIdx.x, t = threadIdx.x;
  float w = expf(-expf(td[h]));
  wb_tab[h * TCH + t] = powf(w, (float)t);
  wk_tab[h * TCH + t] = powf(w, (float)(TCH - 1 - t));
  if (t == 0) wspow[h] = powf(w, (float)TCH);
}

// ---- time-shift mixes -------------------------------------------------------
__device__ __forceinline__ void mix_body(const u16* cur, const u16* prev, bool hasp,
                                         const float* mc, u16* dst) {
  ushort4 c0 = *(const ushort4*)cur;
  ushort4 c1 = *(const ushort4*)(cur + 4);
  ushort4 p0 = {0, 0, 0, 0}, p1 = {0, 0, 0, 0};
  if (hasp) { p0 = *(const ushort4*)prev; p1 = *(const ushort4*)(prev + 4); }
  float4 mA = *(const float4*)mc;
  float4 mB = *(const float4*)(mc + 4);
  ushort4 r0, r1;
  r0.x = f2bf(bf2f(c0.x) * mA.x + bf2f(p0.x) * (1.f - mA.x));
  r0.y = f2bf(bf2f(c0.y) * mA.y + bf2f(p0.y) * (1.f - mA.y));
  r0.z = f2bf(bf2f(c0.z) * mA.z + bf2f(p0.z) * (1.f - mA.z));
  r0.w = f2bf(bf2f(c0.w) * mA.w + bf2f(p0.w) * (1.f - mA.w));
  r1.x = f2bf(bf2f(c1.x) * mB.x + bf2f(p1.x) * (1.f - mB.x));
  r1.y = f2bf(bf2f(c1.y) * mB.y + bf2f(p1.y) * (1.f - mB.y));
  r1.z = f2bf(bf2f(c1.z) * mB.z + bf2f(p1.z) * (1.f - mB.z));
  r1.w = f2bf(bf2f(c1.w) * mB.w + bf2f(p1.w) * (1.f - mB.w));
  *(ushort4*)dst = r0;
  *(ushort4*)(dst + 4) = r1;
}

__global__ __launch_bounds__(256) void mix3(const u16* __restrict__ h,
                                            const float* __restrict__ mk,
                                            const float* __restrict__ mv,
                                            const float* __restrict__ mr,
                                            u16* __restrict__ xk, u16* __restrict__ xv,
                                            u16* __restrict__ xr) {
  size_t i8 = (size_t)blockIdx.x * 256 + threadIdx.x;
  size_t off = i8 * 8;
  int c0 = (int)(off & (C_ - 1));
  int row = (int)(i8 >> 8);
  bool hasp = (row & (TT_ - 1)) != 0;
  const u16* cur = h + off;
  const u16* prev = cur - C_;
  mix_body(cur, prev, hasp, mk + c0, xk + off);
  mix_body(cur, prev, hasp, mv + c0, xv + off);
  mix_body(cur, prev, hasp, mr + c0, xr + off);
}

__global__ __launch_bounds__(256) void mix2(const u16* __restrict__ h,
                                            const float* __restrict__ mk,
                                            const float* __restrict__ mr,
                                            u16* __restrict__ xk, u16* __restrict__ xr) {
  size_t i8 = (size_t)blockIdx.x * 256 + threadIdx.x;
  size_t off = i8 * 8;
  int c0 = (int)(off & (C_ - 1));
  int row = (int)(i8 >> 8);
  bool hasp = (row & (TT_ - 1)) != 0;
  const u16* cur = h + off;
  const u16* prev = cur - C_;
  mix_body(cur, prev, hasp, mk + c0, xk + off);
  mix_body(cur, prev, hasp, mr + c0, xr + off);
}

// ---- GEMM, BK=64 (m97 structure + XCD swizzle): C(M,N)=A(M,K[lda])*Bt(N,K[ldb])^T
// EPI: 0 = bf16 store ; 1 = f32 out = acc + res ; 2 = bf16 relu(acc)^2 ;
//      3 = bf16 sigmoid(acc) ; 9 = f32 out = out + bf16(sr)*acc (fused FFN gate)
template <int EPI>
__global__ __launch_bounds__(256) void gemm_bt(const u16* __restrict__ A,
                                               const u16* __restrict__ Bt,
                                               void* __restrict__ Cv,
                                               const float* __restrict__ res,
                                               const u16* __restrict__ srp,
                                               int N, int K, int lda, int ldb, int gy) {
  __shared__ alignas(16) u16 As[128 * 64];
  __shared__ alignas(16) u16 Bs[128 * 64];
  const int nwg = gridDim.x;
  const int qq = nwg >> 3;
  const int wg = (int)(blockIdx.x & 7) * qq + (int)(blockIdx.x >> 3);
  const int bx = wg / gy, by = wg % gy;
  const int tid = threadIdx.x;
  const int wid = tid >> 6, lane = tid & 63;
  const int fr = lane & 15, fq = lane >> 4;
  const int m0 = bx * 128, n0 = by * 128;
  const int wm = (wid >> 1) * 64, wn = (wid & 1) * 64;
  const int rowS = tid >> 3, colS = (tid & 7) * 8;
  const u16* Ag = A + (size_t)(m0 + rowS) * lda + colS;
  const u16* Bg = Bt + (size_t)(n0 + rowS) * ldb + colS;
  char* ldsA = (char*)As + wid * 1024;
  char* ldsB = (char*)Bs + wid * 1024;
  f32x4 acc[4][4];
#pragma unroll
  for (int i = 0; i < 4; i++)
#pragma unroll
    for (int j = 0; j < 4; j++) acc[i][j] = (f32x4){0.f, 0.f, 0.f, 0.f};

  for (int k0 = 0; k0 < K; k0 += 64) {
    GLOAD16(Ag + k0, ldsA);
    GLOAD16(Ag + k0 + (size_t)32 * lda, ldsA + 4096);
    GLOAD16(Ag + k0 + (size_t)64 * lda, ldsA + 8192);
    GLOAD16(Ag + k0 + (size_t)96 * lda, ldsA + 12288);
    GLOAD16(Bg + k0, ldsB);
    GLOAD16(Bg + k0 + (size_t)32 * ldb, ldsB + 4096);
    GLOAD16(Bg + k0 + (size_t)64 * ldb, ldsB + 8192);
    GLOAD16(Bg + k0 + (size_t)96 * ldb, ldsB + 12288);
    __syncthreads();
#pragma unroll
    for (int kk = 0; kk < 2; kk++) {
      bf16x8 av[4], bv[4];
#pragma unroll
      for (int m = 0; m < 4; m++)
        av[m] = *(const bf16x8*)&As[(wm + m * 16 + fr) * 64 + kk * 32 + fq * 8];
#pragma unroll
      for (int n = 0; n < 4; n++)
        bv[n] = *(const bf16x8*)&Bs[(wn + n * 16 + fr) * 64 + kk * 32 + fq * 8];
#pragma unroll
      for (int m = 0; m < 4; m++)
#pragma unroll
        for (int n = 0; n < 4; n++)
          acc[m][n] = __builtin_amdgcn_mfma_f32_16x16x32_bf16(av[m], bv[n], acc[m][n], 0, 0, 0);
    }
    __syncthreads();
  }
#pragma unroll
  for (int m = 0; m < 4; m++)
#pragma unroll
    for (int n = 0; n < 4; n++)
#pragma unroll
      for (int j = 0; j < 4; j++) {
        int row = m0 + wm + m * 16 + fq * 4 + j;
        int col = n0 + wn + n * 16 + fr;
        size_t idx = (size_t)row * N + col;
        float v = acc[m][n][j];
        if (EPI == 0) ((u16*)Cv)[idx] = f2bf(v);
        else if (EPI == 1) ((float*)Cv)[idx] = v + res[idx];
        else if (EPI == 2) { float r = v > 0.f ? v : 0.f; ((u16*)Cv)[idx] = f2bf(r * r); }
        else if (EPI == 3) ((u16*)Cv)[idx] = f2bf(1.f / (1.f + expf(-v)));
        else {
          float pvv = ((float*)Cv)[idx];
          ((float*)Cv)[idx] = pvv + bf2f(srp[idx]) * v;
        }
      }
}

// ---- kvsum: per-chunk S_c[s][sv] = sum_t wk[t]*K[t][s]*V[t][sv]  (MFMA) -----
__global__ __launch_bounds__(256) void kvsum_m(const u16* __restrict__ K,
                                               const u16* __restrict__ V,
                                               const float* __restrict__ wk_tab,
                                               float* __restrict__ SC) {
  const int bh = blockIdx.x & 127, c = blockIdx.x >> 7;
  const int b = bh >> 5, h = bh & 31;
  const int tid = threadIdx.x, w = tid >> 6, lane = tid & 63;
  const int fr = lane & 15, fq = lane >> 4;
  const size_t chunkbase = (size_t)b * TT_ + (size_t)c * TCH;
  const u16* Kp = K + chunkbase * C_ + h * 64;
  const u16* Vp = V + chunkbase * C_ + h * 64;
  __shared__ alignas(16) u16 Kts[64 * 128];
  __shared__ alignas(16) u16 Vts[64 * 128];
  f32x4 acc[4];
#pragma unroll
  for (int n = 0; n < 4; n++) acc[n] = (f32x4){0.f, 0.f, 0.f, 0.f};

  for (int tb = 0; tb < 4; tb++) {
    __syncthreads();
    const int u = tid >> 1;
    const int tg = tb * 128 + u;
    const float wkv = wk_tab[h * TCH + tg];
#pragma unroll
    for (int i = 0; i < 4; i++) {
      int s0 = (tid & 1) * 32 + i * 8;
      uint4 dK = *(const uint4*)(Kp + (size_t)tg * C_ + s0);
      uint4 dV = *(const uint4*)(Vp + (size_t)tg * C_ + s0);
      const u16* ek = (const u16*)&dK;
      const u16* ev = (const u16*)&dV;
#pragma unroll
      for (int j = 0; j < 8; j++) {
        int s = s0 + j;
        int byte = s * 256 + u * 2;
        byte ^= (s & 7) << 4;
        *(u16*)((char*)Kts + byte) = f2bf(bf2f(ek[j]) * wkv);
        *(u16*)((char*)Vts + byte) = ev[j];
      }
    }
    __syncthreads();
#pragma unroll
    for (int kk = 0; kk < 4; kk++) {
      int rbyteA = (w * 16 + fr) * 256 + kk * 64 + fq * 16;
      rbyteA ^= (fr & 7) << 4;
      bf16x8 av = *(const bf16x8*)((char*)Kts + rbyteA);
#pragma unroll
      for (int n = 0; n < 4; n++) {
        int rbyteB = (n * 16 + fr) * 256 + kk * 64 + fq * 16;
        rbyteB ^= (fr & 7) << 4;
        bf16x8 bv = *(const bf16x8*)((char*)Vts + rbyteB);
        acc[n] = __builtin_amdgcn_mfma_f32_16x16x32_bf16(av, bv, acc[n], 0, 0, 0);
      }
    }
  }
  float* out = SC + ((size_t)c * 128 + bh) * 4096;
#pragma unroll
  for (int n = 0; n < 4; n++)
#pragma unroll
    for (int j = 0; j < 4; j++) {
      int srow = w * 16 + fq * 4 + j;
      int scol = n * 16 + fr;
      out[srow * 64 + scol] = acc[n][j];
    }
}

// ---- state combine: STt[c][s][sp] = bf16( sum_{j<c} ws^(c-1-j) SC[j][sp][s] )
__global__ __launch_bounds__(256) void stcomb(const float* __restrict__ SC,
                                              u16* __restrict__ STt,
                                              const float* __restrict__ wspow) {
  const int bh = blockIdx.x;
  const float ws = wspow[bh & 31];
  const int tid = threadIdx.x;
#pragma unroll
  for (int e = 0; e < 16; e++) {
    int idxT = e * 256 + tid;
    int s = idxT >> 6, sp = idxT & 63;
    int src = sp * 64 + s;
    float st = 0.f;
#pragma unroll
    for (int c = 0; c < 4; c++) {
      STt[((size_t)c * 128 + bh) * 4096 + idxT] = f2bf(st);
      st = ws * st + SC[((size_t)c * 128 + bh) * 4096 + src];
    }
  }
}

// ---- attention output (MFMA, batched over chunks; 34KB LDS) -----------------
__global__ __launch_bounds__(256) void att_out_m(const u16* __restrict__ R,
                                                 const u16* __restrict__ K,
                                                 const u16* __restrict__ V,
                                                 const u16* __restrict__ STt,
                                                 const float* __restrict__ wb_tab,
                                                 const float* __restrict__ u_vec,
                                                 u16* __restrict__ xa) {
  const int bh = blockIdx.x;
  const int ti = blockIdx.y;
  const int c  = blockIdx.z;
  const int b = bh >> 5, h = bh & 31;
  const int tid = threadIdx.x, w = tid >> 6, lane = tid & 63;
  const int fr = lane & 15, fq = lane >> 4;
  const int t0 = ti * 64;
  const size_t chunkbase = (size_t)b * TT_ + (size_t)c * TCH;
  const u16* Rp = R + (chunkbase + t0) * C_ + h * 64;
  const u16* Kp = K + chunkbase * C_ + h * 64;
  const u16* Vp = V + chunkbase * C_ + h * 64;

  __shared__ alignas(16) u16 Rs[64 * 64];
  __shared__ alignas(16) u16 Ks[64 * 64];
  __shared__ alignas(16) u16 Vts[64 * 64];
  __shared__ alignas(16) u16 Xs[64 * 64];
  __shared__ float wbs[512];

#pragma unroll
  for (int it = 0; it < 2; it++) {
    int r = (tid >> 3) + it * 32;
    int cb = (tid & 7) * 16;
    uint4 d = *(const uint4*)((const char*)(Rp + (size_t)r * C_) + cb);
    int byte = (r * 128 + cb) ^ ((r & 7) << 4);
    *(uint4*)((char*)Rs + byte) = d;
  }
  const u16* stg = STt + ((size_t)c * 128 + bh) * 4096;
#pragma unroll
  for (int it = 0; it < 2; it++) {
    int s = (tid >> 3) + it * 32;
    int cb = (tid & 7) * 16;
    uint4 d = *(const uint4*)((const char*)(stg + (size_t)s * 64) + cb);
    int byte = (s * 128 + cb) ^ ((s & 7) << 4);
    *(uint4*)((char*)Xs + byte) = d;
  }
  wbs[tid] = wb_tab[h * TCH + tid];
  wbs[tid + 256] = wb_tab[h * TCH + tid + 256];
  const float uh = u_vec[h];
  __syncthreads();

  f32x4 pv[4];
#pragma unroll
  for (int n = 0; n < 4; n++) pv[n] = (f32x4){0.f, 0.f, 0.f, 0.f};
#pragma unroll
  for (int kk = 0; kk < 2; kk++) {
    int rbA = ((w * 16 + fr) * 128 + kk * 64 + fq * 16) ^ ((fr & 7) << 4);
    bf16x8 av = *(const bf16x8*)((char*)Rs + rbA);
#pragma unroll
    for (int n = 0; n < 4; n++) {
      int rbB = ((n * 16 + fr) * 128 + kk * 64 + fq * 16) ^ ((fr & 7) << 4);
      bf16x8 bv = *(const bf16x8*)((char*)Xs + rbB);
      pv[n] = __builtin_amdgcn_mfma_f32_16x16x32_bf16(av, bv, pv[n], 0, 0, 0);
    }
  }
#pragma unroll
  for (int n = 0; n < 4; n++)
#pragma unroll
    for (int j = 0; j < 4; j++) {
      int tg = t0 + w * 16 + fq * 4 + j;
      pv[n][j] *= wbs[tg];
    }

  for (int ub = 0; ub <= ti; ub++) {
    const int u0 = ub * 64;
    __syncthreads();
#pragma unroll
    for (int it = 0; it < 2; it++) {
      int r = (tid >> 3) + it * 32;
      int cb = (tid & 7) * 16;
      uint4 d = *(const uint4*)((const char*)(Kp + (size_t)(u0 + r) * C_) + cb);
      int byte = (r * 128 + cb) ^ ((r & 7) << 4);
      *(uint4*)((char*)Ks + byte) = d;
    }
#pragma unroll
    for (int it = 0; it < 2; it++) {
      int u = (tid >> 3) + it * 32;
      int s0 = (tid & 7) * 8;
      uint4 d = *(const uint4*)(Vp + (size_t)(u0 + u) * C_ + s0);
      const u16* ev = (const u16*)&d;
#pragma unroll
      for (int j = 0; j < 8; j++) {
        int s = s0 + j;
        int byte = (s * 128 + u * 2) ^ ((s & 7) << 4);
        *(u16*)((char*)Vts + byte) = ev[j];
      }
    }
    __syncthreads();
    f32x4 accA[4];
#pragma unroll
    for (int n = 0; n < 4; n++) accA[n] = (f32x4){0.f, 0.f, 0.f, 0.f};
#pragma unroll
    for (int kk = 0; kk < 2; kk++) {
      int rbA = ((w * 16 + fr) * 128 + kk * 64 + fq * 16) ^ ((fr & 7) << 4);
      bf16x8 av = *(const bf16x8*)((char*)Rs + rbA);
#pragma unroll
      for (int n = 0; n < 4; n++) {
        int rbB = ((n * 16 + fr) * 128 + kk * 64 + fq * 16) ^ ((fr & 7) << 4);
        bf16x8 bv = *(const bf16x8*)((char*)Ks + rbB);
        accA[n] = __builtin_amdgcn_mfma_f32_16x16x32_bf16(av, bv, accA[n], 0, 0, 0);
      }
    }
#pragma unroll
    for (int n = 0; n < 4; n++) {
#pragma unroll
      for (int j = 0; j < 4; j++) {
        int tl = w * 16 + fq * 4 + j;
        int tg = t0 + tl;
        int u = u0 + n * 16 + fr;
        int d = tg - u;
        float f = (d > 0) ? wbs[d - 1] : ((d == 0) ? uh : 0.f);
        int byte = (tl * 128 + (n * 16 + fr) * 2) ^ ((tl & 7) << 4);
        *(u16*)((char*)Xs + byte) = f2bf(accA[n][j] * f);
      }
    }
#pragma unroll
    for (int kk = 0; kk < 2; kk++) {
      int rbA = ((w * 16 + fr) * 128 + kk * 64 + fq * 16) ^ ((fr & 7) << 4);
      bf16x8 ap = *(const bf16x8*)((char*)Xs + rbA);
#pragma unroll
      for (int n = 0; n < 4; n++) {
        int rbB = ((n * 16 + fr) * 128 + kk * 64 + fq * 16) ^ ((fr & 7) << 4);
        bf16x8 vp = *(const bf16x8*)((char*)Vts + rbB);
        pv[n] = __builtin_amdgcn_mfma_f32_16x16x32_bf16(ap, vp, pv[n], 0, 0, 0);
      }
    }
  }
  u16* xout = xa + (chunkbase + t0) * C_ + h * 64;
#pragma unroll
  for (int n = 0; n < 4; n++)
#pragma unroll
    for (int j = 0; j < 4; j++) {
      int tl = w * 16 + fq * 4 + j;
      xout[(size_t)tl * C_ + n * 16 + fr] = f2bf(pv[n][j]);
    }
}

// ---- per-head groupnorm ------------------------------------------------------
__global__ __launch_bounds__(256) void gnorm(const u16* __restrict__ xa,
                                             const float* __restrict__ g,
                                             const float* __restrict__ b,
                                             u16* __restrict__ out) {
  const int row = blockIdx.x;
  const int lane = threadIdx.x & 63, wv = threadIdx.x >> 6;
  const u16* xp = xa + (size_t)row * C_;
  u16* op = out + (size_t)row * C_;
  for (int h = wv; h < 32; h += 4) {
    float v = bf2f(xp[h * 64 + lane]) * 0.125f;
    float s = v, s2 = v * v;
#pragma unroll
    for (int o = 32; o > 0; o >>= 1) { s += __shfl_down(s, o); s2 += __shfl_down(s2, o); }
    s = __shfl(s, 0); s2 = __shfl(s2, 0);
    float m = s * (1.f / 64.f), var = s2 * (1.f / 64.f) - m * m;
    float nv = (v - m) * rsqrtf(var + 1e-5f);
    op[h * 64 + lane] = f2bf(nv * g[h * 64 + lane] + b[h * 64 + lane]);
  }
}

// ---- launcher ---------------------------------------------------------------
extern "C" void kernel_launch(void* const* d_in, const int* in_sizes, int n_in,
                              void* d_out, int out_size, void* d_ws, size_t ws_size,
                              hipStream_t stream) {
  (void)in_sizes; (void)n_in; (void)out_size; (void)ws_size;
  const float* x    = (const float*)d_in[0];
  const float* ln1g = (const float*)d_in[1];
  const float* ln1b = (const float*)d_in[2];
  const float* ln2g = (const float*)d_in[3];
  const float* ln2b = (const float*)d_in[4];
  const float* amk  = (const float*)d_in[5];
  const float* amv  = (const float*)d_in[6];
  const float* amr  = (const float*)d_in[7];
  const float* tdec = (const float*)d_in[8];
  const float* tfaa = (const float*)d_in[9];
  const float* Wr   = (const float*)d_in[10];
  const float* Wk   = (const float*)d_in[11];
  const float* Wv   = (const float*)d_in[12];
  const float* Wo   = (const float*)d_in[13];
  const float* lnxg = (const float*)d_in[14];
  const float* lnxb = (const float*)d_in[15];
  const float* fmk  = (const float*)d_in[16];
  const float* fmr  = (const float*)d_in[17];
  const float* Wfk  = (const float*)d_in[18];
  const float* Wfr  = (const float*)d_in[19];
  const float* Wfv  = (const float*)d_in[20];

  char* ws = (char*)d_ws;
  const size_t MB = 1ull << 20;
  // Overlay map (peak ~216 MiB):
  u16* WR  = (u16*)(ws + 0 * MB);     // attn weights; dead -> SC/STt -> XK2(0-32)
  u16* WK  = (u16*)(ws + 8 * MB);
  u16* WV  = (u16*)(ws + 16 * MB);
  u16* WO  = (u16*)(ws + 24 * MB);
  u16* WFR = (u16*)(ws + 32 * MB);
  u16* WFK = (u16*)(ws + 40 * MB);    // 28 MB
  u16* WFV = (u16*)(ws + 68 * MB);    // 28 MB
  u16* H1  = (u16*)(ws + 96 * MB);    // h1 -> r -> xan -> xr2
  u16* XR  = (u16*)(ws + 128 * MB);   // xr -> k -> SR(bf16)
  u16* XK  = (u16*)(ws + 160 * MB);   // xk -> v -> KFH(160-216)
  u16* XV  = (u16*)(ws + 192 * MB);   // xv -> xa -> h2
  float* WBT = (float*)(ws + 224 * MB);
  float* WKT = (float*)(ws + 224 * MB + 65536);
  float* WSP = (float*)(ws + 224 * MB + 131072);
  float* SCb = (float*)(ws + 0 * MB);   // 8 MB (WR dead at attn time)
  u16* STTb  = (u16*)(ws + 8 * MB);     // 4 MB (WK dead)
  u16* RB   = H1;
  u16* KB   = XR;
  u16* VB   = XK;
  u16* XA   = XV;
  u16* XAN  = H1;
  u16* H2   = XV;
  u16* XK2  = WR;                     // 0-32 MB
  u16* XR2  = H1;
  u16* SR   = XR;                     // 128-160 MB bf16 gate
  u16* KFH  = XK;                     // 56 MB kf half (160-216)
  float* OUT = (float*)d_out;         // x_mid then final

  dim3 blk(256);
  wcvt_t<<<dim3(64, 64), blk, 0, stream>>>(Wr, WR, 2048, 2048, 0);
  wcvt_t<<<dim3(64, 64), blk, 0, stream>>>(Wk, WK, 2048, 2048, 0);
  wcvt_t<<<dim3(64, 64), blk, 0, stream>>>(Wv, WV, 2048, 2048, 0);
  wcvt_t<<<dim3(64, 64), blk, 0, stream>>>(Wo, WO, 2048, 2048, 0);
  wcvt_t<<<dim3(64, 64), blk, 0, stream>>>(Wfr, WFR, 2048, 2048, 0);
  wcvt_t<<<dim3(224, 64), blk, 0, stream>>>(Wfk, WFK, 2048, 7168, 0);
  wcvt_t<<<dim3(64, 224), blk, 0, stream>>>(Wfv, WFV, 7168, 2048, 0);

  // ---- attention branch ----
  ln_rows<<<8192, blk, 0, stream>>>(x, ln1g, ln1b, H1);
  mix3<<<8192, blk, 0, stream>>>(H1, amk, amv, amr, XK, XV, XR);
  gemm_bt<0><<<1024, blk, 0, stream>>>(XR, WR, RB, nullptr, nullptr, 2048, 2048, 2048, 2048, 16);
  gemm_bt<0><<<1024, blk, 0, stream>>>(XK, WK, KB, nullptr, nullptr, 2048, 2048, 2048, 2048, 16);
  gemm_bt<0><<<1024, blk, 0, stream>>>(XV, WV, VB, nullptr, nullptr, 2048, 2048, 2048, 2048, 16);

  wtabs_k<<<32, 512, 0, stream>>>(tdec, WBT, WKT, WSP);
  kvsum_m<<<512, blk, 0, stream>>>(KB, VB, WKT, SCb);
  stcomb<<<128, blk, 0, stream>>>(SCb, STTb, WSP);
  att_out_m<<<dim3(128, 8, 4), blk, 0, stream>>>(RB, KB, VB, STTb, WBT, tfaa, XA);

  gnorm<<<8192, blk, 0, stream>>>(XA, lnxg, lnxb, XAN);
  // x_mid directly into d_out (f32)
  gemm_bt<1><<<1024, blk, 0, stream>>>(XAN, WO, OUT, x, nullptr, 2048, 2048, 2048, 2048, 16);

  // ---- FFN branch ----
  ln_rows<<<8192, blk, 0, stream>>>(OUT, ln2g, ln2b, H2);
  mix2<<<8192, blk, 0, stream>>>(H2, fmk, fmr, XK2, XR2);
  // gate: SR = sigmoid(xr2 @ Wfr^T) stored bf16
  gemm_bt<3><<<1024, blk, 0, stream>>>(XR2, WFR, SR, nullptr, nullptr, 2048, 2048, 2048, 2048, 16);

  for (int half = 0; half < 2; half++) {
    const u16* a_half = XK2 + (size_t)half * 4096 * 2048;
    gemm_bt<2><<<1792, blk, 0, stream>>>(a_half, WFK, KFH, nullptr, nullptr,
                                         7168, 2048, 2048, 2048, 56);
    gemm_bt<9><<<512, blk, 0, stream>>>(KFH, WFV, OUT + (size_t)half * 4096 * 2048,
                                        nullptr, SR + (size_t)half * 4096 * 2048,
                                        2048, 7168, 7168, 7168, 16);
  }
}

// Round 8
// 1449.848 us; speedup vs baseline: 2.0576x; 1.1620x over previous
//
#include <hip/hip_runtime.h>

#define B_   4
#define TT_  2048
#define C_   2048
#define H_   32
#define S_   64
#define DF_  7168
#define TCH  512
#define NCH  4

typedef unsigned short u16;
typedef __bf16 bf16x8 __attribute__((ext_vector_type(8)));
typedef float  f32x4  __attribute__((ext_vector_type(4)));

__device__ __forceinline__ u16 f2bf(float f) {
  unsigned u = __builtin_bit_cast(unsigned, f);
  u = u + 0x7FFFu + ((u >> 16) & 1u);
  return (u16)(u >> 16);
}
__device__ __forceinline__ float bf2f(u16 v) {
  unsigned u = ((unsigned)v) << 16;
  return __builtin_bit_cast(float, u);
}

#define GLOAD16(g, l) __builtin_amdgcn_global_load_lds( \
    (const __attribute__((address_space(1))) void*)(g), \
    (__attribute__((address_space(3))) void*)(l), 16, 0, 0)

// ---- weight convert+transpose ----------------------------------------------
__global__ __launch_bounds__(256) void wcvt_t(const float* __restrict__ W,
                                              u16* __restrict__ Wt, int K, int Nfull,
                                              int n0off) {
  __shared__ alignas(16) float tile[32][33];
  int nloc = blockIdx.x * 32, k0 = blockIdx.y * 32;
  int tx = threadIdx.x & 31, ty = threadIdx.x >> 5;
  for (int r = ty; r < 32; r += 8)
    tile[r][tx] = W[(size_t)(k0 + r) * Nfull + n0off + nloc + tx];
  __syncthreads();
  for (int r = ty; r < 32; r += 8)
    Wt[(size_t)(nloc + r) * K + k0 + tx] = f2bf(tile[tx][r]);
}

// ---- layernorm over C=2048, f32 in -> bf16 out ------------------------------
__global__ __launch_bounds__(256) void ln_rows(const float* __restrict__ x,
                                               const float* __restrict__ g,
                                               const float* __restrict__ b,
                                               u16* __restrict__ out) {
  const int row = blockIdx.x;
  const float* xr = x + (size_t)row * C_;
  float v[8]; float s = 0.f, s2 = 0.f;
#pragma unroll
  for (int i = 0; i < 8; i++) { v[i] = xr[threadIdx.x + i * 256]; s += v[i]; s2 += v[i] * v[i]; }
#pragma unroll
  for (int o = 32; o > 0; o >>= 1) { s += __shfl_down(s, o); s2 += __shfl_down(s2, o); }
  __shared__ float rs[4], rs2[4];
  int wid = threadIdx.x >> 6, lane = threadIdx.x & 63;
  if (lane == 0) { rs[wid] = s; rs2[wid] = s2; }
  __syncthreads();
  s = rs[0] + rs[1] + rs[2] + rs[3];
  s2 = rs2[0] + rs2[1] + rs2[2] + rs2[3];
  float m = s * (1.f / C_);
  float var = s2 * (1.f / C_) - m * m;
  float inv = rsqrtf(var + 1e-5f);
  u16* orow = out + (size_t)row * C_;
#pragma unroll
  for (int i = 0; i < 8; i++) {
    int c = threadIdx.x + i * 256;
    orow[c] = f2bf((v[i] - m) * inv * g[c] + b[c]);
  }
}

// ---- decay tables -----------------------------------------------------------
__global__ void wtabs_k(const float* __restrict__ td, float* __restrict__ wb_tab,
                        float* __restrict__ wk_tab, float* __restrict__ wspow) {
  int h = blockIdx.x, t = threadIdx.x;
  float w = expf(-expf(td[h]));
  wb_tab[h * TCH + t] = powf(w, (float)t);
  wk_tab[h * TCH + t] = powf(w, (float)(TCH - 1 - t));
  if (t == 0) wspow[h] = powf(w, (float)TCH);
}

// ---- time-shift mixes -------------------------------------------------------
__device__ __forceinline__ void mix_body(const u16* cur, const u16* prev, bool hasp,
                                         const float* mc, u16* dst) {
  ushort4 c0 = *(const ushort4*)cur;
  ushort4 c1 = *(const ushort4*)(cur + 4);
  ushort4 p0 = {0, 0, 0, 0}, p1 = {0, 0, 0, 0};
  if (hasp) { p0 = *(const ushort4*)prev; p1 = *(const ushort4*)(prev + 4); }
  float4 mA = *(const float4*)mc;
  float4 mB = *(const float4*)(mc + 4);
  ushort4 r0, r1;
  r0.x = f2bf(bf2f(c0.x) * mA.x + bf2f(p0.x) * (1.f - mA.x));
  r0.y = f2bf(bf2f(c0.y) * mA.y + bf2f(p0.y) * (1.f - mA.y));
  r0.z = f2bf(bf2f(c0.z) * mA.z + bf2f(p0.z) * (1.f - mA.z));
  r0.w = f2bf(bf2f(c0.w) * mA.w + bf2f(p0.w) * (1.f - mA.w));
  r1.x = f2bf(bf2f(c1.x) * mB.x + bf2f(p1.x) * (1.f - mB.x));
  r1.y = f2bf(bf2f(c1.y) * mB.y + bf2f(p1.y) * (1.f - mB.y));
  r1.z = f2bf(bf2f(c1.z) * mB.z + bf2f(p1.z) * (1.f - mB.z));
  r1.w = f2bf(bf2f(c1.w) * mB.w + bf2f(p1.w) * (1.f - mB.w));
  *(ushort4*)dst = r0;
  *(ushort4*)(dst + 4) = r1;
}

__global__ __launch_bounds__(256) void mix3(const u16* __restrict__ h,
                                            const float* __restrict__ mk,
                                            const float* __restrict__ mv,
                                            const float* __restrict__ mr,
                                            u16* __restrict__ xk, u16* __restrict__ xv,
                                            u16* __restrict__ xr) {
  size_t i8 = (size_t)blockIdx.x * 256 + threadIdx.x;
  size_t off = i8 * 8;
  int c0 = (int)(off & (C_ - 1));
  int row = (int)(i8 >> 8);
  bool hasp = (row & (TT_ - 1)) != 0;
  const u16* cur = h + off;
  const u16* prev = cur - C_;
  mix_body(cur, prev, hasp, mk + c0, xk + off);
  mix_body(cur, prev, hasp, mv + c0, xv + off);
  mix_body(cur, prev, hasp, mr + c0, xr + off);
}

__global__ __launch_bounds__(256) void mix2(const u16* __restrict__ h,
                                            const float* __restrict__ mk,
                                            const float* __restrict__ mr,
                                            u16* __restrict__ xk, u16* __restrict__ xr) {
  size_t i8 = (size_t)blockIdx.x * 256 + threadIdx.x;
  size_t off = i8 * 8;
  int c0 = (int)(off & (C_ - 1));
  int row = (int)(i8 >> 8);
  bool hasp = (row & (TT_ - 1)) != 0;
  const u16* cur = h + off;
  const u16* prev = cur - C_;
  mix_body(cur, prev, hasp, mk + c0, xk + off);
  mix_body(cur, prev, hasp, mr + c0, xr + off);
}

// ---- GEMM, BK=64, T2 swizzle (pre-swizzled global source + swizzled ds_read)
// EPI: 0 = bf16 store ; 1 = f32 out = acc + res ; 2 = bf16 relu(acc)^2 ;
//      3 = bf16 sigmoid(acc) ; 9 = f32 out = out + bf16(sr)*acc (fused FFN gate)
template <int EPI>
__global__ __launch_bounds__(256) void gemm_bt(const u16* __restrict__ A,
                                               const u16* __restrict__ Bt,
                                               void* __restrict__ Cv,
                                               const float* __restrict__ res,
                                               const u16* __restrict__ srp,
                                               int N, int K, int lda, int ldb, int gy) {
  __shared__ alignas(16) u16 As[128 * 64];
  __shared__ alignas(16) u16 Bs[128 * 64];
  const int nwg = gridDim.x;
  const int qq = nwg >> 3;
  const int wg = (int)(blockIdx.x & 7) * qq + (int)(blockIdx.x >> 3);
  const int bx = wg / gy, by = wg % gy;
  const int tid = threadIdx.x;
  const int wid = tid >> 6, lane = tid & 63;
  const int fr = lane & 15, fq = lane >> 4;
  const int m0 = bx * 128, n0 = by * 128;
  const int wm = (wid >> 1) * 64, wn = (wid & 1) * 64;
  const int rowS = tid >> 3;
  // T2: inverse-swizzle the SOURCE column so the linear global_load_lds write
  // lands data in XOR-swizzled LDS position (rule #21: both-sides-or-neither).
  const int colS = ((tid & 7) * 8) ^ ((rowS & 7) << 3);
  const u16* Ag = A + (size_t)(m0 + rowS) * lda + colS;
  const u16* Bg = Bt + (size_t)(n0 + rowS) * ldb + colS;
  char* ldsA = (char*)As + wid * 1024;
  char* ldsB = (char*)Bs + wid * 1024;
  f32x4 acc[4][4];
#pragma unroll
  for (int i = 0; i < 4; i++)
#pragma unroll
    for (int j = 0; j < 4; j++) acc[i][j] = (f32x4){0.f, 0.f, 0.f, 0.f};

  for (int k0 = 0; k0 < K; k0 += 64) {
    GLOAD16(Ag + k0, ldsA);
    GLOAD16(Ag + k0 + (size_t)32 * lda, ldsA + 4096);
    GLOAD16(Ag + k0 + (size_t)64 * lda, ldsA + 8192);
    GLOAD16(Ag + k0 + (size_t)96 * lda, ldsA + 12288);
    GLOAD16(Bg + k0, ldsB);
    GLOAD16(Bg + k0 + (size_t)32 * ldb, ldsB + 4096);
    GLOAD16(Bg + k0 + (size_t)64 * ldb, ldsB + 8192);
    GLOAD16(Bg + k0 + (size_t)96 * ldb, ldsB + 12288);
    __syncthreads();
#pragma unroll
    for (int kk = 0; kk < 2; kk++) {
      bf16x8 av[4], bv[4];
#pragma unroll
      for (int m = 0; m < 4; m++) {
        int row = wm + m * 16 + fr;
        int byte = (row * 128 + kk * 64 + fq * 16) ^ ((row & 7) << 4);
        av[m] = *(const bf16x8*)((char*)As + byte);
      }
#pragma unroll
      for (int n = 0; n < 4; n++) {
        int row = wn + n * 16 + fr;
        int byte = (row * 128 + kk * 64 + fq * 16) ^ ((row & 7) << 4);
        bv[n] = *(const bf16x8*)((char*)Bs + byte);
      }
#pragma unroll
      for (int m = 0; m < 4; m++)
#pragma unroll
        for (int n = 0; n < 4; n++)
          acc[m][n] = __builtin_amdgcn_mfma_f32_16x16x32_bf16(av[m], bv[n], acc[m][n], 0, 0, 0);
    }
    __syncthreads();
  }
#pragma unroll
  for (int m = 0; m < 4; m++)
#pragma unroll
    for (int n = 0; n < 4; n++)
#pragma unroll
      for (int j = 0; j < 4; j++) {
        int row = m0 + wm + m * 16 + fq * 4 + j;
        int col = n0 + wn + n * 16 + fr;
        size_t idx = (size_t)row * N + col;
        float v = acc[m][n][j];
        if (EPI == 0) ((u16*)Cv)[idx] = f2bf(v);
        else if (EPI == 1) ((float*)Cv)[idx] = v + res[idx];
        else if (EPI == 2) { float r = v > 0.f ? v : 0.f; ((u16*)Cv)[idx] = f2bf(r * r); }
        else if (EPI == 3) ((u16*)Cv)[idx] = f2bf(1.f / (1.f + expf(-v)));
        else {
          float pvv = ((float*)Cv)[idx];
          ((float*)Cv)[idx] = pvv + bf2f(srp[idx]) * v;
        }
      }
}

// ---- kvsum: per-chunk S_c[s][sv] = sum_t wk[t]*K[t][s]*V[t][sv]  (MFMA) -----
__global__ __launch_bounds__(256) void kvsum_m(const u16* __restrict__ K,
                                               const u16* __restrict__ V,
                                               const float* __restrict__ wk_tab,
                                               float* __restrict__ SC) {
  const int bh = blockIdx.x & 127, c = blockIdx.x >> 7;
  const int b = bh >> 5, h = bh & 31;
  const int tid = threadIdx.x, w = tid >> 6, lane = tid & 63;
  const int fr = lane & 15, fq = lane >> 4;
  const size_t chunkbase = (size_t)b * TT_ + (size_t)c * TCH;
  const u16* Kp = K + chunkbase * C_ + h * 64;
  const u16* Vp = V + chunkbase * C_ + h * 64;
  __shared__ alignas(16) u16 Kts[64 * 128];
  __shared__ alignas(16) u16 Vts[64 * 128];
  f32x4 acc[4];
#pragma unroll
  for (int n = 0; n < 4; n++) acc[n] = (f32x4){0.f, 0.f, 0.f, 0.f};

  for (int tb = 0; tb < 4; tb++) {
    __syncthreads();
    const int u = tid >> 1;
    const int tg = tb * 128 + u;
    const float wkv = wk_tab[h * TCH + tg];
#pragma unroll
    for (int i = 0; i < 4; i++) {
      int s0 = (tid & 1) * 32 + i * 8;
      uint4 dK = *(const uint4*)(Kp + (size_t)tg * C_ + s0);
      uint4 dV = *(const uint4*)(Vp + (size_t)tg * C_ + s0);
      const u16* ek = (const u16*)&dK;
      const u16* ev = (const u16*)&dV;
#pragma unroll
      for (int j = 0; j < 8; j++) {
        int s = s0 + j;
        int byte = s * 256 + u * 2;
        byte ^= (s & 7) << 4;
        *(u16*)((char*)Kts + byte) = f2bf(bf2f(ek[j]) * wkv);
        *(u16*)((char*)Vts + byte) = ev[j];
      }
    }
    __syncthreads();
#pragma unroll
    for (int kk = 0; kk < 4; kk++) {
      int rbyteA = (w * 16 + fr) * 256 + kk * 64 + fq * 16;
      rbyteA ^= (fr & 7) << 4;
      bf16x8 av = *(const bf16x8*)((char*)Kts + rbyteA);
#pragma unroll
      for (int n = 0; n < 4; n++) {
        int rbyteB = (n * 16 + fr) * 256 + kk * 64 + fq * 16;
        rbyteB ^= (fr & 7) << 4;
        bf16x8 bv = *(const bf16x8*)((char*)Vts + rbyteB);
        acc[n] = __builtin_amdgcn_mfma_f32_16x16x32_bf16(av, bv, acc[n], 0, 0, 0);
      }
    }
  }
  float* out = SC + ((size_t)c * 128 + bh) * 4096;
#pragma unroll
  for (int n = 0; n < 4; n++)
#pragma unroll
    for (int j = 0; j < 4; j++) {
      int srow = w * 16 + fq * 4 + j;
      int scol = n * 16 + fr;
      out[srow * 64 + scol] = acc[n][j];
    }
}

// ---- state combine: STt[c][s][sp] = bf16( sum_{j<c} ws^(c-1-j) SC[j][sp][s] )
__global__ __launch_bounds__(256) void stcomb(const float* __restrict__ SC,
                                              u16* __restrict__ STt,
                                              const float* __restrict__ wspow) {
  const int bh = blockIdx.x;
  const float ws = wspow[bh & 31];
  const int tid = threadIdx.x;
#pragma unroll
  for (int e = 0; e < 16; e++) {
    int idxT = e * 256 + tid;
    int s = idxT >> 6, sp = idxT & 63;
    int src = sp * 64 + s;
    float st = 0.f;
#pragma unroll
    for (int c = 0; c < 4; c++) {
      STt[((size_t)c * 128 + bh) * 4096 + idxT] = f2bf(st);
      st = ws * st + SC[((size_t)c * 128 + bh) * 4096 + src];
    }
  }
}

// ---- attention output (MFMA, batched over chunks; 34KB LDS) -----------------
__global__ __launch_bounds__(256) void att_out_m(const u16* __restrict__ R,
                                                 const u16* __restrict__ K,
                                                 const u16* __restrict__ V,
                                                 const u16* __restrict__ STt,
                                                 const float* __restrict__ wb_tab,
                                                 const float* __restrict__ u_vec,
                                                 u16* __restrict__ xa) {
  const int bh = blockIdx.x;
  const int ti = blockIdx.y;
  const int c  = blockIdx.z;
  const int b = bh >> 5, h = bh & 31;
  const int tid = threadIdx.x, w = tid >> 6, lane = tid & 63;
  const int fr = lane & 15, fq = lane >> 4;
  const int t0 = ti * 64;
  const size_t chunkbase = (size_t)b * TT_ + (size_t)c * TCH;
  const u16* Rp = R + (chunkbase + t0) * C_ + h * 64;
  const u16* Kp = K + chunkbase * C_ + h * 64;
  const u16* Vp = V + chunkbase * C_ + h * 64;

  __shared__ alignas(16) u16 Rs[64 * 64];
  __shared__ alignas(16) u16 Ks[64 * 64];
  __shared__ alignas(16) u16 Vts[64 * 64];
  __shared__ alignas(16) u16 Xs[64 * 64];
  __shared__ float wbs[512];

#pragma unroll
  for (int it = 0; it < 2; it++) {
    int r = (tid >> 3) + it * 32;
    int cb = (tid & 7) * 16;
    uint4 d = *(const uint4*)((const char*)(Rp + (size_t)r * C_) + cb);
    int byte = (r * 128 + cb) ^ ((r & 7) << 4);
    *(uint4*)((char*)Rs + byte) = d;
  }
  const u16* stg = STt + ((size_t)c * 128 + bh) * 4096;
#pragma unroll
  for (int it = 0; it < 2; it++) {
    int s = (tid >> 3) + it * 32;
    int cb = (tid & 7) * 16;
    uint4 d = *(const uint4*)((const char*)(stg + (size_t)s * 64) + cb);
    int byte = (s * 128 + cb) ^ ((s & 7) << 4);
    *(uint4*)((char*)Xs + byte) = d;
  }
  wbs[tid] = wb_tab[h * TCH + tid];
  wbs[tid + 256] = wb_tab[h * TCH + tid + 256];
  const float uh = u_vec[h];
  __syncthreads();

  f32x4 pv[4];
#pragma unroll
  for (int n = 0; n < 4; n++) pv[n] = (f32x4){0.f, 0.f, 0.f, 0.f};
#pragma unroll
  for (int kk = 0; kk < 2; kk++) {
    int rbA = ((w * 16 + fr) * 128 + kk * 64 + fq * 16) ^ ((fr & 7) << 4);
    bf16x8 av = *(const bf16x8*)((char*)Rs + rbA);
#pragma unroll
    for (int n = 0; n < 4; n++) {
      int rbB = ((n * 16 + fr) * 128 + kk * 64 + fq * 16) ^ ((fr & 7) << 4);
      bf16x8 bv = *(const bf16x8*)((char*)Xs + rbB);
      pv[n] = __builtin_amdgcn_mfma_f32_16x16x32_bf16(av, bv, pv[n], 0, 0, 0);
    }
  }
#pragma unroll
  for (int n = 0; n < 4; n++)
#pragma unroll
    for (int j = 0; j < 4; j++) {
      int tg = t0 + w * 16 + fq * 4 + j;
      pv[n][j] *= wbs[tg];
    }

  for (int ub = 0; ub <= ti; ub++) {
    const int u0 = ub * 64;
    __syncthreads();
#pragma unroll
    for (int it = 0; it < 2; it++) {
      int r = (tid >> 3) + it * 32;
      int cb = (tid & 7) * 16;
      uint4 d = *(const uint4*)((const char*)(Kp + (size_t)(u0 + r) * C_) + cb);
      int byte = (r * 128 + cb) ^ ((r & 7) << 4);
      *(uint4*)((char*)Ks + byte) = d;
    }
#pragma unroll
    for (int it = 0; it < 2; it++) {
      int u = (tid >> 3) + it * 32;
      int s0 = (tid & 7) * 8;
      uint4 d = *(const uint4*)(Vp + (size_t)(u0 + u) * C_ + s0);
      const u16* ev = (const u16*)&d;
#pragma unroll
      for (int j = 0; j < 8; j++) {
        int s = s0 + j;
        int byte = (s * 128 + u * 2) ^ ((s & 7) << 4);
        *(u16*)((char*)Vts + byte) = ev[j];
      }
    }
    __syncthreads();
    f32x4 accA[4];
#pragma unroll
    for (int n = 0; n < 4; n++) accA[n] = (f32x4){0.f, 0.f, 0.f, 0.f};
#pragma unroll
    for (int kk = 0; kk < 2; kk++) {
      int rbA = ((w * 16 + fr) * 128 + kk * 64 + fq * 16) ^ ((fr & 7) << 4);
      bf16x8 av = *(const bf16x8*)((char*)Rs + rbA);
#pragma unroll
      for (int n = 0; n < 4; n++) {
        int rbB = ((n * 16 + fr) * 128 + kk * 64 + fq * 16) ^ ((fr & 7) << 4);
        bf16x8 bv = *(const bf16x8*)((char*)Ks + rbB);
        accA[n] = __builtin_amdgcn_mfma_f32_16x16x32_bf16(av, bv, accA[n], 0, 0, 0);
      }
    }
#pragma unroll
    for (int n = 0; n < 4; n++) {
#pragma unroll
      for (int j = 0; j < 4; j++) {
        int tl = w * 16 + fq * 4 + j;
        int tg = t0 + tl;
        int u = u0 + n * 16 + fr;
        int d = tg - u;
        float f = (d > 0) ? wbs[d - 1] : ((d == 0) ? uh : 0.f);
        int byte = (tl * 128 + (n * 16 + fr) * 2) ^ ((tl & 7) << 4);
        *(u16*)((char*)Xs + byte) = f2bf(accA[n][j] * f);
      }
    }
#pragma unroll
    for (int kk = 0; kk < 2; kk++) {
      int rbA = ((w * 16 + fr) * 128 + kk * 64 + fq * 16) ^ ((fr & 7) << 4);
      bf16x8 ap = *(const bf16x8*)((char*)Xs + rbA);
#pragma unroll
      for (int n = 0; n < 4; n++) {
        int rbB = ((n * 16 + fr) * 128 + kk * 64 + fq * 16) ^ ((fr & 7) << 4);
        bf16x8 vp = *(const bf16x8*)((char*)Vts + rbB);
        pv[n] = __builtin_amdgcn_mfma_f32_16x16x32_bf16(ap, vp, pv[n], 0, 0, 0);
      }
    }
  }
  u16* xout = xa + (chunkbase + t0) * C_ + h * 64;
#pragma unroll
  for (int n = 0; n < 4; n++)
#pragma unroll
    for (int j = 0; j < 4; j++) {
      int tl = w * 16 + fq * 4 + j;
      xout[(size_t)tl * C_ + n * 16 + fr] = f2bf(pv[n][j]);
    }
}

// ---- per-head groupnorm ------------------------------------------------------
__global__ __launch_bounds__(256) void gnorm(const u16* __restrict__ xa,
                                             const float* __restrict__ g,
                                             const float* __restrict__ b,
                                             u16* __restrict__ out) {
  const int row = blockIdx.x;
  const int lane = threadIdx.x & 63, wv = threadIdx.x >> 6;
  const u16* xp = xa + (size_t)row * C_;
  u16* op = out + (size_t)row * C_;
  for (int h = wv; h < 32; h += 4) {
    float v = bf2f(xp[h * 64 + lane]) * 0.125f;
    float s = v, s2 = v * v;
#pragma unroll
    for (int o = 32; o > 0; o >>= 1) { s += __shfl_down(s, o); s2 += __shfl_down(s2, o); }
    s = __shfl(s, 0); s2 = __shfl(s2, 0);
    float m = s * (1.f / 64.f), var = s2 * (1.f / 64.f) - m * m;
    float nv = (v - m) * rsqrtf(var + 1e-5f);
    op[h * 64 + lane] = f2bf(nv * g[h * 64 + lane] + b[h * 64 + lane]);
  }
}

// ---- launcher ---------------------------------------------------------------
extern "C" void kernel_launch(void* const* d_in, const int* in_sizes, int n_in,
                              void* d_out, int out_size, void* d_ws, size_t ws_size,
                              hipStream_t stream) {
  (void)in_sizes; (void)n_in; (void)out_size; (void)ws_size;
  const float* x    = (const float*)d_in[0];
  const float* ln1g = (const float*)d_in[1];
  const float* ln1b = (const float*)d_in[2];
  const float* ln2g = (const float*)d_in[3];
  const float* ln2b = (const float*)d_in[4];
  const float* amk  = (const float*)d_in[5];
  const float* amv  = (const float*)d_in[6];
  const float* amr  = (const float*)d_in[7];
  const float* tdec = (const float*)d_in[8];
  const float* tfaa = (const float*)d_in[9];
  const float* Wr   = (const float*)d_in[10];
  const float* Wk   = (const float*)d_in[11];
  const float* Wv   = (const float*)d_in[12];
  const float* Wo   = (const float*)d_in[13];
  const float* lnxg = (const float*)d_in[14];
  const float* lnxb = (const float*)d_in[15];
  const float* fmk  = (const float*)d_in[16];
  const float* fmr  = (const float*)d_in[17];
  const float* Wfk  = (const float*)d_in[18];
  const float* Wfr  = (const float*)d_in[19];
  const float* Wfv  = (const float*)d_in[20];

  char* ws = (char*)d_ws;
  const size_t MB = 1ull << 20;
  // Overlay map (peak ~216 MiB):
  u16* WR  = (u16*)(ws + 0 * MB);     // attn weights; dead -> SC/STt -> XK2(0-32)
  u16* WK  = (u16*)(ws + 8 * MB);
  u16* WV  = (u16*)(ws + 16 * MB);
  u16* WO  = (u16*)(ws + 24 * MB);
  u16* WFR = (u16*)(ws + 32 * MB);
  u16* WFK = (u16*)(ws + 40 * MB);    // 28 MB
  u16* WFV = (u16*)(ws + 68 * MB);    // 28 MB
  u16* H1  = (u16*)(ws + 96 * MB);    // h1 -> r -> xan -> xr2
  u16* XR  = (u16*)(ws + 128 * MB);   // xr -> k -> SR(bf16)
  u16* XK  = (u16*)(ws + 160 * MB);   // xk -> v -> KFH(160-216)
  u16* XV  = (u16*)(ws + 192 * MB);   // xv -> xa -> h2
  float* WBT = (float*)(ws + 224 * MB);
  float* WKT = (float*)(ws + 224 * MB + 65536);
  float* WSP = (float*)(ws + 224 * MB + 131072);
  float* SCb = (float*)(ws + 0 * MB);   // 8 MB (WR dead at attn time)
  u16* STTb  = (u16*)(ws + 8 * MB);     // 4 MB (WK dead)
  u16* RB   = H1;
  u16* KB   = XR;
  u16* VB   = XK;
  u16* XA   = XV;
  u16* XAN  = H1;
  u16* H2   = XV;
  u16* XK2  = WR;                     // 0-32 MB
  u16* XR2  = H1;
  u16* SR   = XR;                     // 128-160 MB bf16 gate
  u16* KFH  = XK;                     // 56 MB kf half (160-216)
  float* OUT = (float*)d_out;         // x_mid then final

  dim3 blk(256);
  wcvt_t<<<dim3(64, 64), blk, 0, stream>>>(Wr, WR, 2048, 2048, 0);
  wcvt_t<<<dim3(64, 64), blk, 0, stream>>>(Wk, WK, 2048, 2048, 0);
  wcvt_t<<<dim3(64, 64), blk, 0, stream>>>(Wv, WV, 2048, 2048, 0);
  wcvt_t<<<dim3(64, 64), blk, 0, stream>>>(Wo, WO, 2048, 2048, 0);
  wcvt_t<<<dim3(64, 64), blk, 0, stream>>>(Wfr, WFR, 2048, 2048, 0);
  wcvt_t<<<dim3(224, 64), blk, 0, stream>>>(Wfk, WFK, 2048, 7168, 0);
  wcvt_t<<<dim3(64, 224), blk, 0, stream>>>(Wfv, WFV, 7168, 2048, 0);

  // ---- attention branch ----
  ln_rows<<<8192, blk, 0, stream>>>(x, ln1g, ln1b, H1);
  mix3<<<8192, blk, 0, stream>>>(H1, amk, amv, amr, XK, XV, XR);
  gemm_bt<0><<<1024, blk, 0, stream>>>(XR, WR, RB, nullptr, nullptr, 2048, 2048, 2048, 2048, 16);
  gemm_bt<0><<<1024, blk, 0, stream>>>(XK, WK, KB, nullptr, nullptr, 2048, 2048, 2048, 2048, 16);
  gemm_bt<0><<<1024, blk, 0, stream>>>(XV, WV, VB, nullptr, nullptr, 2048, 2048, 2048, 2048, 16);

  wtabs_k<<<32, 512, 0, stream>>>(tdec, WBT, WKT, WSP);
  kvsum_m<<<512, blk, 0, stream>>>(KB, VB, WKT, SCb);
  stcomb<<<128, blk, 0, stream>>>(SCb, STTb, WSP);
  att_out_m<<<dim3(128, 8, 4), blk, 0, stream>>>(RB, KB, VB, STTb, WBT, tfaa, XA);

  gnorm<<<8192, blk, 0, stream>>>(XA, lnxg, lnxb, XAN);
  // x_mid directly into d_out (f32)
  gemm_bt<1><<<1024, blk, 0, stream>>>(XAN, WO, OUT, x, nullptr, 2048, 2048, 2048, 2048, 16);

  // ---- FFN branch ----
  ln_rows<<<8192, blk, 0, stream>>>(OUT, ln2g, ln2b, H2);
  mix2<<<8192, blk, 0, stream>>>(H2, fmk, fmr, XK2, XR2);
  // gate: SR = sigmoid(xr2 @ Wfr^T) stored bf16
  gemm_bt<3><<<1024, blk, 0, stream>>>(XR2, WFR, SR, nullptr, nullptr, 2048, 2048, 2048, 2048, 16);

  for (int half = 0; half < 2; half++) {
    const u16* a_half = XK2 + (size_t)half * 4096 * 2048;
    gemm_bt<2><<<1792, blk, 0, stream>>>(a_half, WFK, KFH, nullptr, nullptr,
                                         7168, 2048, 2048, 2048, 56);
    gemm_bt<9><<<512, blk, 0, stream>>>(KFH, WFV, OUT + (size_t)half * 4096 * 2048,
                                        nullptr, SR + (size_t)half * 4096 * 2048,
                                        2048, 7168, 7168, 7168, 16);
  }
}

// Round 9
// 1368.410 us; speedup vs baseline: 2.1801x; 1.0595x over previous
//
#include <hip/hip_runtime.h>

#define B_   4
#define TT_  2048
#define C_   2048
#define H_   32
#define S_   64
#define DF_  7168
#define TCH  512
#define NCH  4

typedef unsigned short u16;
typedef __bf16 bf16x8 __attribute__((ext_vector_type(8)));
typedef float  f32x4  __attribute__((ext_vector_type(4)));

__device__ __forceinline__ u16 f2bf(float f) {
  unsigned u = __builtin_bit_cast(unsigned, f);
  u = u + 0x7FFFu + ((u >> 16) & 1u);
  return (u16)(u >> 16);
}
__device__ __forceinline__ float bf2f(u16 v) {
  unsigned u = ((unsigned)v) << 16;
  return __builtin_bit_cast(float, u);
}

#define GLOAD16(g, l) __builtin_amdgcn_global_load_lds( \
    (const __attribute__((address_space(1))) void*)(g), \
    (__attribute__((address_space(3))) void*)(l), 16, 0, 0)

// ---- weight convert+transpose ----------------------------------------------
__global__ __launch_bounds__(256) void wcvt_t(const float* __restrict__ W,
                                              u16* __restrict__ Wt, int K, int Nfull,
                                              int n0off) {
  __shared__ alignas(16) float tile[32][33];
  int nloc = blockIdx.x * 32, k0 = blockIdx.y * 32;
  int tx = threadIdx.x & 31, ty = threadIdx.x >> 5;
  for (int r = ty; r < 32; r += 8)
    tile[r][tx] = W[(size_t)(k0 + r) * Nfull + n0off + nloc + tx];
  __syncthreads();
  for (int r = ty; r < 32; r += 8)
    Wt[(size_t)(nloc + r) * K + k0 + tx] = f2bf(tile[tx][r]);
}

// ---- layernorm over C=2048, f32 in -> bf16 out ------------------------------
__global__ __launch_bounds__(256) void ln_rows(const float* __restrict__ x,
                                               const float* __restrict__ g,
                                               const float* __restrict__ b,
                                               u16* __restrict__ out) {
  const int row = blockIdx.x;
  const float* xr = x + (size_t)row * C_;
  float v[8]; float s = 0.f, s2 = 0.f;
#pragma unroll
  for (int i = 0; i < 8; i++) { v[i] = xr[threadIdx.x + i * 256]; s += v[i]; s2 += v[i] * v[i]; }
#pragma unroll
  for (int o = 32; o > 0; o >>= 1) { s += __shfl_down(s, o); s2 += __shfl_down(s2, o); }
  __shared__ float rs[4], rs2[4];
  int wid = threadIdx.x >> 6, lane = threadIdx.x & 63;
  if (lane == 0) { rs[wid] = s; rs2[wid] = s2; }
  __syncthreads();
  s = rs[0] + rs[1] + rs[2] + rs[3];
  s2 = rs2[0] + rs2[1] + rs2[2] + rs2[3];
  float m = s * (1.f / C_);
  float var = s2 * (1.f / C_) - m * m;
  float inv = rsqrtf(var + 1e-5f);
  u16* orow = out + (size_t)row * C_;
#pragma unroll
  for (int i = 0; i < 8; i++) {
    int c = threadIdx.x + i * 256;
    orow[c] = f2bf((v[i] - m) * inv * g[c] + b[c]);
  }
}

// ---- decay tables -----------------------------------------------------------
__global__ void wtabs_k(const float* __restrict__ td, float* __restrict__ wb_tab,
                        float* __restrict__ wk_tab, float* __restrict__ wspow) {
  int h = blockIdx.x, t = threadIdx.x;
  float w = expf(-expf(td[h]));
  wb_tab[h * TCH + t] = powf(w, (float)t);
  wk_tab[h * TCH + t] = powf(w, (float)(TCH - 1 - t));
  if (t == 0) wspow[h] = powf(w, (float)TCH);
}

// ---- time-shift mixes -------------------------------------------------------
__device__ __forceinline__ void mix_body(const u16* cur, const u16* prev, bool hasp,
                                         const float* mc, u16* dst) {
  ushort4 c0 = *(const ushort4*)cur;
  ushort4 c1 = *(const ushort4*)(cur + 4);
  ushort4 p0 = {0, 0, 0, 0}, p1 = {0, 0, 0, 0};
  if (hasp) { p0 = *(const ushort4*)prev; p1 = *(const ushort4*)(prev + 4); }
  float4 mA = *(const float4*)mc;
  float4 mB = *(const float4*)(mc + 4);
  ushort4 r0, r1;
  r0.x = f2bf(bf2f(c0.x) * mA.x + bf2f(p0.x) * (1.f - mA.x));
  r0.y = f2bf(bf2f(c0.y) * mA.y + bf2f(p0.y) * (1.f - mA.y));
  r0.z = f2bf(bf2f(c0.z) * mA.z + bf2f(p0.z) * (1.f - mA.z));
  r0.w = f2bf(bf2f(c0.w) * mA.w + bf2f(p0.w) * (1.f - mA.w));
  r1.x = f2bf(bf2f(c1.x) * mB.x + bf2f(p1.x) * (1.f - mB.x));
  r1.y = f2bf(bf2f(c1.y) * mB.y + bf2f(p1.y) * (1.f - mB.y));
  r1.z = f2bf(bf2f(c1.z) * mB.z + bf2f(p1.z) * (1.f - mB.z));
  r1.w = f2bf(bf2f(c1.w) * mB.w + bf2f(p1.w) * (1.f - mB.w));
  *(ushort4*)dst = r0;
  *(ushort4*)(dst + 4) = r1;
}

__global__ __launch_bounds__(256) void mix3(const u16* __restrict__ h,
                                            const float* __restrict__ mk,
                                            const float* __restrict__ mv,
                                            const float* __restrict__ mr,
                                            u16* __restrict__ xk, u16* __restrict__ xv,
                                            u16* __restrict__ xr) {
  size_t i8 = (size_t)blockIdx.x * 256 + threadIdx.x;
  size_t off = i8 * 8;
  int c0 = (int)(off & (C_ - 1));
  int row = (int)(i8 >> 8);
  bool hasp = (row & (TT_ - 1)) != 0;
  const u16* cur = h + off;
  const u16* prev = cur - C_;
  mix_body(cur, prev, hasp, mk + c0, xk + off);
  mix_body(cur, prev, hasp, mv + c0, xv + off);
  mix_body(cur, prev, hasp, mr + c0, xr + off);
}

__global__ __launch_bounds__(256) void mix2(const u16* __restrict__ h,
                                            const float* __restrict__ mk,
                                            const float* __restrict__ mr,
                                            u16* __restrict__ xk, u16* __restrict__ xr) {
  size_t i8 = (size_t)blockIdx.x * 256 + threadIdx.x;
  size_t off = i8 * 8;
  int c0 = (int)(off & (C_ - 1));
  int row = (int)(i8 >> 8);
  bool hasp = (row & (TT_ - 1)) != 0;
  const u16* cur = h + off;
  const u16* prev = cur - C_;
  mix_body(cur, prev, hasp, mk + c0, xk + off);
  mix_body(cur, prev, hasp, mr + c0, xr + off);
}

// ---- GEMM v2: BM=MREP*32, BN=NREP*64, BK=64, 512 thr / 8 waves (2M x 4N) ----
// Double-buffered LDS, 2-phase pipeline (stage t+1 before compute t, one
// barrier per K-tile), T2 swizzle both sides (validated round 8).
// EPI: 0 = bf16 store ; 1 = f32 out = acc + res ; 2 = bf16 relu(acc)^2 ;
//      3 = bf16 sigmoid(acc) ; 9 = f32 out = out + bf16(sr)*acc
template <int MREP, int NREP, int EPI>
__global__ __launch_bounds__(512) void gemm2(const u16* __restrict__ A,
                                             const u16* __restrict__ Bt,
                                             void* __restrict__ Cv,
                                             const float* __restrict__ res,
                                             const u16* __restrict__ srp,
                                             int N, int K, int lda, int ldb, int gy) {
  __shared__ alignas(16) u16 As[2][MREP * 32 * 64];
  __shared__ alignas(16) u16 Bs[2][NREP * 64 * 64];
  const int nwg = gridDim.x;
  const int qq = nwg >> 3;
  const int wg = (int)(blockIdx.x & 7) * qq + (int)(blockIdx.x >> 3);
  const int bx = wg / gy, by = wg % gy;
  const int tid = threadIdx.x;
  const int w = tid >> 6, lane = tid & 63;
  const int fr = lane & 15, fq = lane >> 4;
  const int m0 = bx * (MREP * 32), n0 = by * (NREP * 64);
  const int wm = (w >> 2) * (MREP * 16);
  const int wn = (w & 3) * (NREP * 16);
  const int rowS = tid >> 3;
  const int colS = ((tid & 7) * 8) ^ ((rowS & 7) << 3);  // T2 inverse-swizzled source
  const u16* Ag = A + (size_t)(m0 + rowS) * lda + colS;
  const u16* Bg = Bt + (size_t)(n0 + rowS) * ldb + colS;
  const int NT = K >> 6;
  f32x4 acc[MREP][NREP];
#pragma unroll
  for (int m = 0; m < MREP; m++)
#pragma unroll
    for (int n = 0; n < NREP; n++) acc[m][n] = (f32x4){0.f, 0.f, 0.f, 0.f};

  // prologue: stage tile 0 into buf 0
#pragma unroll
  for (int i = 0; i < MREP / 2; i++)
    GLOAD16(Ag + (size_t)(i * 64) * lda, (char*)As[0] + i * 8192 + w * 1024);
#pragma unroll
  for (int i = 0; i < NREP; i++)
    GLOAD16(Bg + (size_t)(i * 64) * ldb, (char*)Bs[0] + i * 8192 + w * 1024);
  __syncthreads();

  for (int t = 0; t < NT; t++) {
    const int p = t & 1;
    if (t + 1 < NT) {  // stage next tile into the other buffer (readers drained last barrier)
      const int k1 = (t + 1) << 6;
#pragma unroll
      for (int i = 0; i < MREP / 2; i++)
        GLOAD16(Ag + (size_t)(i * 64) * lda + k1, (char*)As[p ^ 1] + i * 8192 + w * 1024);
#pragma unroll
      for (int i = 0; i < NREP; i++)
        GLOAD16(Bg + (size_t)(i * 64) * ldb + k1, (char*)Bs[p ^ 1] + i * 8192 + w * 1024);
    }
#pragma unroll
    for (int kk = 0; kk < 2; kk++) {
      bf16x8 av[MREP], bv[NREP];
#pragma unroll
      for (int m = 0; m < MREP; m++) {
        int row = wm + m * 16 + fr;
        int byte = (row * 128 + kk * 64 + fq * 16) ^ ((row & 7) << 4);
        av[m] = *(const bf16x8*)((char*)As[p] + byte);
      }
#pragma unroll
      for (int n = 0; n < NREP; n++) {
        int row = wn + n * 16 + fr;
        int byte = (row * 128 + kk * 64 + fq * 16) ^ ((row & 7) << 4);
        bv[n] = *(const bf16x8*)((char*)Bs[p] + byte);
      }
#pragma unroll
      for (int m = 0; m < MREP; m++)
#pragma unroll
        for (int n = 0; n < NREP; n++)
          acc[m][n] = __builtin_amdgcn_mfma_f32_16x16x32_bf16(av[m], bv[n], acc[m][n], 0, 0, 0);
    }
    __syncthreads();  // drains staging (issued a full compute-phase ago) + LDS reads
  }
#pragma unroll
  for (int m = 0; m < MREP; m++)
#pragma unroll
    for (int n = 0; n < NREP; n++)
#pragma unroll
      for (int j = 0; j < 4; j++) {
        int row = m0 + wm + m * 16 + fq * 4 + j;
        int col = n0 + wn + n * 16 + fr;
        size_t idx = (size_t)row * N + col;
        float v = acc[m][n][j];
        if (EPI == 0) ((u16*)Cv)[idx] = f2bf(v);
        else if (EPI == 1) ((float*)Cv)[idx] = v + res[idx];
        else if (EPI == 2) { float r = v > 0.f ? v : 0.f; ((u16*)Cv)[idx] = f2bf(r * r); }
        else if (EPI == 3) ((u16*)Cv)[idx] = f2bf(1.f / (1.f + expf(-v)));
        else {
          float pvv = ((float*)Cv)[idx];
          ((float*)Cv)[idx] = pvv + bf2f(srp[idx]) * v;
        }
      }
}

// ---- kvsum: per-chunk S_c[s][sv] = sum_t wk[t]*K[t][s]*V[t][sv]  (MFMA) -----
__global__ __launch_bounds__(256) void kvsum_m(const u16* __restrict__ K,
                                               const u16* __restrict__ V,
                                               const float* __restrict__ wk_tab,
                                               float* __restrict__ SC) {
  const int bh = blockIdx.x & 127, c = blockIdx.x >> 7;
  const int b = bh >> 5, h = bh & 31;
  const int tid = threadIdx.x, w = tid >> 6, lane = tid & 63;
  const int fr = lane & 15, fq = lane >> 4;
  const size_t chunkbase = (size_t)b * TT_ + (size_t)c * TCH;
  const u16* Kp = K + chunkbase * C_ + h * 64;
  const u16* Vp = V + chunkbase * C_ + h * 64;
  __shared__ alignas(16) u16 Kts[64 * 128];
  __shared__ alignas(16) u16 Vts[64 * 128];
  f32x4 acc[4];
#pragma unroll
  for (int n = 0; n < 4; n++) acc[n] = (f32x4){0.f, 0.f, 0.f, 0.f};

  for (int tb = 0; tb < 4; tb++) {
    __syncthreads();
    const int u = tid >> 1;
    const int tg = tb * 128 + u;
    const float wkv = wk_tab[h * TCH + tg];
#pragma unroll
    for (int i = 0; i < 4; i++) {
      int s0 = (tid & 1) * 32 + i * 8;
      uint4 dK = *(const uint4*)(Kp + (size_t)tg * C_ + s0);
      uint4 dV = *(const uint4*)(Vp + (size_t)tg * C_ + s0);
      const u16* ek = (const u16*)&dK;
      const u16* ev = (const u16*)&dV;
#pragma unroll
      for (int j = 0; j < 8; j++) {
        int s = s0 + j;
        int byte = s * 256 + u * 2;
        byte ^= (s & 7) << 4;
        *(u16*)((char*)Kts + byte) = f2bf(bf2f(ek[j]) * wkv);
        *(u16*)((char*)Vts + byte) = ev[j];
      }
    }
    __syncthreads();
#pragma unroll
    for (int kk = 0; kk < 4; kk++) {
      int rbyteA = (w * 16 + fr) * 256 + kk * 64 + fq * 16;
      rbyteA ^= (fr & 7) << 4;
      bf16x8 av = *(const bf16x8*)((char*)Kts + rbyteA);
#pragma unroll
      for (int n = 0; n < 4; n++) {
        int rbyteB = (n * 16 + fr) * 256 + kk * 64 + fq * 16;
        rbyteB ^= (fr & 7) << 4;
        bf16x8 bv = *(const bf16x8*)((char*)Vts + rbyteB);
        acc[n] = __builtin_amdgcn_mfma_f32_16x16x32_bf16(av, bv, acc[n], 0, 0, 0);
      }
    }
  }
  float* out = SC + ((size_t)c * 128 + bh) * 4096;
#pragma unroll
  for (int n = 0; n < 4; n++)
#pragma unroll
    for (int j = 0; j < 4; j++) {
      int srow = w * 16 + fq * 4 + j;
      int scol = n * 16 + fr;
      out[srow * 64 + scol] = acc[n][j];
    }
}

// ---- state combine: STt[c][s][sp] = bf16( sum_{j<c} ws^(c-1-j) SC[j][sp][s] )
__global__ __launch_bounds__(256) void stcomb(const float* __restrict__ SC,
                                              u16* __restrict__ STt,
                                              const float* __restrict__ wspow) {
  const int bh = blockIdx.x;
  const float ws = wspow[bh & 31];
  const int tid = threadIdx.x;
#pragma unroll
  for (int e = 0; e < 16; e++) {
    int idxT = e * 256 + tid;
    int s = idxT >> 6, sp = idxT & 63;
    int src = sp * 64 + s;
    float st = 0.f;
#pragma unroll
    for (int c = 0; c < 4; c++) {
      STt[((size_t)c * 128 + bh) * 4096 + idxT] = f2bf(st);
      st = ws * st + SC[((size_t)c * 128 + bh) * 4096 + src];
    }
  }
}

// ---- attention output (MFMA, batched over chunks; 34KB LDS) -----------------
__global__ __launch_bounds__(256) void att_out_m(const u16* __restrict__ R,
                                                 const u16* __restrict__ K,
                                                 const u16* __restrict__ V,
                                                 const u16* __restrict__ STt,
                                                 const float* __restrict__ wb_tab,
                                                 const float* __restrict__ u_vec,
                                                 u16* __restrict__ xa) {
  const int bh = blockIdx.x;
  const int ti = blockIdx.y;
  const int c  = blockIdx.z;
  const int b = bh >> 5, h = bh & 31;
  const int tid = threadIdx.x, w = tid >> 6, lane = tid & 63;
  const int fr = lane & 15, fq = lane >> 4;
  const int t0 = ti * 64;
  const size_t chunkbase = (size_t)b * TT_ + (size_t)c * TCH;
  const u16* Rp = R + (chunkbase + t0) * C_ + h * 64;
  const u16* Kp = K + chunkbase * C_ + h * 64;
  const u16* Vp = V + chunkbase * C_ + h * 64;

  __shared__ alignas(16) u16 Rs[64 * 64];
  __shared__ alignas(16) u16 Ks[64 * 64];
  __shared__ alignas(16) u16 Vts[64 * 64];
  __shared__ alignas(16) u16 Xs[64 * 64];
  __shared__ float wbs[512];

#pragma unroll
  for (int it = 0; it < 2; it++) {
    int r = (tid >> 3) + it * 32;
    int cb = (tid & 7) * 16;
    uint4 d = *(const uint4*)((const char*)(Rp + (size_t)r * C_) + cb);
    int byte = (r * 128 + cb) ^ ((r & 7) << 4);
    *(uint4*)((char*)Rs + byte) = d;
  }
  const u16* stg = STt + ((size_t)c * 128 + bh) * 4096;
#pragma unroll
  for (int it = 0; it < 2; it++) {
    int s = (tid >> 3) + it * 32;
    int cb = (tid & 7) * 16;
    uint4 d = *(const uint4*)((const char*)(stg + (size_t)s * 64) + cb);
    int byte = (s * 128 + cb) ^ ((s & 7) << 4);
    *(uint4*)((char*)Xs + byte) = d;
  }
  wbs[tid] = wb_tab[h * TCH + tid];
  wbs[tid + 256] = wb_tab[h * TCH + tid + 256];
  const float uh = u_vec[h];
  __syncthreads();

  f32x4 pv[4];
#pragma unroll
  for (int n = 0; n < 4; n++) pv[n] = (f32x4){0.f, 0.f, 0.f, 0.f};
#pragma unroll
  for (int kk = 0; kk < 2; kk++) {
    int rbA = ((w * 16 + fr) * 128 + kk * 64 + fq * 16) ^ ((fr & 7) << 4);
    bf16x8 av = *(const bf16x8*)((char*)Rs + rbA);
#pragma unroll
    for (int n = 0; n < 4; n++) {
      int rbB = ((n * 16 + fr) * 128 + kk * 64 + fq * 16) ^ ((fr & 7) << 4);
      bf16x8 bv = *(const bf16x8*)((char*)Xs + rbB);
      pv[n] = __builtin_amdgcn_mfma_f32_16x16x32_bf16(av, bv, pv[n], 0, 0, 0);
    }
  }
#pragma unroll
  for (int n = 0; n < 4; n++)
#pragma unroll
    for (int j = 0; j < 4; j++) {
      int tg = t0 + w * 16 + fq * 4 + j;
      pv[n][j] *= wbs[tg];
    }

  for (int ub = 0; ub <= ti; ub++) {
    const int u0 = ub * 64;
    __syncthreads();
#pragma unroll
    for (int it = 0; it < 2; it++) {
      int r = (tid >> 3) + it * 32;
      int cb = (tid & 7) * 16;
      uint4 d = *(const uint4*)((const char*)(Kp + (size_t)(u0 + r) * C_) + cb);
      int byte = (r * 128 + cb) ^ ((r & 7) << 4);
      *(uint4*)((char*)Ks + byte) = d;
    }
#pragma unroll
    for (int it = 0; it < 2; it++) {
      int u = (tid >> 3) + it * 32;
      int s0 = (tid & 7) * 8;
      uint4 d = *(const uint4*)(Vp + (size_t)(u0 + u) * C_ + s0);
      const u16* ev = (const u16*)&d;
#pragma unroll
      for (int j = 0; j < 8; j++) {
        int s = s0 + j;
        int byte = (s * 128 + u * 2) ^ ((s & 7) << 4);
        *(u16*)((char*)Vts + byte) = ev[j];
      }
    }
    __syncthreads();
    f32x4 accA[4];
#pragma unroll
    for (int n = 0; n < 4; n++) accA[n] = (f32x4){0.f, 0.f, 0.f, 0.f};
#pragma unroll
    for (int kk = 0; kk < 2; kk++) {
      int rbA = ((w * 16 + fr) * 128 + kk * 64 + fq * 16) ^ ((fr & 7) << 4);
      bf16x8 av = *(const bf16x8*)((char*)Rs + rbA);
#pragma unroll
      for (int n = 0; n < 4; n++) {
        int rbB = ((n * 16 + fr) * 128 + kk * 64 + fq * 16) ^ ((fr & 7) << 4);
        bf16x8 bv = *(const bf16x8*)((char*)Ks + rbB);
        accA[n] = __builtin_amdgcn_mfma_f32_16x16x32_bf16(av, bv, accA[n], 0, 0, 0);
      }
    }
#pragma unroll
    for (int n = 0; n < 4; n++) {
#pragma unroll
      for (int j = 0; j < 4; j++) {
        int tl = w * 16 + fq * 4 + j;
        int tg = t0 + tl;
        int u = u0 + n * 16 + fr;
        int d = tg - u;
        float f = (d > 0) ? wbs[d - 1] : ((d == 0) ? uh : 0.f);
        int byte = (tl * 128 + (n * 16 + fr) * 2) ^ ((tl & 7) << 4);
        *(u16*)((char*)Xs + byte) = f2bf(accA[n][j] * f);
      }
    }
#pragma unroll
    for (int kk = 0; kk < 2; kk++) {
      int rbA = ((w * 16 + fr) * 128 + kk * 64 + fq * 16) ^ ((fr & 7) << 4);
      bf16x8 ap = *(const bf16x8*)((char*)Xs + rbA);
#pragma unroll
      for (int n = 0; n < 4; n++) {
        int rbB = ((n * 16 + fr) * 128 + kk * 64 + fq * 16) ^ ((fr & 7) << 4);
        bf16x8 vp = *(const bf16x8*)((char*)Vts + rbB);
        pv[n] = __builtin_amdgcn_mfma_f32_16x16x32_bf16(ap, vp, pv[n], 0, 0, 0);
      }
    }
  }
  u16* xout = xa + (chunkbase + t0) * C_ + h * 64;
#pragma unroll
  for (int n = 0; n < 4; n++)
#pragma unroll
    for (int j = 0; j < 4; j++) {
      int tl = w * 16 + fq * 4 + j;
      xout[(size_t)tl * C_ + n * 16 + fr] = f2bf(pv[n][j]);
    }
}

// ---- per-head groupnorm ------------------------------------------------------
__global__ __launch_bounds__(256) void gnorm(const u16* __restrict__ xa,
                                             const float* __restrict__ g,
                                             const float* __restrict__ b,
                                             u16* __restrict__ out) {
  const int row = blockIdx.x;
  const int lane = threadIdx.x & 63, wv = threadIdx.x >> 6;
  const u16* xp = xa + (size_t)row * C_;
  u16* op = out + (size_t)row * C_;
  for (int h = wv; h < 32; h += 4) {
    float v = bf2f(xp[h * 64 + lane]) * 0.125f;
    float s = v, s2 = v * v;
#pragma unroll
    for (int o = 32; o > 0; o >>= 1) { s += __shfl_down(s, o); s2 += __shfl_down(s2, o); }
    s = __shfl(s, 0); s2 = __shfl(s2, 0);
    float m = s * (1.f / 64.f), var = s2 * (1.f / 64.f) - m * m;
    float nv = (v - m) * rsqrtf(var + 1e-5f);
    op[h * 64 + lane] = f2bf(nv * g[h * 64 + lane] + b[h * 64 + lane]);
  }
}

// ---- launcher ---------------------------------------------------------------
extern "C" void kernel_launch(void* const* d_in, const int* in_sizes, int n_in,
                              void* d_out, int out_size, void* d_ws, size_t ws_size,
                              hipStream_t stream) {
  (void)in_sizes; (void)n_in; (void)out_size; (void)ws_size;
  const float* x    = (const float*)d_in[0];
  const float* ln1g = (const float*)d_in[1];
  const float* ln1b = (const float*)d_in[2];
  const float* ln2g = (const float*)d_in[3];
  const float* ln2b = (const float*)d_in[4];
  const float* amk  = (const float*)d_in[5];
  const float* amv  = (const float*)d_in[6];
  const float* amr  = (const float*)d_in[7];
  const float* tdec = (const float*)d_in[8];
  const float* tfaa = (const float*)d_in[9];
  const float* Wr   = (const float*)d_in[10];
  const float* Wk   = (const float*)d_in[11];
  const float* Wv   = (const float*)d_in[12];
  const float* Wo   = (const float*)d_in[13];
  const float* lnxg = (const float*)d_in[14];
  const float* lnxb = (const float*)d_in[15];
  const float* fmk  = (const float*)d_in[16];
  const float* fmr  = (const float*)d_in[17];
  const float* Wfk  = (const float*)d_in[18];
  const float* Wfr  = (const float*)d_in[19];
  const float* Wfv  = (const float*)d_in[20];

  char* ws = (char*)d_ws;
  const size_t MB = 1ull << 20;
  // Overlay map (peak ~216 MiB):
  u16* WR  = (u16*)(ws + 0 * MB);     // attn weights; dead -> SC/STt -> XK2(0-32)
  u16* WK  = (u16*)(ws + 8 * MB);
  u16* WV  = (u16*)(ws + 16 * MB);
  u16* WO  = (u16*)(ws + 24 * MB);
  u16* WFR = (u16*)(ws + 32 * MB);
  u16* WFK = (u16*)(ws + 40 * MB);    // 28 MB
  u16* WFV = (u16*)(ws + 68 * MB);    // 28 MB
  u16* H1  = (u16*)(ws + 96 * MB);    // h1 -> r -> xan -> xr2
  u16* XR  = (u16*)(ws + 128 * MB);   // xr -> k -> SR(bf16)
  u16* XK  = (u16*)(ws + 160 * MB);   // xk -> v -> KFH(160-216)
  u16* XV  = (u16*)(ws + 192 * MB);   // xv -> xa -> h2
  float* WBT = (float*)(ws + 224 * MB);
  float* WKT = (float*)(ws + 224 * MB + 65536);
  float* WSP = (float*)(ws + 224 * MB + 131072);
  float* SCb = (float*)(ws + 0 * MB);   // 8 MB (WR dead at attn time)
  u16* STTb  = (u16*)(ws + 8 * MB);     // 4 MB (WK dead)
  u16* RB   = H1;
  u16* KB   = XR;
  u16* VB   = XK;
  u16* XA   = XV;
  u16* XAN  = H1;
  u16* H2   = XV;
  u16* XK2  = WR;                     // 0-32 MB
  u16* XR2  = H1;
  u16* SR   = XR;                     // 128-160 MB bf16 gate
  u16* KFH  = XK;                     // 56 MB kf half (160-216)
  float* OUT = (float*)d_out;         // x_mid then final

  dim3 blk(256), gblk(512);
  wcvt_t<<<dim3(64, 64), blk, 0, stream>>>(Wr, WR, 2048, 2048, 0);
  wcvt_t<<<dim3(64, 64), blk, 0, stream>>>(Wk, WK, 2048, 2048, 0);
  wcvt_t<<<dim3(64, 64), blk, 0, stream>>>(Wv, WV, 2048, 2048, 0);
  wcvt_t<<<dim3(64, 64), blk, 0, stream>>>(Wo, WO, 2048, 2048, 0);
  wcvt_t<<<dim3(64, 64), blk, 0, stream>>>(Wfr, WFR, 2048, 2048, 0);
  wcvt_t<<<dim3(224, 64), blk, 0, stream>>>(Wfk, WFK, 2048, 7168, 0);
  wcvt_t<<<dim3(64, 224), blk, 0, stream>>>(Wfv, WFV, 7168, 2048, 0);

  // ---- attention branch ----
  ln_rows<<<8192, blk, 0, stream>>>(x, ln1g, ln1b, H1);
  mix3<<<8192, blk, 0, stream>>>(H1, amk, amv, amr, XK, XV, XR);
  gemm2<8, 4, 0><<<256, gblk, 0, stream>>>(XR, WR, RB, nullptr, nullptr, 2048, 2048, 2048, 2048, 8);
  gemm2<8, 4, 0><<<256, gblk, 0, stream>>>(XK, WK, KB, nullptr, nullptr, 2048, 2048, 2048, 2048, 8);
  gemm2<8, 4, 0><<<256, gblk, 0, stream>>>(XV, WV, VB, nullptr, nullptr, 2048, 2048, 2048, 2048, 8);

  wtabs_k<<<32, 512, 0, stream>>>(tdec, WBT, WKT, WSP);
  kvsum_m<<<512, blk, 0, stream>>>(KB, VB, WKT, SCb);
  stcomb<<<128, blk, 0, stream>>>(SCb, STTb, WSP);
  att_out_m<<<dim3(128, 8, 4), blk, 0, stream>>>(RB, KB, VB, STTb, WBT, tfaa, XA);

  gnorm<<<8192, blk, 0, stream>>>(XA, lnxg, lnxb, XAN);
  // x_mid directly into d_out (f32)
  gemm2<8, 4, 1><<<256, gblk, 0, stream>>>(XAN, WO, OUT, x, nullptr, 2048, 2048, 2048, 2048, 8);

  // ---- FFN branch ----
  ln_rows<<<8192, blk, 0, stream>>>(OUT, ln2g, ln2b, H2);
  mix2<<<8192, blk, 0, stream>>>(H2, fmk, fmr, XK2, XR2);
  // gate: SR = sigmoid(xr2 @ Wfr^T) stored bf16
  gemm2<8, 4, 3><<<256, gblk, 0, stream>>>(XR2, WFR, SR, nullptr, nullptr, 2048, 2048, 2048, 2048, 8);

  for (int half = 0; half < 2; half++) {
    const u16* a_half = XK2 + (size_t)half * 4096 * 2048;
    gemm2<8, 4, 2><<<448, gblk, 0, stream>>>(a_half, WFK, KFH, nullptr, nullptr,
                                             7168, 2048, 2048, 2048, 28);
    gemm2<4, 4, 9><<<256, gblk, 0, stream>>>(KFH, WFV, OUT + (size_t)half * 4096 * 2048,
                                             nullptr, SR + (size_t)half * 4096 * 2048,
                                             2048, 7168, 7168, 7168, 8);
  }
}